// Round 1
// baseline (1506.252 us; speedup 1.0000x reference)
//
#include <hip/hip_runtime.h>
#include <stdint.h>

#define B_  8
#define S_  1024
#define D_  768
#define H_  12
#define HD_ 64
#define FF_ 3072
#define M_  (B_*S_)   // 8192 tokens
#define R_  16

typedef unsigned short u16;
typedef short s16x8 __attribute__((ext_vector_type(8)));   // 8 bf16 (4 VGPRs)
typedef float fx4  __attribute__((ext_vector_type(4)));    // 4 fp32 acc

__device__ __forceinline__ float b2f(u16 u) {
  union { unsigned int i; float f; } c; c.i = ((unsigned int)u) << 16; return c.f;
}
__device__ __forceinline__ u16 f2b(float f) {   // RNE f32->bf16
  union { float f; unsigned int i; } c; c.f = f;
  unsigned int x = c.i;
  x += 0x7FFFu + ((x >> 16) & 1u);
  return (u16)(x >> 16);
}
__device__ __forceinline__ float gelu_f(float x) {  // jax.nn.gelu approximate=True (tanh)
  float u = 0.7978845608028654f * (x + 0.044715f * x * x * x);
  float e = __expf(2.f * u);
  float t = 1.f - 2.f / (e + 1.f);
  return 0.5f * x * (1.f + t);
}
__device__ __forceinline__ void gload16(const u16* gsrc, u16* ldst) {
  // async global->LDS, 16B per lane; dest must be wave-uniform base + lane*16
  __builtin_amdgcn_global_load_lds(
      (__attribute__((address_space(1))) void*)(gsrc),
      (__attribute__((address_space(3))) void*)(ldst), 16, 0, 0);
}

// ---------------- f32 -> bf16 weight conversion (vectorized) ----------------
__global__ __launch_bounds__(256)
void cvt_f2b(const float* __restrict__ in, u16* __restrict__ out, int n4) {
  const int i = blockIdx.x * 256 + threadIdx.x;
  if (i < n4) {
    const float4 f = ((const float4*)in)[i];
    ushort4 o4; o4.x = f2b(f.x); o4.y = f2b(f.y); o4.z = f2b(f.z); o4.w = f2b(f.w);
    ((ushort4*)out)[i] = o4;
  }
}

// ---------------- LayerNorm (optionally fused residual add) ----------------
// out_bf16 = LN(x [+ add_bf16]); if ADD also writes xsum (f32) = x + add
template<bool ADD>
__global__ __launch_bounds__(256)
void ln_k(const float* __restrict__ x, const u16* __restrict__ add,
          const float* __restrict__ g, const float* __restrict__ beta,
          u16* __restrict__ outb, float* __restrict__ xsum)
{
  const int row = blockIdx.x;
  const size_t base = (size_t)row * D_;
  float v0[3]; float s = 0.f, sq = 0.f;
  #pragma unroll
  for (int i = 0; i < 3; ++i) {
    const int d = threadIdx.x + i * 256;
    float val = x[base + d];
    if (ADD) { val += b2f(add[base + d]); xsum[base + d] = val; }
    v0[i] = val; s += val; sq += val * val;
  }
  #pragma unroll
  for (int mm = 32; mm >= 1; mm >>= 1) { s += __shfl_xor(s, mm); sq += __shfl_xor(sq, mm); }
  __shared__ float ss[4], s2[4];
  if ((threadIdx.x & 63) == 0) { ss[threadIdx.x >> 6] = s; s2[threadIdx.x >> 6] = sq; }
  __syncthreads();
  s  = ss[0] + ss[1] + ss[2] + ss[3];
  sq = s2[0] + s2[1] + s2[2] + s2[3];
  const float mean = s * (1.f / D_);
  const float var  = sq * (1.f / D_) - mean * mean;
  const float rs   = rsqrtf(var + 1e-6f);
  #pragma unroll
  for (int i = 0; i < 3; ++i) {
    const int d = threadIdx.x + i * 256;
    outb[base + d] = f2b((v0[i] - mean) * rs * g[d] + beta[d]);
  }
}

// ---------------- bf16 MFMA GEMM: C[M,N] = A[M,K] * W[N,K]^T + bias ----------------
// 128x128 tile, BK=32, 4 waves (2x2 of 64x64), global_load_lds(16B) staging.
__global__ __launch_bounds__(256)
void gemm_bt(const u16* __restrict__ A, const u16* __restrict__ W,
             const float* __restrict__ bias, u16* __restrict__ C,
             int M, int N, int K)
{
  __shared__ u16 As[128 * 32];
  __shared__ u16 Bs[128 * 32];
  const int tid   = threadIdx.x;
  const int lane  = tid & 63;
  const int wid   = tid >> 6;
  const int wr    = wid >> 1;
  const int wc    = wid & 1;
  const int lr    = lane & 15;
  const int lk    = (lane >> 4) << 3;   // k offset within BK: 0,8,16,24
  const int m0    = blockIdx.x * 128;
  const int n0    = blockIdx.y * 128;
  const int kg    = (tid & 3) * 8;      // staging k sub-offset (elements)
  const int row_a = tid >> 2;           // staging row 0..63

  fx4 acc[4][4];
  const fx4 zero = {0.f, 0.f, 0.f, 0.f};
  #pragma unroll
  for (int i = 0; i < 4; ++i)
    #pragma unroll
    for (int j = 0; j < 4; ++j) acc[i][j] = zero;

  for (int k0 = 0; k0 < K; k0 += 32) {
    #pragma unroll
    for (int u = 0; u < 2; ++u) {
      const int row = u * 64 + row_a;        // 0..127
      const int li  = u * 256 + tid;         // linear 16B chunk id
      gload16(A + (size_t)(m0 + row) * K + k0 + kg, &As[li * 8]);
      gload16(W + (size_t)(n0 + row) * K + k0 + kg, &Bs[li * 8]);
    }
    __syncthreads();   // compiler emits vmcnt(0) drain before barrier
    s16x8 av[4], bv[4];
    #pragma unroll
    for (int i = 0; i < 4; ++i)
      av[i] = *(const s16x8*)&As[(wr * 64 + i * 16 + lr) * 32 + lk];
    #pragma unroll
    for (int j = 0; j < 4; ++j)
      bv[j] = *(const s16x8*)&Bs[(wc * 64 + j * 16 + lr) * 32 + lk];
    #pragma unroll
    for (int i = 0; i < 4; ++i)
      #pragma unroll
      for (int j = 0; j < 4; ++j)
        acc[i][j] = __builtin_amdgcn_mfma_f32_16x16x32_bf16(av[i], bv[j], acc[i][j], 0, 0, 0);
    __syncthreads();
  }

  // C/D fragment mapping (m89/m91 verified): col = lane&15, row = (lane>>4)*4 + reg
  const int rb = (lane >> 4) * 4;
  #pragma unroll
  for (int j = 0; j < 4; ++j) {
    const int col = n0 + wc * 64 + j * 16 + lr;
    const float bj = bias ? bias[col] : 0.f;
    #pragma unroll
    for (int i = 0; i < 4; ++i) {
      const int row = m0 + wr * 64 + i * 16 + rb;
      #pragma unroll
      for (int r = 0; r < 4; ++r)
        C[(size_t)(row + r) * N + col] = f2b(acc[i][j][r] + bj);
    }
  }
}

// ---------------- flash attention (fp32 vector, online softmax) ----------------
// grid (S/64, B*H); block 256 = 16x16 threads; per-thread 4q x 4k sub-tile.
__global__ __launch_bounds__(256)
void attn_fwd(const u16* __restrict__ q, const u16* __restrict__ k,
              const u16* __restrict__ v, const float* __restrict__ mask,
              u16* __restrict__ o)
{
  __shared__ float Ql[64][65];
  __shared__ float Kl[64][65];
  __shared__ float Vl[64][65];
  __shared__ float Pl[64][65];
  __shared__ float mrow[64], lrow[64];

  const float scale = 0.125f;   // 1/sqrt(64)
  const int tid = threadIdx.x;
  const int ty = tid >> 4, tx = tid & 15;
  const int qb = blockIdx.x;
  const int bh = blockIdx.y;
  const int b  = bh / H_;
  const int h  = bh % H_;
  const size_t qbase = ((size_t)(b * S_ + qb * 64)) * D_ + h * HD_;

  for (int i = tid; i < 64 * 8; i += 256) {
    const int r = i >> 3, c8 = (i & 7) * 8;
    s16x8 t8 = *(const s16x8*)(q + qbase + (size_t)r * D_ + c8);
    #pragma unroll
    for (int jj = 0; jj < 8; ++jj) Ql[r][c8 + jj] = scale * b2f((u16)t8[jj]);
  }
  if (tid < 64) { mrow[tid] = -3.0e38f; lrow[tid] = 0.f; }
  float oac[4][4] = {};
  __syncthreads();

  for (int kt = 0; kt < S_ / 64; ++kt) {
    const size_t kbase = ((size_t)(b * S_ + kt * 64)) * D_ + h * HD_;
    for (int i = tid; i < 64 * 8; i += 256) {
      const int r = i >> 3, c8 = (i & 7) * 8;
      s16x8 t8 = *(const s16x8*)(k + kbase + (size_t)r * D_ + c8);
      s16x8 u8 = *(const s16x8*)(v + kbase + (size_t)r * D_ + c8);
      #pragma unroll
      for (int jj = 0; jj < 8; ++jj) {
        Kl[r][c8 + jj] = b2f((u16)t8[jj]);
        Vl[r][c8 + jj] = b2f((u16)u8[jj]);
      }
    }
    __syncthreads();

    float s[4][4] = {};
    for (int d = 0; d < 64; ++d) {
      float qv[4], kv[4];
      #pragma unroll
      for (int i = 0; i < 4; ++i) qv[i] = Ql[ty * 4 + i][d];
      #pragma unroll
      for (int j = 0; j < 4; ++j) kv[j] = Kl[tx * 4 + j][d];
      #pragma unroll
      for (int i = 0; i < 4; ++i)
        #pragma unroll
        for (int j = 0; j < 4; ++j) s[i][j] += qv[i] * kv[j];
    }
    const float* mp = mask + (size_t)(qb * 64) * S_ + (size_t)kt * 64;
    #pragma unroll
    for (int i = 0; i < 4; ++i)
      #pragma unroll
      for (int j = 0; j < 4; ++j) s[i][j] += mp[(size_t)(ty * 4 + i) * S_ + tx * 4 + j];

    // per-row online softmax; the 16 threads of a row share a wave (lockstep)
    float fac[4];
    #pragma unroll
    for (int i = 0; i < 4; ++i) {
      float mx = fmaxf(fmaxf(s[i][0], s[i][1]), fmaxf(s[i][2], s[i][3]));
      #pragma unroll
      for (int mm = 8; mm >= 1; mm >>= 1) mx = fmaxf(mx, __shfl_xor(mx, mm));
      const float om = mrow[ty * 4 + i];
      const float nm = fmaxf(om, mx);
      fac[i] = __expf(om - nm);
      float sum = 0.f;
      #pragma unroll
      for (int j = 0; j < 4; ++j) {
        const float p = __expf(s[i][j] - nm);
        Pl[ty * 4 + i][tx * 4 + j] = p;
        sum += p;
      }
      #pragma unroll
      for (int mm = 8; mm >= 1; mm >>= 1) sum += __shfl_xor(sum, mm);
      if (tx == 0) { lrow[ty * 4 + i] = lrow[ty * 4 + i] * fac[i] + sum; mrow[ty * 4 + i] = nm; }
      #pragma unroll
      for (int j = 0; j < 4; ++j) oac[i][j] *= fac[i];
    }
    __syncthreads();

    for (int c = 0; c < 64; ++c) {
      float pv[4], vv[4];
      #pragma unroll
      for (int i = 0; i < 4; ++i) pv[i] = Pl[ty * 4 + i][c];
      #pragma unroll
      for (int j = 0; j < 4; ++j) vv[j] = Vl[c][tx * 4 + j];
      #pragma unroll
      for (int i = 0; i < 4; ++i)
        #pragma unroll
        for (int j = 0; j < 4; ++j) oac[i][j] += pv[i] * vv[j];
    }
    __syncthreads();
  }

  #pragma unroll
  for (int i = 0; i < 4; ++i) {
    const float inv = 1.f / lrow[ty * 4 + i];
    #pragma unroll
    for (int j = 0; j < 4; ++j)
      o[qbase + (size_t)(ty * 4 + i) * D_ + tx * 4 + j] = f2b(oac[i][j] * inv);
  }
}

// ---------------- adapter down-projection: tmp[M,16] = act @ A (lora or vera) ----------------
__global__ __launch_bounds__(256)
void adapter_mv(const u16* __restrict__ act, const float* __restrict__ Alora,
                const float* __restrict__ Avera, const float* __restrict__ dvec,
                float* __restrict__ tmp, int Kd, const int* __restrict__ nbp)
{
  const int nb = *nbp;
  const int r  = threadIdx.x & 15;
  const int ti = threadIdx.x >> 4;
  const int m  = blockIdx.x * 16 + ti;
  const bool ex = ((m % S_) >= nb);
  const float* Am = ex ? Avera : Alora;
  const u16* rowp = act + (size_t)m * Kd;
  float acc = 0.f;
  for (int kk = 0; kk < Kd; ++kk) acc += b2f(rowp[kk]) * Am[kk * R_ + r];
  if (ex) acc *= dvec[r];
  tmp[m * R_ + r] = acc;
}

// ---------------- fc1 epilogue: hid = gelu(fc1out + adapter_up) (in-place, bias already in GEMM) ----
__global__ __launch_bounds__(256)
void mlp_epi1(u16* __restrict__ hid, const float* __restrict__ tmp,
              const float* __restrict__ Blora, const float* __restrict__ Bvera,
              const float* __restrict__ evec, const int* __restrict__ nbp)
{
  const int nb = *nbp;
  const int m = blockIdx.x;
  const bool ex = ((m % S_) >= nb);
  __shared__ float t[R_];
  if (threadIdx.x < R_) t[threadIdx.x] = tmp[m * R_ + threadIdx.x];
  __syncthreads();
  const float* Bm = ex ? Bvera : Blora;
  for (int f = threadIdx.x; f < FF_; f += 256) {
    float ad = 0.f;
    #pragma unroll
    for (int r = 0; r < R_; ++r) ad += t[r] * Bm[(size_t)r * FF_ + f];
    if (ex) ad *= evec[f];
    const size_t idx = (size_t)m * FF_ + f;
    const float pre = b2f(hid[idx]) + ad;
    hid[idx] = f2b(gelu_f(pre));
  }
}

// ---------------- final: d_out = x1 + fc2out(+bias in GEMM) + adapter2_up ----------------
__global__ __launch_bounds__(256)
void final_add(float* __restrict__ out, const u16* __restrict__ fc2o,
               const float* __restrict__ tmp, const float* __restrict__ Blora,
               const float* __restrict__ Bvera, const float* __restrict__ evec,
               const int* __restrict__ nbp)
{
  const int nb = *nbp;
  const int m = blockIdx.x;
  const bool ex = ((m % S_) >= nb);
  __shared__ float t[R_];
  if (threadIdx.x < R_) t[threadIdx.x] = tmp[m * R_ + threadIdx.x];
  __syncthreads();
  const float* Bm = ex ? Bvera : Blora;
  for (int d = threadIdx.x; d < D_; d += 256) {
    float ad = 0.f;
    #pragma unroll
    for (int r = 0; r < R_; ++r) ad += t[r] * Bm[(size_t)r * D_ + d];
    if (ex) ad *= evec[d];
    const size_t idx = (size_t)m * D_ + d;
    out[idx] += b2f(fc2o[idx]) + ad;
  }
}

extern "C" void kernel_launch(void* const* d_in, const int* in_sizes, int n_in,
                              void* d_out, int out_size, void* d_ws, size_t ws_size,
                              hipStream_t stream)
{
  const float* x      = (const float*)d_in[0];
  const float* mask   = (const float*)d_in[1];
  const float* n1g    = (const float*)d_in[2];
  const float* n1b    = (const float*)d_in[3];
  const float* q_w    = (const float*)d_in[4];
  const float* q_bv   = (const float*)d_in[5];
  const float* k_w    = (const float*)d_in[6];
  const float* k_bv   = (const float*)d_in[7];
  const float* v_w    = (const float*)d_in[8];
  const float* v_bv   = (const float*)d_in[9];
  const float* o_w    = (const float*)d_in[10];
  const float* o_bv   = (const float*)d_in[11];
  const float* n2g    = (const float*)d_in[12];
  const float* n2b    = (const float*)d_in[13];
  const float* fc1_w  = (const float*)d_in[14];
  const float* fc1_bv = (const float*)d_in[15];
  const float* fc2_w  = (const float*)d_in[16];
  const float* fc2_bv = (const float*)d_in[17];
  const float* lora1A = (const float*)d_in[18];
  const float* lora1B = (const float*)d_in[19];
  const float* lora2A = (const float*)d_in[20];
  const float* lora2B = (const float*)d_in[21];
  const float* vera1A = (const float*)d_in[22];
  const float* vera1B = (const float*)d_in[23];
  const float* vera2A = (const float*)d_in[24];
  const float* vera2B = (const float*)d_in[25];
  const float* e1d    = (const float*)d_in[26];
  const float* e1b    = (const float*)d_in[27];
  const float* e2d    = (const float*)d_in[28];
  const float* e2b    = (const float*)d_in[29];
  const int*   nbp    = (const int*)d_in[30];

  // workspace layout (~111 MB)
  char* wsb = (char*)d_ws;
  u16* h1    = (u16*)wsb; wsb += (size_t)M_ * D_ * 2;
  u16* qb_   = (u16*)wsb; wsb += (size_t)M_ * D_ * 2;
  u16* kb_   = (u16*)wsb; wsb += (size_t)M_ * D_ * 2;
  u16* vb_   = (u16*)wsb; wsb += (size_t)M_ * D_ * 2;
  u16* attno = (u16*)wsb; wsb += (size_t)M_ * D_ * 2;
  u16* oproj = (u16*)wsb; wsb += (size_t)M_ * D_ * 2;
  u16* n2    = (u16*)wsb; wsb += (size_t)M_ * D_ * 2;
  u16* fc2o  = (u16*)wsb; wsb += (size_t)M_ * D_ * 2;
  u16* wq    = (u16*)wsb; wsb += (size_t)D_ * D_ * 2;
  u16* wk    = (u16*)wsb; wsb += (size_t)D_ * D_ * 2;
  u16* wv    = (u16*)wsb; wsb += (size_t)D_ * D_ * 2;
  u16* wo    = (u16*)wsb; wsb += (size_t)D_ * D_ * 2;
  u16* wfc1  = (u16*)wsb; wsb += (size_t)FF_ * D_ * 2;
  u16* wfc2  = (u16*)wsb; wsb += (size_t)D_ * FF_ * 2;
  float* tmp1 = (float*)wsb; wsb += (size_t)M_ * R_ * 4;
  float* tmp2 = (float*)wsb; wsb += (size_t)M_ * R_ * 4;
  u16* hidb = h1;   // [M,FF] reuses h1/q/k/v region (4*M*D == M*FF), dead by then

  // weights -> bf16
  cvt_f2b<<<(D_*D_/4 + 255)/256, 256, 0, stream>>>(q_w,   wq,   D_*D_/4);
  cvt_f2b<<<(D_*D_/4 + 255)/256, 256, 0, stream>>>(k_w,   wk,   D_*D_/4);
  cvt_f2b<<<(D_*D_/4 + 255)/256, 256, 0, stream>>>(v_w,   wv,   D_*D_/4);
  cvt_f2b<<<(D_*D_/4 + 255)/256, 256, 0, stream>>>(o_w,   wo,   D_*D_/4);
  cvt_f2b<<<(FF_*D_/4 + 255)/256, 256, 0, stream>>>(fc1_w, wfc1, FF_*D_/4);
  cvt_f2b<<<(D_*FF_/4 + 255)/256, 256, 0, stream>>>(fc2_w, wfc2, D_*FF_/4);

  // attention
  ln_k<false><<<M_, 256, 0, stream>>>(x, nullptr, n1g, n1b, h1, nullptr);
  dim3 g768(M_/128, D_/128);
  gemm_bt<<<g768, 256, 0, stream>>>(h1, wq, q_bv, qb_, M_, D_, D_);
  gemm_bt<<<g768, 256, 0, stream>>>(h1, wk, k_bv, kb_, M_, D_, D_);
  gemm_bt<<<g768, 256, 0, stream>>>(h1, wv, v_bv, vb_, M_, D_, D_);
  attn_fwd<<<dim3(S_/64, B_*H_), 256, 0, stream>>>(qb_, kb_, vb_, mask, attno);
  gemm_bt<<<g768, 256, 0, stream>>>(attno, wo, o_bv, oproj, M_, D_, D_);

  // x1 = x + attn_proj (into d_out), n2 = LN(x1)
  ln_k<true><<<M_, 256, 0, stream>>>(x, oproj, n2g, n2b, n2, (float*)d_out);

  // MLP + adapters
  adapter_mv<<<M_/16, 256, 0, stream>>>(n2, lora1A, vera1A, e1d, tmp1, D_, nbp);
  gemm_bt<<<dim3(M_/128, FF_/128), 256, 0, stream>>>(n2, wfc1, fc1_bv, hidb, M_, FF_, D_);
  mlp_epi1<<<M_, 256, 0, stream>>>(hidb, tmp1, lora1B, vera1B, e1b, nbp);
  adapter_mv<<<M_/16, 256, 0, stream>>>(hidb, lora2A, vera2A, e2d, tmp2, FF_, nbp);
  gemm_bt<<<g768, 256, 0, stream>>>(hidb, wfc2, fc2_bv, fc2o, M_, D_, FF_);
  final_add<<<M_, 256, 0, stream>>>((float*)d_out, fc2o, tmp2, lora2B, vera2B, e2b, nbp);
}

// Round 2
// 1030.739 us; speedup vs baseline: 1.4613x; 1.4613x over previous
//
#include <hip/hip_runtime.h>
#include <stdint.h>

#define B_  8
#define S_  1024
#define D_  768
#define H_  12
#define HD_ 64
#define FF_ 3072
#define M_  (B_*S_)   // 8192 tokens
#define R_  16

typedef unsigned short u16;
typedef short s16x8 __attribute__((ext_vector_type(8)));   // 8 bf16 (4 VGPRs)
typedef float fx4  __attribute__((ext_vector_type(4)));    // 4 fp32 acc

__device__ __forceinline__ float b2f(u16 u) {
  union { unsigned int i; float f; } c; c.i = ((unsigned int)u) << 16; return c.f;
}
__device__ __forceinline__ u16 f2b(float f) {   // RNE f32->bf16
  union { float f; unsigned int i; } c; c.f = f;
  unsigned int x = c.i;
  x += 0x7FFFu + ((x >> 16) & 1u);
  return (u16)(x >> 16);
}
__device__ __forceinline__ float gelu_f(float x) {  // jax.nn.gelu approximate=True (tanh)
  float u = 0.7978845608028654f * (x + 0.044715f * x * x * x);
  float e = __expf(2.f * u);
  float t = 1.f - 2.f / (e + 1.f);
  return 0.5f * x * (1.f + t);
}
__device__ __forceinline__ void gload16(const u16* gsrc, u16* ldst) {
  // async global->LDS, 16B per lane; dest must be wave-uniform base + lane*16
  __builtin_amdgcn_global_load_lds(
      (__attribute__((address_space(1))) void*)(gsrc),
      (__attribute__((address_space(3))) void*)(ldst), 16, 0, 0);
}

// ---------------- f32 -> bf16 weight conversion (vectorized) ----------------
__global__ __launch_bounds__(256)
void cvt_f2b(const float* __restrict__ in, u16* __restrict__ out, int n4) {
  const int i = blockIdx.x * 256 + threadIdx.x;
  if (i < n4) {
    const float4 f = ((const float4*)in)[i];
    ushort4 o4; o4.x = f2b(f.x); o4.y = f2b(f.y); o4.z = f2b(f.z); o4.w = f2b(f.w);
    ((ushort4*)out)[i] = o4;
  }
}

// ---------------- LayerNorm (optionally fused residual add) ----------------
template<bool ADD>
__global__ __launch_bounds__(256)
void ln_k(const float* __restrict__ x, const u16* __restrict__ add,
          const float* __restrict__ g, const float* __restrict__ beta,
          u16* __restrict__ outb, float* __restrict__ xsum)
{
  const int row = blockIdx.x;
  const size_t base = (size_t)row * D_;
  float v0[3]; float s = 0.f, sq = 0.f;
  #pragma unroll
  for (int i = 0; i < 3; ++i) {
    const int d = threadIdx.x + i * 256;
    float val = x[base + d];
    if (ADD) { val += b2f(add[base + d]); xsum[base + d] = val; }
    v0[i] = val; s += val; sq += val * val;
  }
  #pragma unroll
  for (int mm = 32; mm >= 1; mm >>= 1) { s += __shfl_xor(s, mm); sq += __shfl_xor(sq, mm); }
  __shared__ float ss[4], s2[4];
  if ((threadIdx.x & 63) == 0) { ss[threadIdx.x >> 6] = s; s2[threadIdx.x >> 6] = sq; }
  __syncthreads();
  s  = ss[0] + ss[1] + ss[2] + ss[3];
  sq = s2[0] + s2[1] + s2[2] + s2[3];
  const float mean = s * (1.f / D_);
  const float var  = sq * (1.f / D_) - mean * mean;
  const float rs   = rsqrtf(var + 1e-6f);
  #pragma unroll
  for (int i = 0; i < 3; ++i) {
    const int d = threadIdx.x + i * 256;
    outb[base + d] = f2b((v0[i] - mean) * rs * g[d] + beta[d]);
  }
}

// ---------------- bf16 MFMA GEMM: C[M,N] = A[M,K] * W[N,K]^T + bias ----------------
__global__ __launch_bounds__(256)
void gemm_bt(const u16* __restrict__ A, const u16* __restrict__ W,
             const float* __restrict__ bias, u16* __restrict__ C,
             int M, int N, int K)
{
  __shared__ u16 As[128 * 32];
  __shared__ u16 Bs[128 * 32];
  const int tid   = threadIdx.x;
  const int lane  = tid & 63;
  const int wid   = tid >> 6;
  const int wr    = wid >> 1;
  const int wc    = wid & 1;
  const int lr    = lane & 15;
  const int lk    = (lane >> 4) << 3;
  const int m0    = blockIdx.x * 128;
  const int n0    = blockIdx.y * 128;
  const int kg    = (tid & 3) * 8;
  const int row_a = tid >> 2;

  fx4 acc[4][4];
  const fx4 zero = {0.f, 0.f, 0.f, 0.f};
  #pragma unroll
  for (int i = 0; i < 4; ++i)
    #pragma unroll
    for (int j = 0; j < 4; ++j) acc[i][j] = zero;

  for (int k0 = 0; k0 < K; k0 += 32) {
    #pragma unroll
    for (int u = 0; u < 2; ++u) {
      const int row = u * 64 + row_a;
      const int li  = u * 256 + tid;
      gload16(A + (size_t)(m0 + row) * K + k0 + kg, &As[li * 8]);
      gload16(W + (size_t)(n0 + row) * K + k0 + kg, &Bs[li * 8]);
    }
    __syncthreads();
    s16x8 av[4], bv[4];
    #pragma unroll
    for (int i = 0; i < 4; ++i)
      av[i] = *(const s16x8*)&As[(wr * 64 + i * 16 + lr) * 32 + lk];
    #pragma unroll
    for (int j = 0; j < 4; ++j)
      bv[j] = *(const s16x8*)&Bs[(wc * 64 + j * 16 + lr) * 32 + lk];
    #pragma unroll
    for (int i = 0; i < 4; ++i)
      #pragma unroll
      for (int j = 0; j < 4; ++j)
        acc[i][j] = __builtin_amdgcn_mfma_f32_16x16x32_bf16(av[i], bv[j], acc[i][j], 0, 0, 0);
    __syncthreads();
  }

  const int rb = (lane >> 4) * 4;
  #pragma unroll
  for (int j = 0; j < 4; ++j) {
    const int col = n0 + wc * 64 + j * 16 + lr;
    const float bj = bias ? bias[col] : 0.f;
    #pragma unroll
    for (int i = 0; i < 4; ++i) {
      const int row = m0 + wr * 64 + i * 16 + rb;
      #pragma unroll
      for (int r = 0; r < 4; ++r)
        C[(size_t)(row + r) * N + col] = f2b(acc[i][j][r] + bj);
    }
  }
}

// ---------------- MFMA flash attention ----------------
// grid (S/64, B*H); block 256 = 4 waves; each wave owns 16 q-rows.
// LDS tiles T2-swizzled: elem (row,col) at row*64 + (col ^ ((row&7)<<3)).
// Vt stores V transposed [d][k] with swizzle k ^ (((d&7)^(d>>3))<<3).
__global__ __launch_bounds__(256)
void attn_mfma(const u16* __restrict__ q, const u16* __restrict__ k,
               const u16* __restrict__ v, const float* __restrict__ mask,
               u16* __restrict__ o)
{
  __shared__ u16 Ql[64 * 64];
  __shared__ u16 Kl[64 * 64];
  __shared__ u16 Vt[64 * 64];
  __shared__ u16 Pl[4][16 * 64];

  const int tid  = threadIdx.x;
  const int lane = tid & 63;
  const int wq   = tid >> 6;       // wave id = q sub-block
  const int lr   = lane & 15;
  const int hi   = lane >> 4;
  const int qb   = blockIdx.x;
  const int bh   = blockIdx.y;
  const int b    = bh / H_;
  const int h    = bh % H_;
  const size_t tok0 = (size_t)b * S_ + (size_t)qb * 64;
  const size_t colh = (size_t)h * HD_;

  // ---- stage Q (swizzled via pre-swizzled global source) ----
  #pragma unroll
  for (int u = 0; u < 2; ++u) {
    const int li = u * 256 + tid;          // 16B chunk id; dest = base + lane*16
    const int r  = li >> 3;
    const int cb = ((li & 7) ^ (r & 7)) * 8;
    gload16(q + (tok0 + r) * D_ + colh + cb, &Ql[li * 8]);
  }
  __syncthreads();

  s16x8 qa[2];
  {
    const int qrow = wq * 16 + lr;
    #pragma unroll
    for (int ks = 0; ks < 2; ++ks)
      qa[ks] = *(const s16x8*)&Ql[qrow * 64 + ((ks * 32 + hi * 8) ^ ((qrow & 7) << 3))];
  }

  const fx4 zero = {0.f, 0.f, 0.f, 0.f};
  fx4 oacc[4];
  #pragma unroll
  for (int dj = 0; dj < 4; ++dj) oacc[dj] = zero;
  float mreg[4], lreg[4];
  #pragma unroll
  for (int r = 0; r < 4; ++r) { mreg[r] = -3.0e38f; lreg[r] = 0.f; }

  for (int kt = 0; kt < S_ / 64; ++kt) {
    const size_t ktok = (size_t)b * S_ + (size_t)kt * 64;
    __syncthreads();   // prev-tile LDS reads done before overwrite

    // stage K (gload16, swizzled source)
    #pragma unroll
    for (int u = 0; u < 2; ++u) {
      const int li = u * 256 + tid;
      const int r  = li >> 3;
      const int cb = ((li & 7) ^ (r & 7)) * 8;
      gload16(k + (ktok + r) * D_ + colh + cb, &Kl[li * 8]);
    }
    // stage V transposed (reg-staged, paired-k b32 writes, conflict-free swizzle)
    {
      const int a  = tid >> 3;            // 0..31 -> k rows 2a, 2a+1
      const int c8 = (tid & 7) * 8;       // d base
      const u16* vp = v + (ktok + 2 * a) * D_ + colh + c8;
      s16x8 v0 = *(const s16x8*)vp;
      s16x8 v1 = *(const s16x8*)(vp + D_);
      #pragma unroll
      for (int jj = 0; jj < 8; ++jj) {
        const int d  = c8 + jj;
        const int sw = ((d & 7) ^ ((d >> 3) & 7)) << 3;
        const int cp = (2 * a) ^ sw;      // even -> 4B aligned
        *(uint32_t*)&Vt[d * 64 + cp] =
            (uint32_t)(u16)v0[jj] | ((uint32_t)(u16)v1[jj] << 16);
      }
    }
    __syncthreads();   // staging visible to all waves

    // mask tile into regs (issued early; hides under MFMAs)
    float mv[4][4];
    {
      const float* mp = mask + (size_t)(qb * 64 + wq * 16 + hi * 4) * S_ + (size_t)kt * 64 + lr;
      #pragma unroll
      for (int r = 0; r < 4; ++r)
        #pragma unroll
        for (int j = 0; j < 4; ++j)
          mv[j][r] = mp[(size_t)r * S_ + j * 16];
    }

    // ---- QK^T ----
    s16x8 kb2[4][2];
    #pragma unroll
    for (int j = 0; j < 4; ++j) {
      const int n = j * 16 + lr;
      #pragma unroll
      for (int ks = 0; ks < 2; ++ks)
        kb2[j][ks] = *(const s16x8*)&Kl[n * 64 + ((ks * 32 + hi * 8) ^ ((n & 7) << 3))];
    }
    fx4 sf[4];
    #pragma unroll
    for (int j = 0; j < 4; ++j) sf[j] = zero;
    #pragma unroll
    for (int ks = 0; ks < 2; ++ks)
      #pragma unroll
      for (int j = 0; j < 4; ++j)
        sf[j] = __builtin_amdgcn_mfma_f32_16x16x32_bf16(qa[ks], kb2[j][ks], sf[j], 0, 0, 0);

    // ---- online softmax (rows = 4*hi + r, shared across 16-lane row group) ----
    float val[4][4];
    #pragma unroll
    for (int j = 0; j < 4; ++j)
      #pragma unroll
      for (int r = 0; r < 4; ++r)
        val[j][r] = sf[j][r] * 0.125f + mv[j][r];
    #pragma unroll
    for (int r = 0; r < 4; ++r) {
      float mx = fmaxf(fmaxf(val[0][r], val[1][r]), fmaxf(val[2][r], val[3][r]));
      mx = fmaxf(mx, __shfl_xor(mx, 1));
      mx = fmaxf(mx, __shfl_xor(mx, 2));
      mx = fmaxf(mx, __shfl_xor(mx, 4));
      mx = fmaxf(mx, __shfl_xor(mx, 8));
      const float mn  = fmaxf(mreg[r], mx);
      const float fac = __expf(mreg[r] - mn);
      mreg[r] = mn;
      float rs = 0.f;
      #pragma unroll
      for (int j = 0; j < 4; ++j) {
        const float p = __expf(val[j][r] - mn);
        val[j][r] = p;
        rs += p;
      }
      rs += __shfl_xor(rs, 1); rs += __shfl_xor(rs, 2);
      rs += __shfl_xor(rs, 4); rs += __shfl_xor(rs, 8);
      lreg[r] = lreg[r] * fac + rs;
      #pragma unroll
      for (int dj = 0; dj < 4; ++dj) oacc[dj][r] *= fac;
    }

    // ---- P -> wave-private LDS (bf16, T2 swizzle) ----
    #pragma unroll
    for (int j = 0; j < 4; ++j) {
      const int col = j * 16 + lr;
      #pragma unroll
      for (int r = 0; r < 4; ++r) {
        const int row = hi * 4 + r;
        Pl[wq][row * 64 + (col ^ ((row & 7) << 3))] = f2b(val[j][r]);
      }
    }
    s16x8 pa[2];
    #pragma unroll
    for (int ks = 0; ks < 2; ++ks)
      pa[ks] = *(const s16x8*)&Pl[wq][lr * 64 + ((ks * 32 + hi * 8) ^ ((lr & 7) << 3))];

    // ---- PV ----
    s16x8 bv2[4][2];
    #pragma unroll
    for (int dj = 0; dj < 4; ++dj) {
      const int n  = dj * 16 + lr;
      const int sw = ((n & 7) ^ ((n >> 3) & 7)) << 3;
      #pragma unroll
      for (int ks = 0; ks < 2; ++ks)
        bv2[dj][ks] = *(const s16x8*)&Vt[n * 64 + ((ks * 32 + hi * 8) ^ sw)];
    }
    #pragma unroll
    for (int ks = 0; ks < 2; ++ks)
      #pragma unroll
      for (int dj = 0; dj < 4; ++dj)
        oacc[dj] = __builtin_amdgcn_mfma_f32_16x16x32_bf16(pa[ks], bv2[dj][ks], oacc[dj], 0, 0, 0);
  }

  // ---- epilogue: O /= l, write ----
  #pragma unroll
  for (int r = 0; r < 4; ++r) {
    const float inv = 1.f / lreg[r];
    const size_t grow = (tok0 + wq * 16 + hi * 4 + r) * D_ + colh;
    #pragma unroll
    for (int dj = 0; dj < 4; ++dj)
      o[grow + dj * 16 + lr] = f2b(oacc[dj][r] * inv);
  }
}

// ---------------- adapter down-projection: tmp[M,16] = act @ A (lora or vera) ----------------
__global__ __launch_bounds__(256)
void adapter_mv(const u16* __restrict__ act, const float* __restrict__ Alora,
                const float* __restrict__ Avera, const float* __restrict__ dvec,
                float* __restrict__ tmp, int Kd, const int* __restrict__ nbp)
{
  const int nb = *nbp;
  const int r  = threadIdx.x & 15;
  const int ti = threadIdx.x >> 4;
  const int m  = blockIdx.x * 16 + ti;
  const bool ex = ((m % S_) >= nb);
  const float* Am = ex ? Avera : Alora;
  const u16* rowp = act + (size_t)m * Kd;
  float acc = 0.f;
  for (int kk = 0; kk < Kd; ++kk) acc += b2f(rowp[kk]) * Am[kk * R_ + r];
  if (ex) acc *= dvec[r];
  tmp[m * R_ + r] = acc;
}

// ---------------- fc1 epilogue: hid = gelu(fc1out + adapter_up) ----------------
__global__ __launch_bounds__(256)
void mlp_epi1(u16* __restrict__ hid, const float* __restrict__ tmp,
              const float* __restrict__ Blora, const float* __restrict__ Bvera,
              const float* __restrict__ evec, const int* __restrict__ nbp)
{
  const int nb = *nbp;
  const int m = blockIdx.x;
  const bool ex = ((m % S_) >= nb);
  __shared__ float t[R_];
  if (threadIdx.x < R_) t[threadIdx.x] = tmp[m * R_ + threadIdx.x];
  __syncthreads();
  const float* Bm = ex ? Bvera : Blora;
  for (int f = threadIdx.x; f < FF_; f += 256) {
    float ad = 0.f;
    #pragma unroll
    for (int r = 0; r < R_; ++r) ad += t[r] * Bm[(size_t)r * FF_ + f];
    if (ex) ad *= evec[f];
    const size_t idx = (size_t)m * FF_ + f;
    const float pre = b2f(hid[idx]) + ad;
    hid[idx] = f2b(gelu_f(pre));
  }
}

// ---------------- final: d_out = x1 + fc2out + adapter2_up ----------------
__global__ __launch_bounds__(256)
void final_add(float* __restrict__ out, const u16* __restrict__ fc2o,
               const float* __restrict__ tmp, const float* __restrict__ Blora,
               const float* __restrict__ Bvera, const float* __restrict__ evec,
               const int* __restrict__ nbp)
{
  const int nb = *nbp;
  const int m = blockIdx.x;
  const bool ex = ((m % S_) >= nb);
  __shared__ float t[R_];
  if (threadIdx.x < R_) t[threadIdx.x] = tmp[m * R_ + threadIdx.x];
  __syncthreads();
  const float* Bm = ex ? Bvera : Blora;
  for (int d = threadIdx.x; d < D_; d += 256) {
    float ad = 0.f;
    #pragma unroll
    for (int r = 0; r < R_; ++r) ad += t[r] * Bm[(size_t)r * D_ + d];
    if (ex) ad *= evec[d];
    const size_t idx = (size_t)m * D_ + d;
    out[idx] += b2f(fc2o[idx]) + ad;
  }
}

extern "C" void kernel_launch(void* const* d_in, const int* in_sizes, int n_in,
                              void* d_out, int out_size, void* d_ws, size_t ws_size,
                              hipStream_t stream)
{
  const float* x      = (const float*)d_in[0];
  const float* mask   = (const float*)d_in[1];
  const float* n1g    = (const float*)d_in[2];
  const float* n1b    = (const float*)d_in[3];
  const float* q_w    = (const float*)d_in[4];
  const float* q_bv   = (const float*)d_in[5];
  const float* k_w    = (const float*)d_in[6];
  const float* k_bv   = (const float*)d_in[7];
  const float* v_w    = (const float*)d_in[8];
  const float* v_bv   = (const float*)d_in[9];
  const float* o_w    = (const float*)d_in[10];
  const float* o_bv   = (const float*)d_in[11];
  const float* n2g    = (const float*)d_in[12];
  const float* n2b    = (const float*)d_in[13];
  const float* fc1_w  = (const float*)d_in[14];
  const float* fc1_bv = (const float*)d_in[15];
  const float* fc2_w  = (const float*)d_in[16];
  const float* fc2_bv = (const float*)d_in[17];
  const float* lora1A = (const float*)d_in[18];
  const float* lora1B = (const float*)d_in[19];
  const float* lora2A = (const float*)d_in[20];
  const float* lora2B = (const float*)d_in[21];
  const float* vera1A = (const float*)d_in[22];
  const float* vera1B = (const float*)d_in[23];
  const float* vera2A = (const float*)d_in[24];
  const float* vera2B = (const float*)d_in[25];
  const float* e1d    = (const float*)d_in[26];
  const float* e1b    = (const float*)d_in[27];
  const float* e2d    = (const float*)d_in[28];
  const float* e2b    = (const float*)d_in[29];
  const int*   nbp    = (const int*)d_in[30];

  char* wsb = (char*)d_ws;
  u16* h1    = (u16*)wsb; wsb += (size_t)M_ * D_ * 2;
  u16* qb_   = (u16*)wsb; wsb += (size_t)M_ * D_ * 2;
  u16* kb_   = (u16*)wsb; wsb += (size_t)M_ * D_ * 2;
  u16* vb_   = (u16*)wsb; wsb += (size_t)M_ * D_ * 2;
  u16* attno = (u16*)wsb; wsb += (size_t)M_ * D_ * 2;
  u16* oproj = (u16*)wsb; wsb += (size_t)M_ * D_ * 2;
  u16* n2    = (u16*)wsb; wsb += (size_t)M_ * D_ * 2;
  u16* fc2o  = (u16*)wsb; wsb += (size_t)M_ * D_ * 2;
  u16* wq    = (u16*)wsb; wsb += (size_t)D_ * D_ * 2;
  u16* wk    = (u16*)wsb; wsb += (size_t)D_ * D_ * 2;
  u16* wv    = (u16*)wsb; wsb += (size_t)D_ * D_ * 2;
  u16* wo    = (u16*)wsb; wsb += (size_t)D_ * D_ * 2;
  u16* wfc1  = (u16*)wsb; wsb += (size_t)FF_ * D_ * 2;
  u16* wfc2  = (u16*)wsb; wsb += (size_t)D_ * FF_ * 2;
  float* tmp1 = (float*)wsb; wsb += (size_t)M_ * R_ * 4;
  float* tmp2 = (float*)wsb; wsb += (size_t)M_ * R_ * 4;
  u16* hidb = h1;   // [M,FF] reuses h1/q/k/v region (4*M*D == M*FF), dead by then

  cvt_f2b<<<(D_*D_/4 + 255)/256, 256, 0, stream>>>(q_w,   wq,   D_*D_/4);
  cvt_f2b<<<(D_*D_/4 + 255)/256, 256, 0, stream>>>(k_w,   wk,   D_*D_/4);
  cvt_f2b<<<(D_*D_/4 + 255)/256, 256, 0, stream>>>(v_w,   wv,   D_*D_/4);
  cvt_f2b<<<(D_*D_/4 + 255)/256, 256, 0, stream>>>(o_w,   wo,   D_*D_/4);
  cvt_f2b<<<(FF_*D_/4 + 255)/256, 256, 0, stream>>>(fc1_w, wfc1, FF_*D_/4);
  cvt_f2b<<<(D_*FF_/4 + 255)/256, 256, 0, stream>>>(fc2_w, wfc2, D_*FF_/4);

  ln_k<false><<<M_, 256, 0, stream>>>(x, nullptr, n1g, n1b, h1, nullptr);
  dim3 g768(M_/128, D_/128);
  gemm_bt<<<g768, 256, 0, stream>>>(h1, wq, q_bv, qb_, M_, D_, D_);
  gemm_bt<<<g768, 256, 0, stream>>>(h1, wk, k_bv, kb_, M_, D_, D_);
  gemm_bt<<<g768, 256, 0, stream>>>(h1, wv, v_bv, vb_, M_, D_, D_);
  attn_mfma<<<dim3(S_/64, B_*H_), 256, 0, stream>>>(qb_, kb_, vb_, mask, attno);
  gemm_bt<<<g768, 256, 0, stream>>>(attno, wo, o_bv, oproj, M_, D_, D_);

  ln_k<true><<<M_, 256, 0, stream>>>(x, oproj, n2g, n2b, n2, (float*)d_out);

  adapter_mv<<<M_/16, 256, 0, stream>>>(n2, lora1A, vera1A, e1d, tmp1, D_, nbp);
  gemm_bt<<<dim3(M_/128, FF_/128), 256, 0, stream>>>(n2, wfc1, fc1_bv, hidb, M_, FF_, D_);
  mlp_epi1<<<M_, 256, 0, stream>>>(hidb, tmp1, lora1B, vera1B, e1b, nbp);
  adapter_mv<<<M_/16, 256, 0, stream>>>(hidb, lora2A, vera2A, e2d, tmp2, FF_, nbp);
  gemm_bt<<<g768, 256, 0, stream>>>(hidb, wfc2, fc2_bv, fc2o, M_, D_, FF_);
  final_add<<<M_, 256, 0, stream>>>((float*)d_out, fc2o, tmp2, lora2B, vera2B, e2b, nbp);
}

// Round 3
// 626.230 us; speedup vs baseline: 2.4053x; 1.6459x over previous
//
#include <hip/hip_runtime.h>
#include <stdint.h>

#define B_  8
#define S_  1024
#define D_  768
#define H_  12
#define HD_ 64
#define FF_ 3072
#define M_  (B_*S_)   // 8192 tokens
#define R_  16

typedef unsigned short u16;
typedef short s16x8 __attribute__((ext_vector_type(8)));   // 8 bf16 (4 VGPRs)
typedef float fx4  __attribute__((ext_vector_type(4)));    // 4 fp32 acc

__device__ __forceinline__ float b2f(u16 u) {
  union { unsigned int i; float f; } c; c.i = ((unsigned int)u) << 16; return c.f;
}
__device__ __forceinline__ u16 f2b(float f) {   // RNE f32->bf16
  union { float f; unsigned int i; } c; c.f = f;
  unsigned int x = c.i;
  x += 0x7FFFu + ((x >> 16) & 1u);
  return (u16)(x >> 16);
}
__device__ __forceinline__ float gelu_f(float x) {  // jax.nn.gelu approximate=True (tanh)
  float u = 0.7978845608028654f * (x + 0.044715f * x * x * x);
  float e = __expf(2.f * u);
  float t = 1.f - 2.f / (e + 1.f);
  return 0.5f * x * (1.f + t);
}
__device__ __forceinline__ void gload16(const u16* gsrc, u16* ldst) {
  __builtin_amdgcn_global_load_lds(
      (__attribute__((address_space(1))) void*)(gsrc),
      (__attribute__((address_space(3))) void*)(ldst), 16, 0, 0);
}

// ---------------- f32 -> bf16 weight conversion (vectorized) ----------------
__global__ __launch_bounds__(256)
void cvt_f2b(const float* __restrict__ in, u16* __restrict__ out, int n4) {
  const int i = blockIdx.x * 256 + threadIdx.x;
  if (i < n4) {
    const float4 f = ((const float4*)in)[i];
    ushort4 o4; o4.x = f2b(f.x); o4.y = f2b(f.y); o4.z = f2b(f.z); o4.w = f2b(f.w);
    ((ushort4*)out)[i] = o4;
  }
}

// ---------------- LayerNorm (+residual add, + fused rank-16 down-projection) ----------------
// ADD: out_bf16 = LN(x+add); xsum = x+add; tmp[row][r] = (LN_row . Acol_r) (*dvec if expert)
template<bool ADD>
__global__ __launch_bounds__(256)
void ln_k(const float* __restrict__ x, const u16* __restrict__ add,
          const float* __restrict__ g, const float* __restrict__ beta,
          u16* __restrict__ outb, float* __restrict__ xsum,
          const float* __restrict__ Alora, const float* __restrict__ Avera,
          const float* __restrict__ dvec, float* __restrict__ tmp,
          const int* __restrict__ nbp)
{
  const int row = blockIdx.x;
  const size_t base = (size_t)row * D_;
  float v0[3]; float s = 0.f, sq = 0.f;
  #pragma unroll
  for (int i = 0; i < 3; ++i) {
    const int d = threadIdx.x + i * 256;
    float val = x[base + d];
    if (ADD) { val += b2f(add[base + d]); xsum[base + d] = val; }
    v0[i] = val; s += val; sq += val * val;
  }
  #pragma unroll
  for (int mm = 32; mm >= 1; mm >>= 1) { s += __shfl_xor(s, mm); sq += __shfl_xor(sq, mm); }
  __shared__ float ss[4], s2[4];
  if ((threadIdx.x & 63) == 0) { ss[threadIdx.x >> 6] = s; s2[threadIdx.x >> 6] = sq; }
  __syncthreads();
  s  = ss[0] + ss[1] + ss[2] + ss[3];
  sq = s2[0] + s2[1] + s2[2] + s2[3];
  const float mean = s * (1.f / D_);
  const float var  = sq * (1.f / D_) - mean * mean;
  const float rs   = rsqrtf(var + 1e-6f);
  float nv[3];
  #pragma unroll
  for (int i = 0; i < 3; ++i) {
    const int d = threadIdx.x + i * 256;
    nv[i] = (v0[i] - mean) * rs * g[d] + beta[d];
    outb[base + d] = f2b(nv[i]);
  }

  if (ADD) {
    const int nb = *nbp;
    const bool ex = (row % S_) >= nb;
    const float* Am = ex ? Avera : Alora;
    float p[16];
    #pragma unroll
    for (int r = 0; r < 16; ++r) p[r] = 0.f;
    #pragma unroll
    for (int i = 0; i < 3; ++i) {
      const int d = threadIdx.x + i * 256;
      const float4* ap = (const float4*)(Am + (size_t)d * R_);
      const float4 a0 = ap[0], a1 = ap[1], a2 = ap[2], a3 = ap[3];
      const float vv = nv[i];
      p[0]  += vv * a0.x; p[1]  += vv * a0.y; p[2]  += vv * a0.z; p[3]  += vv * a0.w;
      p[4]  += vv * a1.x; p[5]  += vv * a1.y; p[6]  += vv * a1.z; p[7]  += vv * a1.w;
      p[8]  += vv * a2.x; p[9]  += vv * a2.y; p[10] += vv * a2.z; p[11] += vv * a2.w;
      p[12] += vv * a3.x; p[13] += vv * a3.y; p[14] += vv * a3.z; p[15] += vv * a3.w;
    }
    // reduce within 16-lane groups (4 butterfly steps), static indices only
    #pragma unroll
    for (int st = 1; st < 16; st <<= 1)
      #pragma unroll
      for (int r = 0; r < 16; ++r) p[r] += __shfl_xor(p[r], st);
    __shared__ float sred[16][16];
    const int grp = threadIdx.x >> 4;
    if ((threadIdx.x & 15) == 0) {
      #pragma unroll
      for (int r = 0; r < 16; ++r) sred[grp][r] = p[r];
    }
    __syncthreads();
    if (threadIdx.x < 16) {
      float v = 0.f;
      #pragma unroll
      for (int gg = 0; gg < 16; ++gg) v += sred[gg][threadIdx.x];
      if (ex) v *= dvec[threadIdx.x];
      tmp[(size_t)row * R_ + threadIdx.x] = v;
    }
  }
}

// ---------------- bf16 MFMA GEMM: C[M,N] = A[M,K] * W[N,K]^T + bias ----------------
__global__ __launch_bounds__(256)
void gemm_bt(const u16* __restrict__ A, const u16* __restrict__ W,
             const float* __restrict__ bias, u16* __restrict__ C,
             int M, int N, int K)
{
  __shared__ u16 As[128 * 32];
  __shared__ u16 Bs[128 * 32];
  const int tid   = threadIdx.x;
  const int lane  = tid & 63;
  const int wid   = tid >> 6;
  const int wr    = wid >> 1;
  const int wc    = wid & 1;
  const int lr    = lane & 15;
  const int lk    = (lane >> 4) << 3;
  const int m0    = blockIdx.x * 128;
  const int n0    = blockIdx.y * 128;
  const int kg    = (tid & 3) * 8;
  const int row_a = tid >> 2;

  fx4 acc[4][4];
  const fx4 zero = {0.f, 0.f, 0.f, 0.f};
  #pragma unroll
  for (int i = 0; i < 4; ++i)
    #pragma unroll
    for (int j = 0; j < 4; ++j) acc[i][j] = zero;

  for (int k0 = 0; k0 < K; k0 += 32) {
    #pragma unroll
    for (int u = 0; u < 2; ++u) {
      const int row = u * 64 + row_a;
      const int li  = u * 256 + tid;
      gload16(A + (size_t)(m0 + row) * K + k0 + kg, &As[li * 8]);
      gload16(W + (size_t)(n0 + row) * K + k0 + kg, &Bs[li * 8]);
    }
    __syncthreads();
    s16x8 av[4], bv[4];
    #pragma unroll
    for (int i = 0; i < 4; ++i)
      av[i] = *(const s16x8*)&As[(wr * 64 + i * 16 + lr) * 32 + lk];
    #pragma unroll
    for (int j = 0; j < 4; ++j)
      bv[j] = *(const s16x8*)&Bs[(wc * 64 + j * 16 + lr) * 32 + lk];
    #pragma unroll
    for (int i = 0; i < 4; ++i)
      #pragma unroll
      for (int j = 0; j < 4; ++j)
        acc[i][j] = __builtin_amdgcn_mfma_f32_16x16x32_bf16(av[i], bv[j], acc[i][j], 0, 0, 0);
    __syncthreads();
  }

  const int rb = (lane >> 4) * 4;
  #pragma unroll
  for (int j = 0; j < 4; ++j) {
    const int col = n0 + wc * 64 + j * 16 + lr;
    const float bj = bias ? bias[col] : 0.f;
    #pragma unroll
    for (int i = 0; i < 4; ++i) {
      const int row = m0 + wr * 64 + i * 16 + rb;
      #pragma unroll
      for (int r = 0; r < 4; ++r)
        C[(size_t)(row + r) * N + col] = f2b(acc[i][j][r] + bj);
    }
  }
}

// ---------------- MFMA flash attention ----------------
__global__ __launch_bounds__(256)
void attn_mfma(const u16* __restrict__ q, const u16* __restrict__ k,
               const u16* __restrict__ v, const float* __restrict__ mask,
               u16* __restrict__ o)
{
  __shared__ u16 Ql[64 * 64];
  __shared__ u16 Kl[64 * 64];
  __shared__ u16 Vt[64 * 64];
  __shared__ u16 Pl[4][16 * 64];

  const int tid  = threadIdx.x;
  const int lane = tid & 63;
  const int wq   = tid >> 6;
  const int lr   = lane & 15;
  const int hi   = lane >> 4;
  const int qb   = blockIdx.x;
  const int bh   = blockIdx.y;
  const int b    = bh / H_;
  const int h    = bh % H_;
  const size_t tok0 = (size_t)b * S_ + (size_t)qb * 64;
  const size_t colh = (size_t)h * HD_;

  #pragma unroll
  for (int u = 0; u < 2; ++u) {
    const int li = u * 256 + tid;
    const int r  = li >> 3;
    const int cb = ((li & 7) ^ (r & 7)) * 8;
    gload16(q + (tok0 + r) * D_ + colh + cb, &Ql[li * 8]);
  }
  __syncthreads();

  s16x8 qa[2];
  {
    const int qrow = wq * 16 + lr;
    #pragma unroll
    for (int ks = 0; ks < 2; ++ks)
      qa[ks] = *(const s16x8*)&Ql[qrow * 64 + ((ks * 32 + hi * 8) ^ ((qrow & 7) << 3))];
  }

  const fx4 zero = {0.f, 0.f, 0.f, 0.f};
  fx4 oacc[4];
  #pragma unroll
  for (int dj = 0; dj < 4; ++dj) oacc[dj] = zero;
  float mreg[4], lreg[4];
  #pragma unroll
  for (int r = 0; r < 4; ++r) { mreg[r] = -3.0e38f; lreg[r] = 0.f; }

  for (int kt = 0; kt < S_ / 64; ++kt) {
    const size_t ktok = (size_t)b * S_ + (size_t)kt * 64;
    __syncthreads();

    #pragma unroll
    for (int u = 0; u < 2; ++u) {
      const int li = u * 256 + tid;
      const int r  = li >> 3;
      const int cb = ((li & 7) ^ (r & 7)) * 8;
      gload16(k + (ktok + r) * D_ + colh + cb, &Kl[li * 8]);
    }
    {
      const int a  = tid >> 3;
      const int c8 = (tid & 7) * 8;
      const u16* vp = v + (ktok + 2 * a) * D_ + colh + c8;
      s16x8 v0 = *(const s16x8*)vp;
      s16x8 v1 = *(const s16x8*)(vp + D_);
      #pragma unroll
      for (int jj = 0; jj < 8; ++jj) {
        const int d  = c8 + jj;
        const int sw = ((d & 7) ^ ((d >> 3) & 7)) << 3;
        const int cp = (2 * a) ^ sw;
        *(uint32_t*)&Vt[d * 64 + cp] =
            (uint32_t)(u16)v0[jj] | ((uint32_t)(u16)v1[jj] << 16);
      }
    }
    __syncthreads();

    float mv[4][4];
    {
      const float* mp = mask + (size_t)(qb * 64 + wq * 16 + hi * 4) * S_ + (size_t)kt * 64 + lr;
      #pragma unroll
      for (int r = 0; r < 4; ++r)
        #pragma unroll
        for (int j = 0; j < 4; ++j)
          mv[j][r] = mp[(size_t)r * S_ + j * 16];
    }

    s16x8 kb2[4][2];
    #pragma unroll
    for (int j = 0; j < 4; ++j) {
      const int n = j * 16 + lr;
      #pragma unroll
      for (int ks = 0; ks < 2; ++ks)
        kb2[j][ks] = *(const s16x8*)&Kl[n * 64 + ((ks * 32 + hi * 8) ^ ((n & 7) << 3))];
    }
    fx4 sf[4];
    #pragma unroll
    for (int j = 0; j < 4; ++j) sf[j] = zero;
    #pragma unroll
    for (int ks = 0; ks < 2; ++ks)
      #pragma unroll
      for (int j = 0; j < 4; ++j)
        sf[j] = __builtin_amdgcn_mfma_f32_16x16x32_bf16(qa[ks], kb2[j][ks], sf[j], 0, 0, 0);

    float val[4][4];
    #pragma unroll
    for (int j = 0; j < 4; ++j)
      #pragma unroll
      for (int r = 0; r < 4; ++r)
        val[j][r] = sf[j][r] * 0.125f + mv[j][r];
    #pragma unroll
    for (int r = 0; r < 4; ++r) {
      float mx = fmaxf(fmaxf(val[0][r], val[1][r]), fmaxf(val[2][r], val[3][r]));
      mx = fmaxf(mx, __shfl_xor(mx, 1));
      mx = fmaxf(mx, __shfl_xor(mx, 2));
      mx = fmaxf(mx, __shfl_xor(mx, 4));
      mx = fmaxf(mx, __shfl_xor(mx, 8));
      const float mn  = fmaxf(mreg[r], mx);
      const float fac = __expf(mreg[r] - mn);
      mreg[r] = mn;
      float rs = 0.f;
      #pragma unroll
      for (int j = 0; j < 4; ++j) {
        const float p = __expf(val[j][r] - mn);
        val[j][r] = p;
        rs += p;
      }
      rs += __shfl_xor(rs, 1); rs += __shfl_xor(rs, 2);
      rs += __shfl_xor(rs, 4); rs += __shfl_xor(rs, 8);
      lreg[r] = lreg[r] * fac + rs;
      #pragma unroll
      for (int dj = 0; dj < 4; ++dj) oacc[dj][r] *= fac;
    }

    #pragma unroll
    for (int j = 0; j < 4; ++j) {
      const int col = j * 16 + lr;
      #pragma unroll
      for (int r = 0; r < 4; ++r) {
        const int row = hi * 4 + r;
        Pl[wq][row * 64 + (col ^ ((row & 7) << 3))] = f2b(val[j][r]);
      }
    }
    s16x8 pa[2];
    #pragma unroll
    for (int ks = 0; ks < 2; ++ks)
      pa[ks] = *(const s16x8*)&Pl[wq][lr * 64 + ((ks * 32 + hi * 8) ^ ((lr & 7) << 3))];

    s16x8 bv2[4][2];
    #pragma unroll
    for (int dj = 0; dj < 4; ++dj) {
      const int n  = dj * 16 + lr;
      const int sw = ((n & 7) ^ ((n >> 3) & 7)) << 3;
      #pragma unroll
      for (int ks = 0; ks < 2; ++ks)
        bv2[dj][ks] = *(const s16x8*)&Vt[n * 64 + ((ks * 32 + hi * 8) ^ sw)];
    }
    #pragma unroll
    for (int ks = 0; ks < 2; ++ks)
      #pragma unroll
      for (int dj = 0; dj < 4; ++dj)
        oacc[dj] = __builtin_amdgcn_mfma_f32_16x16x32_bf16(pa[ks], bv2[dj][ks], oacc[dj], 0, 0, 0);
  }

  #pragma unroll
  for (int r = 0; r < 4; ++r) {
    const float inv = 1.f / lreg[r];
    const size_t grow = (tok0 + wq * 16 + hi * 4 + r) * D_ + colh;
    #pragma unroll
    for (int dj = 0; dj < 4; ++dj)
      o[grow + dj * 16 + lr] = f2b(oacc[dj][r] * inv);
  }
}

// ---------------- fc1 epilogue: hid = gelu(fc1out + adapter1_up); tmp2 = gelu(hid) @ A2 ----------------
__global__ __launch_bounds__(256)
void mlp_epi1(u16* __restrict__ hid, const float* __restrict__ tmp,
              const float* __restrict__ Blora, const float* __restrict__ Bvera,
              const float* __restrict__ evec,
              const float* __restrict__ A2lora, const float* __restrict__ A2vera,
              const float* __restrict__ d2vec, float* __restrict__ tmp2,
              const int* __restrict__ nbp)
{
  const int nb = *nbp;
  const int m = blockIdx.x;
  const bool ex = ((m % S_) >= nb);
  __shared__ float t[R_];
  if (threadIdx.x < R_) t[threadIdx.x] = tmp[m * R_ + threadIdx.x];
  __syncthreads();
  float tr[16];
  #pragma unroll
  for (int r = 0; r < 16; ++r) tr[r] = t[r];
  const float* Bm  = ex ? Bvera : Blora;
  const float* Am2 = ex ? A2vera : A2lora;

  float p[16];
  #pragma unroll
  for (int r = 0; r < 16; ++r) p[r] = 0.f;

  #pragma unroll
  for (int it = 0; it < FF_ / 256; ++it) {
    const int f = it * 256 + threadIdx.x;
    float ad = 0.f;
    #pragma unroll
    for (int r = 0; r < R_; ++r) ad += tr[r] * Bm[(size_t)r * FF_ + f];
    if (ex) ad *= evec[f];
    const size_t idx = (size_t)m * FF_ + f;
    const float pre = b2f(hid[idx]) + ad;
    const float gl  = gelu_f(pre);
    hid[idx] = f2b(gl);
    const float4* ap = (const float4*)(Am2 + (size_t)f * R_);
    const float4 a0 = ap[0], a1 = ap[1], a2 = ap[2], a3 = ap[3];
    p[0]  += gl * a0.x; p[1]  += gl * a0.y; p[2]  += gl * a0.z; p[3]  += gl * a0.w;
    p[4]  += gl * a1.x; p[5]  += gl * a1.y; p[6]  += gl * a1.z; p[7]  += gl * a1.w;
    p[8]  += gl * a2.x; p[9]  += gl * a2.y; p[10] += gl * a2.z; p[11] += gl * a2.w;
    p[12] += gl * a3.x; p[13] += gl * a3.y; p[14] += gl * a3.z; p[15] += gl * a3.w;
  }

  #pragma unroll
  for (int st = 1; st < 16; st <<= 1)
    #pragma unroll
    for (int r = 0; r < 16; ++r) p[r] += __shfl_xor(p[r], st);
  __shared__ float sred[16][16];
  const int grp = threadIdx.x >> 4;
  if ((threadIdx.x & 15) == 0) {
    #pragma unroll
    for (int r = 0; r < 16; ++r) sred[grp][r] = p[r];
  }
  __syncthreads();
  if (threadIdx.x < 16) {
    float v = 0.f;
    #pragma unroll
    for (int gg = 0; gg < 16; ++gg) v += sred[gg][threadIdx.x];
    if (ex) v *= d2vec[threadIdx.x];
    tmp2[(size_t)m * R_ + threadIdx.x] = v;
  }
}

// ---------------- final: d_out = x1 + fc2out + adapter2_up ----------------
__global__ __launch_bounds__(256)
void final_add(float* __restrict__ out, const u16* __restrict__ fc2o,
               const float* __restrict__ tmp, const float* __restrict__ Blora,
               const float* __restrict__ Bvera, const float* __restrict__ evec,
               const int* __restrict__ nbp)
{
  const int nb = *nbp;
  const int m = blockIdx.x;
  const bool ex = ((m % S_) >= nb);
  __shared__ float t[R_];
  if (threadIdx.x < R_) t[threadIdx.x] = tmp[m * R_ + threadIdx.x];
  __syncthreads();
  const float* Bm = ex ? Bvera : Blora;
  for (int d = threadIdx.x; d < D_; d += 256) {
    float ad = 0.f;
    #pragma unroll
    for (int r = 0; r < R_; ++r) ad += t[r] * Bm[(size_t)r * D_ + d];
    if (ex) ad *= evec[d];
    const size_t idx = (size_t)m * D_ + d;
    out[idx] += b2f(fc2o[idx]) + ad;
  }
}

extern "C" void kernel_launch(void* const* d_in, const int* in_sizes, int n_in,
                              void* d_out, int out_size, void* d_ws, size_t ws_size,
                              hipStream_t stream)
{
  const float* x      = (const float*)d_in[0];
  const float* mask   = (const float*)d_in[1];
  const float* n1g    = (const float*)d_in[2];
  const float* n1b    = (const float*)d_in[3];
  const float* q_w    = (const float*)d_in[4];
  const float* q_bv   = (const float*)d_in[5];
  const float* k_w    = (const float*)d_in[6];
  const float* k_bv   = (const float*)d_in[7];
  const float* v_w    = (const float*)d_in[8];
  const float* v_bv   = (const float*)d_in[9];
  const float* o_w    = (const float*)d_in[10];
  const float* o_bv   = (const float*)d_in[11];
  const float* n2g    = (const float*)d_in[12];
  const float* n2b    = (const float*)d_in[13];
  const float* fc1_w  = (const float*)d_in[14];
  const float* fc1_bv = (const float*)d_in[15];
  const float* fc2_w  = (const float*)d_in[16];
  const float* fc2_bv = (const float*)d_in[17];
  const float* lora1A = (const float*)d_in[18];
  const float* lora1B = (const float*)d_in[19];
  const float* lora2A = (const float*)d_in[20];
  const float* lora2B = (const float*)d_in[21];
  const float* vera1A = (const float*)d_in[22];
  const float* vera1B = (const float*)d_in[23];
  const float* vera2A = (const float*)d_in[24];
  const float* vera2B = (const float*)d_in[25];
  const float* e1d    = (const float*)d_in[26];
  const float* e1b    = (const float*)d_in[27];
  const float* e2d    = (const float*)d_in[28];
  const float* e2b    = (const float*)d_in[29];
  const int*   nbp    = (const int*)d_in[30];

  char* wsb = (char*)d_ws;
  u16* h1    = (u16*)wsb; wsb += (size_t)M_ * D_ * 2;
  u16* qb_   = (u16*)wsb; wsb += (size_t)M_ * D_ * 2;
  u16* kb_   = (u16*)wsb; wsb += (size_t)M_ * D_ * 2;
  u16* vb_   = (u16*)wsb; wsb += (size_t)M_ * D_ * 2;
  u16* attno = (u16*)wsb; wsb += (size_t)M_ * D_ * 2;
  u16* oproj = (u16*)wsb; wsb += (size_t)M_ * D_ * 2;
  u16* n2    = (u16*)wsb; wsb += (size_t)M_ * D_ * 2;
  u16* fc2o  = (u16*)wsb; wsb += (size_t)M_ * D_ * 2;
  u16* wq    = (u16*)wsb; wsb += (size_t)D_ * D_ * 2;
  u16* wk    = (u16*)wsb; wsb += (size_t)D_ * D_ * 2;
  u16* wv    = (u16*)wsb; wsb += (size_t)D_ * D_ * 2;
  u16* wo    = (u16*)wsb; wsb += (size_t)D_ * D_ * 2;
  u16* wfc1  = (u16*)wsb; wsb += (size_t)FF_ * D_ * 2;
  u16* wfc2  = (u16*)wsb; wsb += (size_t)D_ * FF_ * 2;
  float* tmp1 = (float*)wsb; wsb += (size_t)M_ * R_ * 4;
  float* tmp2 = (float*)wsb; wsb += (size_t)M_ * R_ * 4;
  u16* hidb = h1;   // [M,FF] reuses h1/q/k/v region (4*M*D == M*FF), dead by then

  cvt_f2b<<<(D_*D_/4 + 255)/256, 256, 0, stream>>>(q_w,   wq,   D_*D_/4);
  cvt_f2b<<<(D_*D_/4 + 255)/256, 256, 0, stream>>>(k_w,   wk,   D_*D_/4);
  cvt_f2b<<<(D_*D_/4 + 255)/256, 256, 0, stream>>>(v_w,   wv,   D_*D_/4);
  cvt_f2b<<<(D_*D_/4 + 255)/256, 256, 0, stream>>>(o_w,   wo,   D_*D_/4);
  cvt_f2b<<<(FF_*D_/4 + 255)/256, 256, 0, stream>>>(fc1_w, wfc1, FF_*D_/4);
  cvt_f2b<<<(D_*FF_/4 + 255)/256, 256, 0, stream>>>(fc2_w, wfc2, D_*FF_/4);

  ln_k<false><<<M_, 256, 0, stream>>>(x, nullptr, n1g, n1b, h1, nullptr,
                                      nullptr, nullptr, nullptr, nullptr, nullptr);
  dim3 g768(M_/128, D_/128);
  gemm_bt<<<g768, 256, 0, stream>>>(h1, wq, q_bv, qb_, M_, D_, D_);
  gemm_bt<<<g768, 256, 0, stream>>>(h1, wk, k_bv, kb_, M_, D_, D_);
  gemm_bt<<<g768, 256, 0, stream>>>(h1, wv, v_bv, vb_, M_, D_, D_);
  attn_mfma<<<dim3(S_/64, B_*H_), 256, 0, stream>>>(qb_, kb_, vb_, mask, attno);
  gemm_bt<<<g768, 256, 0, stream>>>(attno, wo, o_bv, oproj, M_, D_, D_);

  // x1 = x + attn_proj (into d_out), n2 = LN(x1), tmp1 = n2 @ A1 (fused)
  ln_k<true><<<M_, 256, 0, stream>>>(x, oproj, n2g, n2b, n2, (float*)d_out,
                                     lora1A, vera1A, e1d, tmp1, nbp);

  gemm_bt<<<dim3(M_/128, FF_/128), 256, 0, stream>>>(n2, wfc1, fc1_bv, hidb, M_, FF_, D_);
  mlp_epi1<<<M_, 256, 0, stream>>>(hidb, tmp1, lora1B, vera1B, e1b,
                                   lora2A, vera2A, e2d, tmp2, nbp);
  gemm_bt<<<g768, 256, 0, stream>>>(hidb, wfc2, fc2_bv, fc2o, M_, D_, FF_);
  final_add<<<M_, 256, 0, stream>>>((float*)d_out, fc2o, tmp2, lora2B, vera2B, e2b, nbp);
}

// Round 4
// 403.496 us; speedup vs baseline: 3.7330x; 1.5520x over previous
//
#include <hip/hip_runtime.h>
#include <stdint.h>

#define B_  8
#define S_  1024
#define D_  768
#define H_  12
#define HD_ 64
#define FF_ 3072
#define M_  (B_*S_)   // 8192 tokens
#define R_  16
#define QLD 2304      // packed QKV row stride

typedef unsigned short u16;
typedef short s16x8 __attribute__((ext_vector_type(8)));   // 8 bf16 (4 VGPRs)
typedef float fx4  __attribute__((ext_vector_type(4)));    // 4 fp32 acc

__device__ __forceinline__ float b2f(u16 u) {
  union { unsigned int i; float f; } c; c.i = ((unsigned int)u) << 16; return c.f;
}
__device__ __forceinline__ u16 f2b(float f) {   // RNE f32->bf16
  union { float f; unsigned int i; } c; c.f = f;
  unsigned int x = c.i;
  x += 0x7FFFu + ((x >> 16) & 1u);
  return (u16)(x >> 16);
}
__device__ __forceinline__ float gelu_f(float x) {  // jax.nn.gelu approximate=True (tanh)
  float u = 0.7978845608028654f * (x + 0.044715f * x * x * x);
  float e = __expf(2.f * u);
  float t = 1.f - 2.f / (e + 1.f);
  return 0.5f * x * (1.f + t);
}
__device__ __forceinline__ void gload16(const u16* gsrc, u16* ldst) {
  __builtin_amdgcn_global_load_lds(
      (__attribute__((address_space(1))) void*)(gsrc),
      (__attribute__((address_space(3))) void*)(ldst), 16, 0, 0);
}

// ---------------- f32 -> bf16 conversion ----------------
__global__ __launch_bounds__(256)
void cvt_f2b(const float* __restrict__ in, u16* __restrict__ out, int n4) {
  const int i = blockIdx.x * 256 + threadIdx.x;
  if (i < n4) {
    const float4 f = ((const float4*)in)[i];
    ushort4 o4; o4.x = f2b(f.x); o4.y = f2b(f.y); o4.z = f2b(f.z); o4.w = f2b(f.w);
    ((ushort4*)out)[i] = o4;
  }
}

// ---------------- small prep kernels (run every launch; all < 5 us) ----------------
__global__ __launch_bounds__(256)
void prep_qkvb(const float* qb, const float* kb, const float* vb, float* out) {
  const int i = blockIdx.x * 256 + threadIdx.x;
  if (i < QLD) out[i] = (i < D_) ? qb[i] : (i < 2 * D_) ? kb[i - D_] : vb[i - 2 * D_];
}
// Bup[n][32] bf16: col-major-transposed adapter-up weight, vera pre-scaled by evec
__global__ __launch_bounds__(256)
void prep_up(const float* __restrict__ Blora, const float* __restrict__ Bvera,
             const float* __restrict__ evec, u16* __restrict__ upL,
             u16* __restrict__ upV, int N) {
  const int f = blockIdx.x * 256 + threadIdx.x;
  if (f >= N) return;
  const float ev = evec[f];
  #pragma unroll
  for (int r = 0; r < 16; ++r) {
    upL[(size_t)f * 32 + r] = f2b(Blora[(size_t)r * N + f]);
    upV[(size_t)f * 32 + r] = f2b(Bvera[(size_t)r * N + f] * ev);
    upL[(size_t)f * 32 + 16 + r] = 0;
    upV[(size_t)f * 32 + 16 + r] = 0;
  }
}
// A2t[r][FF] bf16 = transpose of A2[FF][16]
__global__ __launch_bounds__(256)
void prep_a2t(const float* __restrict__ Alora, const float* __restrict__ Avera,
              u16* __restrict__ tL, u16* __restrict__ tV) {
  const int f = blockIdx.x * 256 + threadIdx.x;
  if (f >= FF_) return;
  const float4* apl = (const float4*)(Alora + (size_t)f * 16);
  const float4* apv = (const float4*)(Avera + (size_t)f * 16);
  #pragma unroll
  for (int q4 = 0; q4 < 4; ++q4) {
    const float4 l4 = apl[q4], v4 = apv[q4];
    tL[(size_t)(q4 * 4 + 0) * FF_ + f] = f2b(l4.x);
    tL[(size_t)(q4 * 4 + 1) * FF_ + f] = f2b(l4.y);
    tL[(size_t)(q4 * 4 + 2) * FF_ + f] = f2b(l4.z);
    tL[(size_t)(q4 * 4 + 3) * FF_ + f] = f2b(l4.w);
    tV[(size_t)(q4 * 4 + 0) * FF_ + f] = f2b(v4.x);
    tV[(size_t)(q4 * 4 + 1) * FF_ + f] = f2b(v4.y);
    tV[(size_t)(q4 * 4 + 2) * FF_ + f] = f2b(v4.z);
    tV[(size_t)(q4 * 4 + 3) * FF_ + f] = f2b(v4.w);
  }
}

// ---------------- LayerNorm (+residual add, + fused rank-16 down-projection) ----------------
template<bool ADD>
__global__ __launch_bounds__(256)
void ln_k(const float* __restrict__ x, const u16* __restrict__ add,
          const float* __restrict__ g, const float* __restrict__ beta,
          u16* __restrict__ outb, float* __restrict__ xsum,
          const float* __restrict__ Alora, const float* __restrict__ Avera,
          const float* __restrict__ dvec, u16* __restrict__ tmp1b,
          const int* __restrict__ nbp)
{
  const int row = blockIdx.x;
  const size_t base = (size_t)row * D_;
  float v0[3]; float s = 0.f, sq = 0.f;
  #pragma unroll
  for (int i = 0; i < 3; ++i) {
    const int d = threadIdx.x + i * 256;
    float val = x[base + d];
    if (ADD) { val += b2f(add[base + d]); xsum[base + d] = val; }
    v0[i] = val; s += val; sq += val * val;
  }
  #pragma unroll
  for (int mm = 32; mm >= 1; mm >>= 1) { s += __shfl_xor(s, mm); sq += __shfl_xor(sq, mm); }
  __shared__ float ss[4], s2[4];
  if ((threadIdx.x & 63) == 0) { ss[threadIdx.x >> 6] = s; s2[threadIdx.x >> 6] = sq; }
  __syncthreads();
  s  = ss[0] + ss[1] + ss[2] + ss[3];
  sq = s2[0] + s2[1] + s2[2] + s2[3];
  const float mean = s * (1.f / D_);
  const float var  = sq * (1.f / D_) - mean * mean;
  const float rs   = rsqrtf(var + 1e-6f);
  float nv[3];
  #pragma unroll
  for (int i = 0; i < 3; ++i) {
    const int d = threadIdx.x + i * 256;
    nv[i] = (v0[i] - mean) * rs * g[d] + beta[d];
    outb[base + d] = f2b(nv[i]);
  }

  if (ADD) {
    const int nb = *nbp;
    const bool ex = (row % S_) >= nb;
    const float* Am = ex ? Avera : Alora;
    float p[16];
    #pragma unroll
    for (int r = 0; r < 16; ++r) p[r] = 0.f;
    #pragma unroll
    for (int i = 0; i < 3; ++i) {
      const int d = threadIdx.x + i * 256;
      const float4* ap = (const float4*)(Am + (size_t)d * R_);
      const float4 a0 = ap[0], a1 = ap[1], a2 = ap[2], a3 = ap[3];
      const float vv = nv[i];
      p[0]  += vv * a0.x; p[1]  += vv * a0.y; p[2]  += vv * a0.z; p[3]  += vv * a0.w;
      p[4]  += vv * a1.x; p[5]  += vv * a1.y; p[6]  += vv * a1.z; p[7]  += vv * a1.w;
      p[8]  += vv * a2.x; p[9]  += vv * a2.y; p[10] += vv * a2.z; p[11] += vv * a2.w;
      p[12] += vv * a3.x; p[13] += vv * a3.y; p[14] += vv * a3.z; p[15] += vv * a3.w;
    }
    #pragma unroll
    for (int st = 1; st < 16; st <<= 1)
      #pragma unroll
      for (int r = 0; r < 16; ++r) p[r] += __shfl_xor(p[r], st);
    __shared__ float sred[16][16];
    const int grp = threadIdx.x >> 4;
    if ((threadIdx.x & 15) == 0) {
      #pragma unroll
      for (int r = 0; r < 16; ++r) sred[grp][r] = p[r];
    }
    __syncthreads();
    if (threadIdx.x < 16) {
      float v = 0.f;
      #pragma unroll
      for (int gg = 0; gg < 16; ++gg) v += sred[gg][threadIdx.x];
      if (ex) v *= dvec[threadIdx.x];
      tmp1b[(size_t)row * 32 + threadIdx.x] = f2b(v);
      tmp1b[(size_t)row * 32 + 16 + threadIdx.x] = 0;
    }
  }
}

// ---------------- bf16 MFMA GEMM: C = A[M,K] * W[N,K]^T + bias (+adapter kstep, epilogues) ----------------
// MODE 0: plain -> bf16 Cb.  MODE 1: +adapter kstep, gelu -> bf16 Cb.
// MODE 2: +adapter kstep, out_f32 = resid + acc + bias -> Cf.
template<int MODE>
__global__ __launch_bounds__(256)
void gemm_bt(const u16* __restrict__ A, const u16* __restrict__ W,
             const float* __restrict__ bias, u16* __restrict__ Cb,
             float* __restrict__ Cf, const float* __restrict__ resid,
             const u16* __restrict__ Aad, const u16* __restrict__ BadL,
             const u16* __restrict__ BadV, const int* __restrict__ nbp,
             int M, int N, int K)
{
  __shared__ u16 As[128 * 32];
  __shared__ u16 Bs[128 * 32];
  const int tid   = threadIdx.x;
  const int lane  = tid & 63;
  const int wid   = tid >> 6;
  const int wr    = wid >> 1;
  const int wc    = wid & 1;
  const int lr    = lane & 15;
  const int lk    = (lane >> 4) << 3;
  const int m0    = blockIdx.x * 128;
  const int n0    = blockIdx.y * 128;
  const int kg    = (tid & 3) * 8;
  const int row_a = tid >> 2;

  fx4 acc[4][4];
  const fx4 zero = {0.f, 0.f, 0.f, 0.f};
  #pragma unroll
  for (int i = 0; i < 4; ++i)
    #pragma unroll
    for (int j = 0; j < 4; ++j) acc[i][j] = zero;

  for (int k0 = 0; k0 < K; k0 += 32) {
    #pragma unroll
    for (int u = 0; u < 2; ++u) {
      const int row = u * 64 + row_a;
      const int li  = u * 256 + tid;
      gload16(A + (size_t)(m0 + row) * K + k0 + kg, &As[li * 8]);
      gload16(W + (size_t)(n0 + row) * K + k0 + kg, &Bs[li * 8]);
    }
    __syncthreads();
    s16x8 av[4], bv[4];
    #pragma unroll
    for (int i = 0; i < 4; ++i)
      av[i] = *(const s16x8*)&As[(wr * 64 + i * 16 + lr) * 32 + lk];
    #pragma unroll
    for (int j = 0; j < 4; ++j)
      bv[j] = *(const s16x8*)&Bs[(wc * 64 + j * 16 + lr) * 32 + lk];
    #pragma unroll
    for (int i = 0; i < 4; ++i)
      #pragma unroll
      for (int j = 0; j < 4; ++j)
        acc[i][j] = __builtin_amdgcn_mfma_f32_16x16x32_bf16(av[i], bv[j], acc[i][j], 0, 0, 0);
    __syncthreads();
  }

  if (MODE >= 1) {
    // one extra K=32 k-step: adapter-up (tmp1b zero-padded [M,32] @ Bup[N,32]^T)
    // NOTE: assumes nb is a multiple of 128 so each M-tile is uniformly lora/vera.
    const int nb = *nbp;
    const u16* Bad = ((m0 % S_) >= nb) ? BadV : BadL;
    #pragma unroll
    for (int u = 0; u < 2; ++u) {
      const int row = u * 64 + row_a;
      const int li  = u * 256 + tid;
      gload16(Aad + (size_t)(m0 + row) * 32 + kg, &As[li * 8]);
      gload16(Bad + (size_t)(n0 + row) * 32 + kg, &Bs[li * 8]);
    }
    __syncthreads();
    s16x8 av[4], bv[4];
    #pragma unroll
    for (int i = 0; i < 4; ++i)
      av[i] = *(const s16x8*)&As[(wr * 64 + i * 16 + lr) * 32 + lk];
    #pragma unroll
    for (int j = 0; j < 4; ++j)
      bv[j] = *(const s16x8*)&Bs[(wc * 64 + j * 16 + lr) * 32 + lk];
    #pragma unroll
    for (int i = 0; i < 4; ++i)
      #pragma unroll
      for (int j = 0; j < 4; ++j)
        acc[i][j] = __builtin_amdgcn_mfma_f32_16x16x32_bf16(av[i], bv[j], acc[i][j], 0, 0, 0);
    __syncthreads();
  }

  const int rb = (lane >> 4) * 4;
  #pragma unroll
  for (int j = 0; j < 4; ++j) {
    const int col = n0 + wc * 64 + j * 16 + lr;
    const float bj = bias ? bias[col] : 0.f;
    #pragma unroll
    for (int i = 0; i < 4; ++i) {
      const int row = m0 + wr * 64 + i * 16 + rb;
      #pragma unroll
      for (int r = 0; r < 4; ++r) {
        const float val = acc[i][j][r] + bj;
        const size_t idx = (size_t)(row + r) * N + col;
        if (MODE == 1)      Cb[idx] = f2b(gelu_f(val));
        else if (MODE == 2) Cf[idx] = resid[idx] + val;
        else                Cb[idx] = f2b(val);
      }
    }
  }
}

// ---------------- skinny down-projection: part[ks][M][16] = hid_kslice @ A2t^T ----------------
// grid (M/128, 8); block 256 = 4 waves, wave w owns 32 rows.
__global__ __launch_bounds__(256)
void downproj(const u16* __restrict__ hid, const u16* __restrict__ A2tL,
              const u16* __restrict__ A2tV, float* __restrict__ part,
              const int* __restrict__ nbp)
{
  __shared__ u16 As[128 * 32];
  __shared__ u16 Bs[16 * 32];
  const int tid  = threadIdx.x;
  const int lane = tid & 63;
  const int w    = tid >> 6;
  const int lr   = lane & 15;
  const int lk   = (lane >> 4) << 3;
  const int m0   = blockIdx.x * 128;
  const int kb   = blockIdx.y * (FF_ / 8);
  const int nb   = *nbp;
  const u16* A2t = ((m0 % S_) >= nb) ? A2tV : A2tL;
  const int kg    = (tid & 3) * 8;
  const int row_a = tid >> 2;

  const fx4 zero = {0.f, 0.f, 0.f, 0.f};
  fx4 acc[2]; acc[0] = zero; acc[1] = zero;

  for (int k0 = kb; k0 < kb + FF_ / 8; k0 += 32) {
    #pragma unroll
    for (int u = 0; u < 2; ++u)
      gload16(hid + (size_t)(m0 + u * 64 + row_a) * FF_ + k0 + kg,
              &As[(u * 256 + tid) * 8]);
    if (tid < 64)
      gload16(A2t + (size_t)(tid >> 2) * FF_ + k0 + kg, &Bs[tid * 8]);
    __syncthreads();
    s16x8 bv = *(const s16x8*)&Bs[lr * 32 + lk];
    #pragma unroll
    for (int i = 0; i < 2; ++i) {
      s16x8 av = *(const s16x8*)&As[(w * 32 + i * 16 + lr) * 32 + lk];
      acc[i] = __builtin_amdgcn_mfma_f32_16x16x32_bf16(av, bv, acc[i], 0, 0, 0);
    }
    __syncthreads();
  }

  const int rb = (lane >> 4) * 4;
  #pragma unroll
  for (int i = 0; i < 2; ++i)
    #pragma unroll
    for (int r = 0; r < 4; ++r)
      part[(size_t)blockIdx.y * M_ * 16 +
           (size_t)(m0 + w * 32 + i * 16 + rb + r) * 16 + lr] = acc[i][r];
}

// ---------------- reduce partials -> tmp2b bf16 [M,32] (x d2 for expert rows) ----------------
__global__ __launch_bounds__(256)
void reduce_dp(const float* __restrict__ part, const float* __restrict__ d2,
               u16* __restrict__ tmp2b, const int* __restrict__ nbp)
{
  const int idx = blockIdx.x * 256 + threadIdx.x;   // m*16 + r
  const int m = idx >> 4, r = idx & 15;
  const int nb = *nbp;
  float s = 0.f;
  #pragma unroll
  for (int ks = 0; ks < 8; ++ks) s += part[(size_t)ks * M_ * 16 + idx];
  if ((m % S_) >= nb) s *= d2[r];
  tmp2b[(size_t)m * 32 + r] = f2b(s);
  tmp2b[(size_t)m * 32 + 16 + r] = 0;
}

// ---------------- MFMA flash attention (packed QKV, row stride 2304) ----------------
__global__ __launch_bounds__(256)
void attn_mfma(const u16* __restrict__ qkv, const float* __restrict__ mask,
               u16* __restrict__ o)
{
  __shared__ u16 Ql[64 * 64];
  __shared__ u16 Kl[64 * 64];
  __shared__ u16 Vt[64 * 64];
  __shared__ u16 Pl[4][16 * 64];

  const int tid  = threadIdx.x;
  const int lane = tid & 63;
  const int wq   = tid >> 6;
  const int lr   = lane & 15;
  const int hi   = lane >> 4;
  const int qb   = blockIdx.x;
  const int bh   = blockIdx.y;
  const int b    = bh / H_;
  const int h    = bh % H_;
  const size_t tok0 = (size_t)b * S_ + (size_t)qb * 64;
  const size_t colh = (size_t)h * HD_;

  #pragma unroll
  for (int u = 0; u < 2; ++u) {
    const int li = u * 256 + tid;
    const int r  = li >> 3;
    const int cb = ((li & 7) ^ (r & 7)) * 8;
    gload16(qkv + (tok0 + r) * QLD + colh + cb, &Ql[li * 8]);
  }
  __syncthreads();

  s16x8 qa[2];
  {
    const int qrow = wq * 16 + lr;
    #pragma unroll
    for (int ks = 0; ks < 2; ++ks)
      qa[ks] = *(const s16x8*)&Ql[qrow * 64 + ((ks * 32 + hi * 8) ^ ((qrow & 7) << 3))];
  }

  const fx4 zero = {0.f, 0.f, 0.f, 0.f};
  fx4 oacc[4];
  #pragma unroll
  for (int dj = 0; dj < 4; ++dj) oacc[dj] = zero;
  float mreg[4], lreg[4];
  #pragma unroll
  for (int r = 0; r < 4; ++r) { mreg[r] = -3.0e38f; lreg[r] = 0.f; }

  for (int kt = 0; kt < S_ / 64; ++kt) {
    const size_t ktok = (size_t)b * S_ + (size_t)kt * 64;
    __syncthreads();

    #pragma unroll
    for (int u = 0; u < 2; ++u) {
      const int li = u * 256 + tid;
      const int r  = li >> 3;
      const int cb = ((li & 7) ^ (r & 7)) * 8;
      gload16(qkv + (ktok + r) * QLD + D_ + colh + cb, &Kl[li * 8]);
    }
    {
      const int a  = tid >> 3;
      const int c8 = (tid & 7) * 8;
      const u16* vp = qkv + (ktok + 2 * a) * QLD + 2 * D_ + colh + c8;
      s16x8 v0 = *(const s16x8*)vp;
      s16x8 v1 = *(const s16x8*)(vp + QLD);
      #pragma unroll
      for (int jj = 0; jj < 8; ++jj) {
        const int d  = c8 + jj;
        const int sw = ((d & 7) ^ ((d >> 3) & 7)) << 3;
        const int cp = (2 * a) ^ sw;
        *(uint32_t*)&Vt[d * 64 + cp] =
            (uint32_t)(u16)v0[jj] | ((uint32_t)(u16)v1[jj] << 16);
      }
    }
    __syncthreads();

    float mv[4][4];
    {
      const float* mp = mask + (size_t)(qb * 64 + wq * 16 + hi * 4) * S_ + (size_t)kt * 64 + lr;
      #pragma unroll
      for (int r = 0; r < 4; ++r)
        #pragma unroll
        for (int j = 0; j < 4; ++j)
          mv[j][r] = mp[(size_t)r * S_ + j * 16];
    }

    s16x8 kb2[4][2];
    #pragma unroll
    for (int j = 0; j < 4; ++j) {
      const int n = j * 16 + lr;
      #pragma unroll
      for (int ks = 0; ks < 2; ++ks)
        kb2[j][ks] = *(const s16x8*)&Kl[n * 64 + ((ks * 32 + hi * 8) ^ ((n & 7) << 3))];
    }
    fx4 sf[4];
    #pragma unroll
    for (int j = 0; j < 4; ++j) sf[j] = zero;
    #pragma unroll
    for (int ks = 0; ks < 2; ++ks)
      #pragma unroll
      for (int j = 0; j < 4; ++j)
        sf[j] = __builtin_amdgcn_mfma_f32_16x16x32_bf16(qa[ks], kb2[j][ks], sf[j], 0, 0, 0);

    float val[4][4];
    #pragma unroll
    for (int j = 0; j < 4; ++j)
      #pragma unroll
      for (int r = 0; r < 4; ++r)
        val[j][r] = sf[j][r] * 0.125f + mv[j][r];
    #pragma unroll
    for (int r = 0; r < 4; ++r) {
      float mx = fmaxf(fmaxf(val[0][r], val[1][r]), fmaxf(val[2][r], val[3][r]));
      mx = fmaxf(mx, __shfl_xor(mx, 1));
      mx = fmaxf(mx, __shfl_xor(mx, 2));
      mx = fmaxf(mx, __shfl_xor(mx, 4));
      mx = fmaxf(mx, __shfl_xor(mx, 8));
      const float mn  = fmaxf(mreg[r], mx);
      const float fac = __expf(mreg[r] - mn);
      mreg[r] = mn;
      float rs = 0.f;
      #pragma unroll
      for (int j = 0; j < 4; ++j) {
        const float p = __expf(val[j][r] - mn);
        val[j][r] = p;
        rs += p;
      }
      rs += __shfl_xor(rs, 1); rs += __shfl_xor(rs, 2);
      rs += __shfl_xor(rs, 4); rs += __shfl_xor(rs, 8);
      lreg[r] = lreg[r] * fac + rs;
      #pragma unroll
      for (int dj = 0; dj < 4; ++dj) oacc[dj][r] *= fac;
    }

    #pragma unroll
    for (int j = 0; j < 4; ++j) {
      const int col = j * 16 + lr;
      #pragma unroll
      for (int r = 0; r < 4; ++r) {
        const int row = hi * 4 + r;
        Pl[wq][row * 64 + (col ^ ((row & 7) << 3))] = f2b(val[j][r]);
      }
    }
    s16x8 pa[2];
    #pragma unroll
    for (int ks = 0; ks < 2; ++ks)
      pa[ks] = *(const s16x8*)&Pl[wq][lr * 64 + ((ks * 32 + hi * 8) ^ ((lr & 7) << 3))];

    s16x8 bv2[4][2];
    #pragma unroll
    for (int dj = 0; dj < 4; ++dj) {
      const int n  = dj * 16 + lr;
      const int sw = ((n & 7) ^ ((n >> 3) & 7)) << 3;
      #pragma unroll
      for (int ks = 0; ks < 2; ++ks)
        bv2[dj][ks] = *(const s16x8*)&Vt[n * 64 + ((ks * 32 + hi * 8) ^ sw)];
    }
    #pragma unroll
    for (int ks = 0; ks < 2; ++ks)
      #pragma unroll
      for (int dj = 0; dj < 4; ++dj)
        oacc[dj] = __builtin_amdgcn_mfma_f32_16x16x32_bf16(pa[ks], bv2[dj][ks], oacc[dj], 0, 0, 0);
  }

  #pragma unroll
  for (int r = 0; r < 4; ++r) {
    const float inv = 1.f / lreg[r];
    const size_t grow = (tok0 + wq * 16 + hi * 4 + r) * D_ + colh;
    #pragma unroll
    for (int dj = 0; dj < 4; ++dj)
      o[grow + dj * 16 + lr] = f2b(oacc[dj][r] * inv);
  }
}

extern "C" void kernel_launch(void* const* d_in, const int* in_sizes, int n_in,
                              void* d_out, int out_size, void* d_ws, size_t ws_size,
                              hipStream_t stream)
{
  const float* x      = (const float*)d_in[0];
  const float* mask   = (const float*)d_in[1];
  const float* n1g    = (const float*)d_in[2];
  const float* n1b    = (const float*)d_in[3];
  const float* q_w    = (const float*)d_in[4];
  const float* q_bv   = (const float*)d_in[5];
  const float* k_w    = (const float*)d_in[6];
  const float* k_bv   = (const float*)d_in[7];
  const float* v_w    = (const float*)d_in[8];
  const float* v_bv   = (const float*)d_in[9];
  const float* o_w    = (const float*)d_in[10];
  const float* o_bv   = (const float*)d_in[11];
  const float* n2g    = (const float*)d_in[12];
  const float* n2b    = (const float*)d_in[13];
  const float* fc1_w  = (const float*)d_in[14];
  const float* fc1_bv = (const float*)d_in[15];
  const float* fc2_w  = (const float*)d_in[16];
  const float* fc2_bv = (const float*)d_in[17];
  const float* lora1A = (const float*)d_in[18];
  const float* lora1B = (const float*)d_in[19];
  const float* lora2A = (const float*)d_in[20];
  const float* lora2B = (const float*)d_in[21];
  const float* vera1A = (const float*)d_in[22];
  const float* vera1B = (const float*)d_in[23];
  const float* vera2A = (const float*)d_in[24];
  const float* vera2B = (const float*)d_in[25];
  const float* e1d    = (const float*)d_in[26];
  const float* e1b    = (const float*)d_in[27];
  const float* e2d    = (const float*)d_in[28];
  const float* e2b    = (const float*)d_in[29];
  const int*   nbp    = (const int*)d_in[30];

  char* wsb = (char*)d_ws;
  u16* h1    = (u16*)wsb; wsb += (size_t)M_ * D_ * 2;       // 12.6 MB
  u16* qkv   = (u16*)wsb; wsb += (size_t)M_ * QLD * 2;      // 37.7 MB
  u16* attno = (u16*)wsb; wsb += (size_t)M_ * D_ * 2;
  u16* oproj = (u16*)wsb; wsb += (size_t)M_ * D_ * 2;
  u16* n2    = (u16*)wsb; wsb += (size_t)M_ * D_ * 2;
  u16* wqkv  = (u16*)wsb; wsb += (size_t)QLD * D_ * 2;
  u16* wo    = (u16*)wsb; wsb += (size_t)D_ * D_ * 2;
  u16* wfc1  = (u16*)wsb; wsb += (size_t)FF_ * D_ * 2;
  u16* wfc2  = (u16*)wsb; wsb += (size_t)D_ * FF_ * 2;
  u16* tmp1b = (u16*)wsb; wsb += (size_t)M_ * 32 * 2;
  u16* tmp2b = (u16*)wsb; wsb += (size_t)M_ * 32 * 2;
  u16* up1L  = (u16*)wsb; wsb += (size_t)FF_ * 32 * 2;
  u16* up1V  = (u16*)wsb; wsb += (size_t)FF_ * 32 * 2;
  u16* up2L  = (u16*)wsb; wsb += (size_t)D_ * 32 * 2;
  u16* up2V  = (u16*)wsb; wsb += (size_t)D_ * 32 * 2;
  u16* a2tL  = (u16*)wsb; wsb += (size_t)16 * FF_ * 2;
  u16* a2tV  = (u16*)wsb; wsb += (size_t)16 * FF_ * 2;
  float* qkvb = (float*)wsb; wsb += (size_t)QLD * 4;
  float* part = (float*)wsb; wsb += (size_t)8 * M_ * 16 * 4; // 4 MB
  // hid [M,FF] bf16 aliases h1+qkv (12.6+37.7 = 50.3 MB, both dead by fc1)
  u16* hidb = h1;

  // weight conversion + preps
  cvt_f2b<<<(D_*D_/4 + 255)/256, 256, 0, stream>>>(q_w, wqkv,              D_*D_/4);
  cvt_f2b<<<(D_*D_/4 + 255)/256, 256, 0, stream>>>(k_w, wqkv +   D_*D_,    D_*D_/4);
  cvt_f2b<<<(D_*D_/4 + 255)/256, 256, 0, stream>>>(v_w, wqkv + 2*D_*D_,    D_*D_/4);
  cvt_f2b<<<(D_*D_/4 + 255)/256, 256, 0, stream>>>(o_w,   wo,   D_*D_/4);
  cvt_f2b<<<(FF_*D_/4 + 255)/256, 256, 0, stream>>>(fc1_w, wfc1, FF_*D_/4);
  cvt_f2b<<<(D_*FF_/4 + 255)/256, 256, 0, stream>>>(fc2_w, wfc2, D_*FF_/4);
  prep_qkvb<<<(QLD + 255)/256, 256, 0, stream>>>(q_bv, k_bv, v_bv, qkvb);
  prep_up<<<(FF_ + 255)/256, 256, 0, stream>>>(lora1B, vera1B, e1b, up1L, up1V, FF_);
  prep_up<<<(D_  + 255)/256, 256, 0, stream>>>(lora2B, vera2B, e2b, up2L, up2V, D_);
  prep_a2t<<<(FF_ + 255)/256, 256, 0, stream>>>(lora2A, vera2A, a2tL, a2tV);

  // attention
  ln_k<false><<<M_, 256, 0, stream>>>(x, nullptr, n1g, n1b, h1, nullptr,
                                      nullptr, nullptr, nullptr, nullptr, nullptr);
  gemm_bt<0><<<dim3(M_/128, QLD/128), 256, 0, stream>>>(
      h1, wqkv, qkvb, qkv, nullptr, nullptr, nullptr, nullptr, nullptr, nullptr,
      M_, QLD, D_);
  attn_mfma<<<dim3(S_/64, B_*H_), 256, 0, stream>>>(qkv, mask, attno);
  gemm_bt<0><<<dim3(M_/128, D_/128), 256, 0, stream>>>(
      attno, wo, o_bv, oproj, nullptr, nullptr, nullptr, nullptr, nullptr, nullptr,
      M_, D_, D_);

  // x1 = x + attn_proj (into d_out), n2 = LN(x1), tmp1b = (n2 @ A1)(*d1) bf16
  ln_k<true><<<M_, 256, 0, stream>>>(x, oproj, n2g, n2b, n2, (float*)d_out,
                                     lora1A, vera1A, e1d, tmp1b, nbp);

  // fc1 (+adapter1 kstep, gelu) -> hid bf16
  gemm_bt<1><<<dim3(M_/128, FF_/128), 256, 0, stream>>>(
      n2, wfc1, fc1_bv, hidb, nullptr, nullptr, tmp1b, up1L, up1V, nbp,
      M_, FF_, D_);

  // tmp2 = gelu_hid @ A2 (K-split MFMA + reduce)
  downproj<<<dim3(M_/128, 8), 256, 0, stream>>>(hidb, a2tL, a2tV, part, nbp);
  reduce_dp<<<M_*16/256, 256, 0, stream>>>(part, e2d, tmp2b, nbp);

  // fc2 (+adapter2 kstep) + residual -> f32 d_out
  gemm_bt<2><<<dim3(M_/128, D_/128), 256, 0, stream>>>(
      hidb, wfc2, fc2_bv, nullptr, (float*)d_out, (const float*)d_out,
      tmp2b, up2L, up2V, nbp, M_, D_, FF_);
}

// Round 5
// 385.750 us; speedup vs baseline: 3.9047x; 1.0460x over previous
//
#include <hip/hip_runtime.h>
#include <stdint.h>

#define B_  8
#define S_  1024
#define D_  768
#define H_  12
#define HD_ 64
#define FF_ 3072
#define M_  (B_*S_)   // 8192 tokens
#define R_  16
#define QLD 2304      // packed QKV row stride
#define KBLK 128

typedef unsigned short u16;
typedef short s16x8 __attribute__((ext_vector_type(8)));   // 8 bf16 (4 VGPRs)
typedef float fx4  __attribute__((ext_vector_type(4)));    // 4 fp32 acc

__device__ __forceinline__ float b2f(u16 u) {
  union { unsigned int i; float f; } c; c.i = ((unsigned int)u) << 16; return c.f;
}
__device__ __forceinline__ u16 f2b(float f) {   // RNE f32->bf16
  union { float f; unsigned int i; } c; c.f = f;
  unsigned int x = c.i;
  x += 0x7FFFu + ((x >> 16) & 1u);
  return (u16)(x >> 16);
}
__device__ __forceinline__ float gelu_f(float x) {  // jax.nn.gelu approximate=True (tanh)
  float u = 0.7978845608028654f * (x + 0.044715f * x * x * x);
  float e = __expf(2.f * u);
  float t = 1.f - 2.f / (e + 1.f);
  return 0.5f * x * (1.f + t);
}
__device__ __forceinline__ void gload16(const u16* gsrc, u16* ldst) {
  __builtin_amdgcn_global_load_lds(
      (__attribute__((address_space(1))) void*)(gsrc),
      (__attribute__((address_space(3))) void*)(ldst), 16, 0, 0);
}

// ---------------- all weights f32 -> bf16, one kernel ----------------
__global__ __launch_bounds__(256)
void cvt_all(const float* __restrict__ q_w, const float* __restrict__ k_w,
             const float* __restrict__ v_w, const float* __restrict__ o_w,
             const float* __restrict__ fc1_w, const float* __restrict__ fc2_w,
             u16* __restrict__ wqkv, u16* __restrict__ wo,
             u16* __restrict__ wfc1, u16* __restrict__ wfc2)
{
  const int i = blockIdx.x * 256 + threadIdx.x;   // quad index
  const int q1  = D_ * D_ / 4;
  const int fd4 = FF_ * D_ / 4;
  const float* s; u16* d; int j;
  if      (i <     q1)       { s = q_w;   d = wqkv;            j = i; }
  else if (i < 2 * q1)       { s = k_w;   d = wqkv + D_*D_;    j = i - q1; }
  else if (i < 3 * q1)       { s = v_w;   d = wqkv + 2*D_*D_;  j = i - 2*q1; }
  else if (i < 4 * q1)       { s = o_w;   d = wo;              j = i - 3*q1; }
  else if (i < 4 * q1 + fd4) { s = fc1_w; d = wfc1;            j = i - 4*q1; }
  else                       { s = fc2_w; d = wfc2;            j = i - 4*q1 - fd4; }
  const float4 f = ((const float4*)s)[j];
  ushort4 o4; o4.x = f2b(f.x); o4.y = f2b(f.y); o4.z = f2b(f.z); o4.w = f2b(f.w);
  ((ushort4*)d)[j] = o4;
}

// ---------------- all small preps, one kernel (grid FF_/256 = 12 blocks) ----------------
__global__ __launch_bounds__(256)
void prep_all(const float* __restrict__ q_bv, const float* __restrict__ k_bv,
              const float* __restrict__ v_bv, float* __restrict__ qkvb,
              const float* __restrict__ lora1B, const float* __restrict__ vera1B,
              const float* __restrict__ e1b, u16* __restrict__ up1L, u16* __restrict__ up1V,
              const float* __restrict__ lora2B, const float* __restrict__ vera2B,
              const float* __restrict__ e2b, u16* __restrict__ up2L, u16* __restrict__ up2V,
              const float* __restrict__ lora2A, const float* __restrict__ vera2A,
              u16* __restrict__ a2tL, u16* __restrict__ a2tV)
{
  const int f = blockIdx.x * 256 + threadIdx.x;   // 0..FF_-1
  if (f < QLD)
    qkvb[f] = (f < D_) ? q_bv[f] : (f < 2 * D_) ? k_bv[f - D_] : v_bv[f - 2 * D_];
  // fc1 adapter-up (N=FF), vera pre-scaled by e1b
  {
    const float ev = e1b[f];
    #pragma unroll
    for (int r = 0; r < 16; ++r) {
      up1L[(size_t)f * 32 + r] = f2b(lora1B[(size_t)r * FF_ + f]);
      up1V[(size_t)f * 32 + r] = f2b(vera1B[(size_t)r * FF_ + f] * ev);
      up1L[(size_t)f * 32 + 16 + r] = 0;
      up1V[(size_t)f * 32 + 16 + r] = 0;
    }
  }
  // A2^T [16][FF]
  {
    const float4* apl = (const float4*)(lora2A + (size_t)f * 16);
    const float4* apv = (const float4*)(vera2A + (size_t)f * 16);
    #pragma unroll
    for (int q4 = 0; q4 < 4; ++q4) {
      const float4 l4 = apl[q4], v4 = apv[q4];
      a2tL[(size_t)(q4*4+0) * FF_ + f] = f2b(l4.x);
      a2tL[(size_t)(q4*4+1) * FF_ + f] = f2b(l4.y);
      a2tL[(size_t)(q4*4+2) * FF_ + f] = f2b(l4.z);
      a2tL[(size_t)(q4*4+3) * FF_ + f] = f2b(l4.w);
      a2tV[(size_t)(q4*4+0) * FF_ + f] = f2b(v4.x);
      a2tV[(size_t)(q4*4+1) * FF_ + f] = f2b(v4.y);
      a2tV[(size_t)(q4*4+2) * FF_ + f] = f2b(v4.z);
      a2tV[(size_t)(q4*4+3) * FF_ + f] = f2b(v4.w);
    }
  }
  // fc2 adapter-up (N=D), vera pre-scaled by e2b
  if (f < D_) {
    const float ev = e2b[f];
    #pragma unroll
    for (int r = 0; r < 16; ++r) {
      up2L[(size_t)f * 32 + r] = f2b(lora2B[(size_t)r * D_ + f]);
      up2V[(size_t)f * 32 + r] = f2b(vera2B[(size_t)r * D_ + f] * ev);
      up2L[(size_t)f * 32 + 16 + r] = 0;
      up2V[(size_t)f * 32 + 16 + r] = 0;
    }
  }
}

// ---------------- LayerNorm (+residual add, + fused rank-16 down-projection) ----------------
template<bool ADD>
__global__ __launch_bounds__(256)
void ln_k(const float* __restrict__ x, const u16* __restrict__ add,
          const float* __restrict__ g, const float* __restrict__ beta,
          u16* __restrict__ outb, float* __restrict__ xsum,
          const float* __restrict__ Alora, const float* __restrict__ Avera,
          const float* __restrict__ dvec, u16* __restrict__ tmp1b,
          const int* __restrict__ nbp)
{
  const int row = blockIdx.x;
  const size_t base = (size_t)row * D_;
  float v0[3]; float s = 0.f, sq = 0.f;
  #pragma unroll
  for (int i = 0; i < 3; ++i) {
    const int d = threadIdx.x + i * 256;
    float val = x[base + d];
    if (ADD) { val += b2f(add[base + d]); xsum[base + d] = val; }
    v0[i] = val; s += val; sq += val * val;
  }
  #pragma unroll
  for (int mm = 32; mm >= 1; mm >>= 1) { s += __shfl_xor(s, mm); sq += __shfl_xor(sq, mm); }
  __shared__ float ss[4], s2[4];
  if ((threadIdx.x & 63) == 0) { ss[threadIdx.x >> 6] = s; s2[threadIdx.x >> 6] = sq; }
  __syncthreads();
  s  = ss[0] + ss[1] + ss[2] + ss[3];
  sq = s2[0] + s2[1] + s2[2] + s2[3];
  const float mean = s * (1.f / D_);
  const float var  = sq * (1.f / D_) - mean * mean;
  const float rs   = rsqrtf(var + 1e-6f);
  float nv[3];
  #pragma unroll
  for (int i = 0; i < 3; ++i) {
    const int d = threadIdx.x + i * 256;
    nv[i] = (v0[i] - mean) * rs * g[d] + beta[d];
    outb[base + d] = f2b(nv[i]);
  }

  if (ADD) {
    const int nb = *nbp;
    const bool ex = (row % S_) >= nb;
    const float* Am = ex ? Avera : Alora;
    float p[16];
    #pragma unroll
    for (int r = 0; r < 16; ++r) p[r] = 0.f;
    #pragma unroll
    for (int i = 0; i < 3; ++i) {
      const int d = threadIdx.x + i * 256;
      const float4* ap = (const float4*)(Am + (size_t)d * R_);
      const float4 a0 = ap[0], a1 = ap[1], a2 = ap[2], a3 = ap[3];
      const float vv = nv[i];
      p[0]  += vv * a0.x; p[1]  += vv * a0.y; p[2]  += vv * a0.z; p[3]  += vv * a0.w;
      p[4]  += vv * a1.x; p[5]  += vv * a1.y; p[6]  += vv * a1.z; p[7]  += vv * a1.w;
      p[8]  += vv * a2.x; p[9]  += vv * a2.y; p[10] += vv * a2.z; p[11] += vv * a2.w;
      p[12] += vv * a3.x; p[13] += vv * a3.y; p[14] += vv * a3.z; p[15] += vv * a3.w;
    }
    #pragma unroll
    for (int st = 1; st < 16; st <<= 1)
      #pragma unroll
      for (int r = 0; r < 16; ++r) p[r] += __shfl_xor(p[r], st);
    __shared__ float sred[16][16];
    const int grp = threadIdx.x >> 4;
    if ((threadIdx.x & 15) == 0) {
      #pragma unroll
      for (int r = 0; r < 16; ++r) sred[grp][r] = p[r];
    }
    __syncthreads();
    if (threadIdx.x < 16) {
      float v = 0.f;
      #pragma unroll
      for (int gg = 0; gg < 16; ++gg) v += sred[gg][threadIdx.x];
      if (ex) v *= dvec[threadIdx.x];
      tmp1b[(size_t)row * 32 + threadIdx.x] = f2b(v);
      tmp1b[(size_t)row * 32 + 16 + threadIdx.x] = 0;
    }
  }
}

// ---------------- bf16 MFMA GEMM: C = A[M,K] * W[N,K]^T + bias (+adapter kstep, epilogues) ----------------
// MODE 0: plain -> bf16 Cb.  MODE 1: +adapter kstep, gelu -> bf16 Cb.
// MODE 2: +adapter kstep, out_f32 = resid + acc + bias -> Cf.
template<int MODE>
__global__ __launch_bounds__(256)
void gemm_bt(const u16* __restrict__ A, const u16* __restrict__ W,
             const float* __restrict__ bias, u16* __restrict__ Cb,
             float* __restrict__ Cf, const float* __restrict__ resid,
             const u16* __restrict__ Aad, const u16* __restrict__ BadL,
             const u16* __restrict__ BadV, const int* __restrict__ nbp,
             int M, int N, int K)
{
  __shared__ u16 As[128 * 32];
  __shared__ u16 Bs[128 * 32];
  const int tid   = threadIdx.x;
  const int lane  = tid & 63;
  const int wid   = tid >> 6;
  const int wr    = wid >> 1;
  const int wc    = wid & 1;
  const int lr    = lane & 15;
  const int lk    = (lane >> 4) << 3;
  const int m0    = blockIdx.x * 128;
  const int n0    = blockIdx.y * 128;
  const int kg    = (tid & 3) * 8;
  const int row_a = tid >> 2;

  fx4 acc[4][4];
  const fx4 zero = {0.f, 0.f, 0.f, 0.f};
  #pragma unroll
  for (int i = 0; i < 4; ++i)
    #pragma unroll
    for (int j = 0; j < 4; ++j) acc[i][j] = zero;

  for (int k0 = 0; k0 < K; k0 += 32) {
    #pragma unroll
    for (int u = 0; u < 2; ++u) {
      const int row = u * 64 + row_a;
      const int li  = u * 256 + tid;
      gload16(A + (size_t)(m0 + row) * K + k0 + kg, &As[li * 8]);
      gload16(W + (size_t)(n0 + row) * K + k0 + kg, &Bs[li * 8]);
    }
    __syncthreads();
    s16x8 av[4], bv[4];
    #pragma unroll
    for (int i = 0; i < 4; ++i)
      av[i] = *(const s16x8*)&As[(wr * 64 + i * 16 + lr) * 32 + lk];
    #pragma unroll
    for (int j = 0; j < 4; ++j)
      bv[j] = *(const s16x8*)&Bs[(wc * 64 + j * 16 + lr) * 32 + lk];
    #pragma unroll
    for (int i = 0; i < 4; ++i)
      #pragma unroll
      for (int j = 0; j < 4; ++j)
        acc[i][j] = __builtin_amdgcn_mfma_f32_16x16x32_bf16(av[i], bv[j], acc[i][j], 0, 0, 0);
    __syncthreads();
  }

  if (MODE >= 1) {
    // one extra K=32 k-step: adapter-up (tmp1b zero-padded [M,32] @ Bup[N,32]^T)
    const int nb = *nbp;
    const u16* Bad = ((m0 % S_) >= nb) ? BadV : BadL;
    #pragma unroll
    for (int u = 0; u < 2; ++u) {
      const int row = u * 64 + row_a;
      const int li  = u * 256 + tid;
      gload16(Aad + (size_t)(m0 + row) * 32 + kg, &As[li * 8]);
      gload16(Bad + (size_t)(n0 + row) * 32 + kg, &Bs[li * 8]);
    }
    __syncthreads();
    s16x8 av[4], bv[4];
    #pragma unroll
    for (int i = 0; i < 4; ++i)
      av[i] = *(const s16x8*)&As[(wr * 64 + i * 16 + lr) * 32 + lk];
    #pragma unroll
    for (int j = 0; j < 4; ++j)
      bv[j] = *(const s16x8*)&Bs[(wc * 64 + j * 16 + lr) * 32 + lk];
    #pragma unroll
    for (int i = 0; i < 4; ++i)
      #pragma unroll
      for (int j = 0; j < 4; ++j)
        acc[i][j] = __builtin_amdgcn_mfma_f32_16x16x32_bf16(av[i], bv[j], acc[i][j], 0, 0, 0);
    __syncthreads();
  }

  const int rb = (lane >> 4) * 4;
  #pragma unroll
  for (int j = 0; j < 4; ++j) {
    const int col = n0 + wc * 64 + j * 16 + lr;
    const float bj = bias ? bias[col] : 0.f;
    #pragma unroll
    for (int i = 0; i < 4; ++i) {
      const int row = m0 + wr * 64 + i * 16 + rb;
      #pragma unroll
      for (int r = 0; r < 4; ++r) {
        const float val = acc[i][j][r] + bj;
        const size_t idx = (size_t)(row + r) * N + col;
        if (MODE == 1)      Cb[idx] = f2b(gelu_f(val));
        else if (MODE == 2) Cf[idx] = resid[idx] + val;
        else                Cb[idx] = f2b(val);
      }
    }
  }
}

// ---------------- skinny down-projection: part[ks][M][16] = hid_kslice @ A2t^T ----------------
__global__ __launch_bounds__(256)
void downproj(const u16* __restrict__ hid, const u16* __restrict__ A2tL,
              const u16* __restrict__ A2tV, float* __restrict__ part,
              const int* __restrict__ nbp)
{
  __shared__ u16 As[128 * 32];
  __shared__ u16 Bs[16 * 32];
  const int tid  = threadIdx.x;
  const int lane = tid & 63;
  const int w    = tid >> 6;
  const int lr   = lane & 15;
  const int lk   = (lane >> 4) << 3;
  const int m0   = blockIdx.x * 128;
  const int kb   = blockIdx.y * (FF_ / 8);
  const int nb   = *nbp;
  const u16* A2t = ((m0 % S_) >= nb) ? A2tV : A2tL;
  const int kg    = (tid & 3) * 8;
  const int row_a = tid >> 2;

  const fx4 zero = {0.f, 0.f, 0.f, 0.f};
  fx4 acc[2]; acc[0] = zero; acc[1] = zero;

  for (int k0 = kb; k0 < kb + FF_ / 8; k0 += 32) {
    #pragma unroll
    for (int u = 0; u < 2; ++u)
      gload16(hid + (size_t)(m0 + u * 64 + row_a) * FF_ + k0 + kg,
              &As[(u * 256 + tid) * 8]);
    if (tid < 64)
      gload16(A2t + (size_t)(tid >> 2) * FF_ + k0 + kg, &Bs[tid * 8]);
    __syncthreads();
    s16x8 bv = *(const s16x8*)&Bs[lr * 32 + lk];
    #pragma unroll
    for (int i = 0; i < 2; ++i) {
      s16x8 av = *(const s16x8*)&As[(w * 32 + i * 16 + lr) * 32 + lk];
      acc[i] = __builtin_amdgcn_mfma_f32_16x16x32_bf16(av, bv, acc[i], 0, 0, 0);
    }
    __syncthreads();
  }

  const int rb = (lane >> 4) * 4;
  #pragma unroll
  for (int i = 0; i < 2; ++i)
    #pragma unroll
    for (int r = 0; r < 4; ++r)
      part[(size_t)blockIdx.y * M_ * 16 +
           (size_t)(m0 + w * 32 + i * 16 + rb + r) * 16 + lr] = acc[i][r];
}

// ---------------- reduce partials -> tmp2b bf16 [M,32] ----------------
__global__ __launch_bounds__(256)
void reduce_dp(const float* __restrict__ part, const float* __restrict__ d2,
               u16* __restrict__ tmp2b, const int* __restrict__ nbp)
{
  const int idx = blockIdx.x * 256 + threadIdx.x;   // m*16 + r
  const int m = idx >> 4, r = idx & 15;
  const int nb = *nbp;
  float s = 0.f;
  #pragma unroll
  for (int ks = 0; ks < 8; ++ks) s += part[(size_t)ks * M_ * 16 + idx];
  if ((m % S_) >= nb) s *= d2[r];
  tmp2b[(size_t)m * 32 + r] = f2b(s);
  tmp2b[(size_t)m * 32 + 16 + r] = 0;
}

// ---------------- MFMA flash attention, KBLK=128, P overlays dead Q LDS ----------------
// grid (S/64, B*H); 4 waves; wave wq owns q-rows wq*16..+15.
__global__ __launch_bounds__(256)
void attn_mfma(const u16* __restrict__ qkv, const float* __restrict__ mask,
               u16* __restrict__ o)
{
  __shared__ u16 Kl[128 * 64];   // row k, col d, swz col^((k&7)<<3)
  __shared__ u16 Vt[64 * 128];   // row d, col k, swz k^(((d&7)^((d>>3)&7))<<3)
  __shared__ u16 QP[4 * 2048];   // prologue: Q 64x64; then per-wave P 16x128

  const int tid  = threadIdx.x;
  const int lane = tid & 63;
  const int wq   = tid >> 6;
  const int lr   = lane & 15;
  const int hi   = lane >> 4;
  const int qb   = blockIdx.x;
  const int bh   = blockIdx.y;
  const int b    = bh / H_;
  const int h    = bh % H_;
  const size_t tok0 = (size_t)b * S_ + (size_t)qb * 64;
  const size_t colh = (size_t)h * HD_;

  // ---- stage Q (swizzled source) into QP ----
  #pragma unroll
  for (int u = 0; u < 2; ++u) {
    const int li = u * 256 + tid;
    const int r  = li >> 3;
    const int cb = ((li & 7) ^ (r & 7)) * 8;
    gload16(qkv + (tok0 + r) * QLD + colh + cb, &QP[li * 8]);
  }
  __syncthreads();
  s16x8 qa[2];
  {
    const int qrow = wq * 16 + lr;
    #pragma unroll
    for (int ks = 0; ks < 2; ++ks)
      qa[ks] = *(const s16x8*)&QP[qrow * 64 + ((ks * 32 + hi * 8) ^ ((qrow & 7) << 3))];
  }

  const fx4 zero = {0.f, 0.f, 0.f, 0.f};
  fx4 oacc[4];
  #pragma unroll
  for (int dj = 0; dj < 4; ++dj) oacc[dj] = zero;
  float mreg[4], lreg[4];
  #pragma unroll
  for (int r = 0; r < 4; ++r) { mreg[r] = -3.0e38f; lreg[r] = 0.f; }

  for (int kt = 0; kt < S_ / KBLK; ++kt) {
    const size_t ktok = (size_t)b * S_ + (size_t)kt * KBLK;
    __syncthreads();   // prev-iter LDS reads done (also protects Q prologue reads)

    // stage K rows 0..127 (gload16, swizzled source)
    #pragma unroll
    for (int u = 0; u < 4; ++u) {
      const int li = u * 256 + tid;
      const int r  = li >> 3;
      const int cb = ((li & 7) ^ (r & 7)) * 8;
      gload16(qkv + (ktok + r) * QLD + D_ + colh + cb, &Kl[li * 8]);
    }
    // stage V transposed: thread handles k-rows 4a..4a+3, d-cols c8..c8+7
    {
      const int a  = tid >> 3;            // 0..31
      const int c8 = (tid & 7) * 8;
      const u16* vp = qkv + (ktok + 4 * a) * QLD + 2 * D_ + colh + c8;
      s16x8 v0 = *(const s16x8*)vp;
      s16x8 v1 = *(const s16x8*)(vp + QLD);
      s16x8 v2 = *(const s16x8*)(vp + 2 * QLD);
      s16x8 v3 = *(const s16x8*)(vp + 3 * QLD);
      #pragma unroll
      for (int jj = 0; jj < 8; ++jj) {
        const int d  = c8 + jj;
        const int sw = ((d & 7) ^ ((d >> 3) & 7)) << 3;
        const int cp = (4 * a) ^ sw;      // bit1 clear -> cp+2 = (4a+2)^sw
        *(uint32_t*)&Vt[d * 128 + cp] =
            (uint32_t)(u16)v0[jj] | ((uint32_t)(u16)v1[jj] << 16);
        *(uint32_t*)&Vt[d * 128 + cp + 2] =
            (uint32_t)(u16)v2[jj] | ((uint32_t)(u16)v3[jj] << 16);
      }
    }
    __syncthreads();

    // ---- QK^T in two register-halves of 4 column-groups ----
    float val[8][4];
    #pragma unroll
    for (int jh = 0; jh < 2; ++jh) {
      s16x8 kb2[4][2];
      #pragma unroll
      for (int j = 0; j < 4; ++j) {
        const int n = (jh * 4 + j) * 16 + lr;
        #pragma unroll
        for (int ks = 0; ks < 2; ++ks)
          kb2[j][ks] = *(const s16x8*)&Kl[n * 64 + ((ks * 32 + hi * 8) ^ ((n & 7) << 3))];
      }
      // mask loads issued before MFMA cluster (latency hides under MFMA)
      float mvh[4][4];
      {
        const float* mp = mask + (size_t)(qb * 64 + wq * 16 + hi * 4) * S_
                        + (size_t)kt * KBLK + jh * 64 + lr;
        #pragma unroll
        for (int j = 0; j < 4; ++j)
          #pragma unroll
          for (int r = 0; r < 4; ++r)
            mvh[j][r] = mp[(size_t)r * S_ + j * 16];
      }
      fx4 sf[4];
      #pragma unroll
      for (int j = 0; j < 4; ++j) sf[j] = zero;
      __builtin_amdgcn_s_setprio(1);
      #pragma unroll
      for (int ks = 0; ks < 2; ++ks)
        #pragma unroll
        for (int j = 0; j < 4; ++j)
          sf[j] = __builtin_amdgcn_mfma_f32_16x16x32_bf16(qa[ks], kb2[j][ks], sf[j], 0, 0, 0);
      __builtin_amdgcn_s_setprio(0);
      #pragma unroll
      for (int j = 0; j < 4; ++j)
        #pragma unroll
        for (int r = 0; r < 4; ++r)
          val[jh * 4 + j][r] = sf[j][r] * 0.125f + mvh[j][r];
    }

    // ---- online softmax over 128 cols (rows shared by 16-lane groups) ----
    #pragma unroll
    for (int r = 0; r < 4; ++r) {
      float mx = val[0][r];
      #pragma unroll
      for (int j = 1; j < 8; ++j) mx = fmaxf(mx, val[j][r]);
      mx = fmaxf(mx, __shfl_xor(mx, 1));
      mx = fmaxf(mx, __shfl_xor(mx, 2));
      mx = fmaxf(mx, __shfl_xor(mx, 4));
      mx = fmaxf(mx, __shfl_xor(mx, 8));
      const float mn  = fmaxf(mreg[r], mx);
      const float fac = __expf(mreg[r] - mn);
      mreg[r] = mn;
      float rs = 0.f;
      #pragma unroll
      for (int j = 0; j < 8; ++j) {
        const float p = __expf(val[j][r] - mn);
        val[j][r] = p;
        rs += p;
      }
      rs += __shfl_xor(rs, 1); rs += __shfl_xor(rs, 2);
      rs += __shfl_xor(rs, 4); rs += __shfl_xor(rs, 8);
      lreg[r] = lreg[r] * fac + rs;
      #pragma unroll
      for (int dj = 0; dj < 4; ++dj) oacc[dj][r] *= fac;
    }

    // ---- P -> wave-private overlay LDS (bf16, swz) ----
    #pragma unroll
    for (int j = 0; j < 8; ++j) {
      const int col = j * 16 + lr;
      #pragma unroll
      for (int r = 0; r < 4; ++r) {
        const int row = hi * 4 + r;
        QP[wq * 2048 + row * 128 + (col ^ ((row & 7) << 3))] = f2b(val[j][r]);
      }
    }

    // ---- PV: 4 K-slices of 32 ----
    #pragma unroll
    for (int ks = 0; ks < 4; ++ks) {
      s16x8 pa = *(const s16x8*)&QP[wq * 2048 + lr * 128 +
                                    ((ks * 32 + hi * 8) ^ ((lr & 7) << 3))];
      s16x8 bv2[4];
      #pragma unroll
      for (int dj = 0; dj < 4; ++dj) {
        const int n  = dj * 16 + lr;
        const int sw = ((n & 7) ^ ((n >> 3) & 7)) << 3;
        bv2[dj] = *(const s16x8*)&Vt[n * 128 + ((ks * 32 + hi * 8) ^ sw)];
      }
      __builtin_amdgcn_s_setprio(1);
      #pragma unroll
      for (int dj = 0; dj < 4; ++dj)
        oacc[dj] = __builtin_amdgcn_mfma_f32_16x16x32_bf16(pa, bv2[dj], oacc[dj], 0, 0, 0);
      __builtin_amdgcn_s_setprio(0);
    }
  }

  // ---- epilogue: O /= l, write ----
  #pragma unroll
  for (int r = 0; r < 4; ++r) {
    const float inv = 1.f / lreg[r];
    const size_t grow = (tok0 + wq * 16 + hi * 4 + r) * D_ + colh;
    #pragma unroll
    for (int dj = 0; dj < 4; ++dj)
      o[grow + dj * 16 + lr] = f2b(oacc[dj][r] * inv);
  }
}

extern "C" void kernel_launch(void* const* d_in, const int* in_sizes, int n_in,
                              void* d_out, int out_size, void* d_ws, size_t ws_size,
                              hipStream_t stream)
{
  const float* x      = (const float*)d_in[0];
  const float* mask   = (const float*)d_in[1];
  const float* n1g    = (const float*)d_in[2];
  const float* n1b    = (const float*)d_in[3];
  const float* q_w    = (const float*)d_in[4];
  const float* q_bv   = (const float*)d_in[5];
  const float* k_w    = (const float*)d_in[6];
  const float* k_bv   = (const float*)d_in[7];
  const float* v_w    = (const float*)d_in[8];
  const float* v_bv   = (const float*)d_in[9];
  const float* o_w    = (const float*)d_in[10];
  const float* o_bv   = (const float*)d_in[11];
  const float* n2g    = (const float*)d_in[12];
  const float* n2b    = (const float*)d_in[13];
  const float* fc1_w  = (const float*)d_in[14];
  const float* fc1_bv = (const float*)d_in[15];
  const float* fc2_w  = (const float*)d_in[16];
  const float* fc2_bv = (const float*)d_in[17];
  const float* lora1A = (const float*)d_in[18];
  const float* lora1B = (const float*)d_in[19];
  const float* lora2A = (const float*)d_in[20];
  const float* lora2B = (const float*)d_in[21];
  const float* vera1A = (const float*)d_in[22];
  const float* vera1B = (const float*)d_in[23];
  const float* vera2A = (const float*)d_in[24];
  const float* vera2B = (const float*)d_in[25];
  const float* e1d    = (const float*)d_in[26];
  const float* e1b    = (const float*)d_in[27];
  const float* e2d    = (const float*)d_in[28];
  const float* e2b    = (const float*)d_in[29];
  const int*   nbp    = (const int*)d_in[30];

  char* wsb = (char*)d_ws;
  u16* h1    = (u16*)wsb; wsb += (size_t)M_ * D_ * 2;       // 12.6 MB
  u16* qkv   = (u16*)wsb; wsb += (size_t)M_ * QLD * 2;      // 37.7 MB
  u16* attno = (u16*)wsb; wsb += (size_t)M_ * D_ * 2;
  u16* oproj = (u16*)wsb; wsb += (size_t)M_ * D_ * 2;
  u16* n2    = (u16*)wsb; wsb += (size_t)M_ * D_ * 2;
  u16* wqkv  = (u16*)wsb; wsb += (size_t)QLD * D_ * 2;
  u16* wo    = (u16*)wsb; wsb += (size_t)D_ * D_ * 2;
  u16* wfc1  = (u16*)wsb; wsb += (size_t)FF_ * D_ * 2;
  u16* wfc2  = (u16*)wsb; wsb += (size_t)D_ * FF_ * 2;
  u16* tmp1b = (u16*)wsb; wsb += (size_t)M_ * 32 * 2;
  u16* tmp2b = (u16*)wsb; wsb += (size_t)M_ * 32 * 2;
  u16* up1L  = (u16*)wsb; wsb += (size_t)FF_ * 32 * 2;
  u16* up1V  = (u16*)wsb; wsb += (size_t)FF_ * 32 * 2;
  u16* up2L  = (u16*)wsb; wsb += (size_t)D_ * 32 * 2;
  u16* up2V  = (u16*)wsb; wsb += (size_t)D_ * 32 * 2;
  u16* a2tL  = (u16*)wsb; wsb += (size_t)16 * FF_ * 2;
  u16* a2tV  = (u16*)wsb; wsb += (size_t)16 * FF_ * 2;
  float* qkvb = (float*)wsb; wsb += (size_t)QLD * 4;
  float* part = (float*)wsb; wsb += (size_t)8 * M_ * 16 * 4; // 4 MB
  u16* hidb = h1;   // [M,FF] bf16 aliases h1+qkv (both dead by fc1)

  // weights -> bf16 (one kernel) + preps (one kernel)
  const int totq = (4 * D_ * D_ + 2 * FF_ * D_) / 4;
  cvt_all<<<totq / 256, 256, 0, stream>>>(q_w, k_w, v_w, o_w, fc1_w, fc2_w,
                                          wqkv, wo, wfc1, wfc2);
  prep_all<<<FF_ / 256, 256, 0, stream>>>(q_bv, k_bv, v_bv, qkvb,
                                          lora1B, vera1B, e1b, up1L, up1V,
                                          lora2B, vera2B, e2b, up2L, up2V,
                                          lora2A, vera2A, a2tL, a2tV);

  // attention
  ln_k<false><<<M_, 256, 0, stream>>>(x, nullptr, n1g, n1b, h1, nullptr,
                                      nullptr, nullptr, nullptr, nullptr, nullptr);
  gemm_bt<0><<<dim3(M_/128, QLD/128), 256, 0, stream>>>(
      h1, wqkv, qkvb, qkv, nullptr, nullptr, nullptr, nullptr, nullptr, nullptr,
      M_, QLD, D_);
  attn_mfma<<<dim3(S_/64, B_*H_), 256, 0, stream>>>(qkv, mask, attno);
  gemm_bt<0><<<dim3(M_/128, D_/128), 256, 0, stream>>>(
      attno, wo, o_bv, oproj, nullptr, nullptr, nullptr, nullptr, nullptr, nullptr,
      M_, D_, D_);

  // x1 = x + attn_proj (into d_out), n2 = LN(x1), tmp1b = (n2 @ A1)(*d1)
  ln_k<true><<<M_, 256, 0, stream>>>(x, oproj, n2g, n2b, n2, (float*)d_out,
                                     lora1A, vera1A, e1d, tmp1b, nbp);

  // fc1 (+adapter1 kstep, gelu) -> hid bf16
  gemm_bt<1><<<dim3(M_/128, FF_/128), 256, 0, stream>>>(
      n2, wfc1, fc1_bv, hidb, nullptr, nullptr, tmp1b, up1L, up1V, nbp,
      M_, FF_, D_);

  // tmp2 = gelu_hid @ A2 (K-split MFMA + reduce)
  downproj<<<dim3(M_/128, 8), 256, 0, stream>>>(hidb, a2tL, a2tV, part, nbp);
  reduce_dp<<<M_*16/256, 256, 0, stream>>>(part, e2d, tmp2b, nbp);

  // fc2 (+adapter2 kstep) + residual -> f32 d_out
  gemm_bt<2><<<dim3(M_/128, D_/128), 256, 0, stream>>>(
      hidb, wfc2, fc2_bv, nullptr, (float*)d_out, (const float*)d_out,
      tmp2b, up2L, up2V, nbp, M_, D_, FF_);
}

// Round 6
// 382.301 us; speedup vs baseline: 3.9400x; 1.0090x over previous
//
#include <hip/hip_runtime.h>
#include <stdint.h>

#define B_  8
#define S_  1024
#define D_  768
#define H_  12
#define HD_ 64
#define FF_ 3072
#define M_  (B_*S_)   // 8192 tokens
#define R_  16
#define QLD 2304      // packed QKV row stride
#define KBLK 128

typedef unsigned short u16;
typedef short s16x8 __attribute__((ext_vector_type(8)));   // 8 bf16 (4 VGPRs)
typedef float fx4  __attribute__((ext_vector_type(4)));    // 4 fp32 acc

__device__ __forceinline__ float b2f(u16 u) {
  union { unsigned int i; float f; } c; c.i = ((unsigned int)u) << 16; return c.f;
}
__device__ __forceinline__ u16 f2b(float f) {   // RNE f32->bf16
  union { float f; unsigned int i; } c; c.f = f;
  unsigned int x = c.i;
  x += 0x7FFFu + ((x >> 16) & 1u);
  return (u16)(x >> 16);
}
__device__ __forceinline__ float gelu_f(float x) {  // jax.nn.gelu approximate=True (tanh)
  float u = 0.7978845608028654f * (x + 0.044715f * x * x * x);
  float e = __expf(2.f * u);
  float t = 1.f - 2.f / (e + 1.f);
  return 0.5f * x * (1.f + t);
}
__device__ __forceinline__ void gload16(const u16* gsrc, u16* ldst) {
  __builtin_amdgcn_global_load_lds(
      (__attribute__((address_space(1))) void*)(gsrc),
      (__attribute__((address_space(3))) void*)(ldst), 16, 0, 0);
}

// ---------------- all weights f32 -> bf16, one kernel ----------------
__global__ __launch_bounds__(256)
void cvt_all(const float* __restrict__ q_w, const float* __restrict__ k_w,
             const float* __restrict__ v_w, const float* __restrict__ o_w,
             const float* __restrict__ fc1_w, const float* __restrict__ fc2_w,
             u16* __restrict__ wqkv, u16* __restrict__ wo,
             u16* __restrict__ wfc1, u16* __restrict__ wfc2)
{
  const int i = blockIdx.x * 256 + threadIdx.x;   // quad index
  const int q1  = D_ * D_ / 4;
  const int fd4 = FF_ * D_ / 4;
  const float* s; u16* d; int j;
  if      (i <     q1)       { s = q_w;   d = wqkv;            j = i; }
  else if (i < 2 * q1)       { s = k_w;   d = wqkv + D_*D_;    j = i - q1; }
  else if (i < 3 * q1)       { s = v_w;   d = wqkv + 2*D_*D_;  j = i - 2*q1; }
  else if (i < 4 * q1)       { s = o_w;   d = wo;              j = i - 3*q1; }
  else if (i < 4 * q1 + fd4) { s = fc1_w; d = wfc1;            j = i - 4*q1; }
  else                       { s = fc2_w; d = wfc2;            j = i - 4*q1 - fd4; }
  const float4 f = ((const float4*)s)[j];
  ushort4 o4; o4.x = f2b(f.x); o4.y = f2b(f.y); o4.z = f2b(f.z); o4.w = f2b(f.w);
  ((ushort4*)d)[j] = o4;
}

// ---------------- all small preps, one kernel (grid FF_/256 = 12 blocks) ----------------
__global__ __launch_bounds__(256)
void prep_all(const float* __restrict__ q_bv, const float* __restrict__ k_bv,
              const float* __restrict__ v_bv, float* __restrict__ qkvb,
              const float* __restrict__ lora1B, const float* __restrict__ vera1B,
              const float* __restrict__ e1b, u16* __restrict__ up1L, u16* __restrict__ up1V,
              const float* __restrict__ lora2B, const float* __restrict__ vera2B,
              const float* __restrict__ e2b, u16* __restrict__ up2L, u16* __restrict__ up2V,
              const float* __restrict__ lora2A, const float* __restrict__ vera2A,
              u16* __restrict__ a2tL, u16* __restrict__ a2tV)
{
  const int f = blockIdx.x * 256 + threadIdx.x;   // 0..FF_-1
  if (f < QLD)
    qkvb[f] = (f < D_) ? q_bv[f] : (f < 2 * D_) ? k_bv[f - D_] : v_bv[f - 2 * D_];
  {
    const float ev = e1b[f];
    #pragma unroll
    for (int r = 0; r < 16; ++r) {
      up1L[(size_t)f * 32 + r] = f2b(lora1B[(size_t)r * FF_ + f]);
      up1V[(size_t)f * 32 + r] = f2b(vera1B[(size_t)r * FF_ + f] * ev);
      up1L[(size_t)f * 32 + 16 + r] = 0;
      up1V[(size_t)f * 32 + 16 + r] = 0;
    }
  }
  {
    const float4* apl = (const float4*)(lora2A + (size_t)f * 16);
    const float4* apv = (const float4*)(vera2A + (size_t)f * 16);
    #pragma unroll
    for (int q4 = 0; q4 < 4; ++q4) {
      const float4 l4 = apl[q4], v4 = apv[q4];
      a2tL[(size_t)(q4*4+0) * FF_ + f] = f2b(l4.x);
      a2tL[(size_t)(q4*4+1) * FF_ + f] = f2b(l4.y);
      a2tL[(size_t)(q4*4+2) * FF_ + f] = f2b(l4.z);
      a2tL[(size_t)(q4*4+3) * FF_ + f] = f2b(l4.w);
      a2tV[(size_t)(q4*4+0) * FF_ + f] = f2b(v4.x);
      a2tV[(size_t)(q4*4+1) * FF_ + f] = f2b(v4.y);
      a2tV[(size_t)(q4*4+2) * FF_ + f] = f2b(v4.z);
      a2tV[(size_t)(q4*4+3) * FF_ + f] = f2b(v4.w);
    }
  }
  if (f < D_) {
    const float ev = e2b[f];
    #pragma unroll
    for (int r = 0; r < 16; ++r) {
      up2L[(size_t)f * 32 + r] = f2b(lora2B[(size_t)r * D_ + f]);
      up2V[(size_t)f * 32 + r] = f2b(vera2B[(size_t)r * D_ + f] * ev);
      up2L[(size_t)f * 32 + 16 + r] = 0;
      up2V[(size_t)f * 32 + 16 + r] = 0;
    }
  }
}

// ---------------- LayerNorm (+residual add, + fused rank-16 down-projection) ----------------
template<bool ADD>
__global__ __launch_bounds__(256)
void ln_k(const float* __restrict__ x, const u16* __restrict__ add,
          const float* __restrict__ g, const float* __restrict__ beta,
          u16* __restrict__ outb, float* __restrict__ xsum,
          const float* __restrict__ Alora, const float* __restrict__ Avera,
          const float* __restrict__ dvec, u16* __restrict__ tmp1b,
          const int* __restrict__ nbp)
{
  const int row = blockIdx.x;
  const size_t base = (size_t)row * D_;
  float v0[3]; float s = 0.f, sq = 0.f;
  #pragma unroll
  for (int i = 0; i < 3; ++i) {
    const int d = threadIdx.x + i * 256;
    float val = x[base + d];
    if (ADD) { val += b2f(add[base + d]); xsum[base + d] = val; }
    v0[i] = val; s += val; sq += val * val;
  }
  #pragma unroll
  for (int mm = 32; mm >= 1; mm >>= 1) { s += __shfl_xor(s, mm); sq += __shfl_xor(sq, mm); }
  __shared__ float ss[4], s2[4];
  if ((threadIdx.x & 63) == 0) { ss[threadIdx.x >> 6] = s; s2[threadIdx.x >> 6] = sq; }
  __syncthreads();
  s  = ss[0] + ss[1] + ss[2] + ss[3];
  sq = s2[0] + s2[1] + s2[2] + s2[3];
  const float mean = s * (1.f / D_);
  const float var  = sq * (1.f / D_) - mean * mean;
  const float rs   = rsqrtf(var + 1e-6f);
  float nv[3];
  #pragma unroll
  for (int i = 0; i < 3; ++i) {
    const int d = threadIdx.x + i * 256;
    nv[i] = (v0[i] - mean) * rs * g[d] + beta[d];
    outb[base + d] = f2b(nv[i]);
  }

  if (ADD) {
    const int nb = *nbp;
    const bool ex = (row % S_) >= nb;
    const float* Am = ex ? Avera : Alora;
    float p[16];
    #pragma unroll
    for (int r = 0; r < 16; ++r) p[r] = 0.f;
    #pragma unroll
    for (int i = 0; i < 3; ++i) {
      const int d = threadIdx.x + i * 256;
      const float4* ap = (const float4*)(Am + (size_t)d * R_);
      const float4 a0 = ap[0], a1 = ap[1], a2 = ap[2], a3 = ap[3];
      const float vv = nv[i];
      p[0]  += vv * a0.x; p[1]  += vv * a0.y; p[2]  += vv * a0.z; p[3]  += vv * a0.w;
      p[4]  += vv * a1.x; p[5]  += vv * a1.y; p[6]  += vv * a1.z; p[7]  += vv * a1.w;
      p[8]  += vv * a2.x; p[9]  += vv * a2.y; p[10] += vv * a2.z; p[11] += vv * a2.w;
      p[12] += vv * a3.x; p[13] += vv * a3.y; p[14] += vv * a3.z; p[15] += vv * a3.w;
    }
    #pragma unroll
    for (int st = 1; st < 16; st <<= 1)
      #pragma unroll
      for (int r = 0; r < 16; ++r) p[r] += __shfl_xor(p[r], st);
    __shared__ float sred[16][16];
    const int grp = threadIdx.x >> 4;
    if ((threadIdx.x & 15) == 0) {
      #pragma unroll
      for (int r = 0; r < 16; ++r) sred[grp][r] = p[r];
    }
    __syncthreads();
    if (threadIdx.x < 16) {
      float v = 0.f;
      #pragma unroll
      for (int gg = 0; gg < 16; ++gg) v += sred[gg][threadIdx.x];
      if (ex) v *= dvec[threadIdx.x];
      tmp1b[(size_t)row * 32 + threadIdx.x] = f2b(v);
      tmp1b[(size_t)row * 32 + 16 + threadIdx.x] = 0;
    }
  }
}

// ---------------- bf16 MFMA GEMM: C = A[M,K] * W[N,K]^T + bias (+adapter kstep, epilogues) ----------------
template<int MODE>
__global__ __launch_bounds__(256)
void gemm_bt(const u16* __restrict__ A, const u16* __restrict__ W,
             const float* __restrict__ bias, u16* __restrict__ Cb,
             float* __restrict__ Cf, const float* __restrict__ resid,
             const u16* __restrict__ Aad, const u16* __restrict__ BadL,
             const u16* __restrict__ BadV, const int* __restrict__ nbp,
             int M, int N, int K)
{
  __shared__ u16 As[128 * 32];
  __shared__ u16 Bs[128 * 32];
  const int tid   = threadIdx.x;
  const int lane  = tid & 63;
  const int wid   = tid >> 6;
  const int wr    = wid >> 1;
  const int wc    = wid & 1;
  const int lr    = lane & 15;
  const int lk    = (lane >> 4) << 3;
  const int m0    = blockIdx.x * 128;
  const int n0    = blockIdx.y * 128;
  const int kg    = (tid & 3) * 8;
  const int row_a = tid >> 2;

  fx4 acc[4][4];
  const fx4 zero = {0.f, 0.f, 0.f, 0.f};
  #pragma unroll
  for (int i = 0; i < 4; ++i)
    #pragma unroll
    for (int j = 0; j < 4; ++j) acc[i][j] = zero;

  for (int k0 = 0; k0 < K; k0 += 32) {
    #pragma unroll
    for (int u = 0; u < 2; ++u) {
      const int row = u * 64 + row_a;
      const int li  = u * 256 + tid;
      gload16(A + (size_t)(m0 + row) * K + k0 + kg, &As[li * 8]);
      gload16(W + (size_t)(n0 + row) * K + k0 + kg, &Bs[li * 8]);
    }
    __syncthreads();
    s16x8 av[4], bv[4];
    #pragma unroll
    for (int i = 0; i < 4; ++i)
      av[i] = *(const s16x8*)&As[(wr * 64 + i * 16 + lr) * 32 + lk];
    #pragma unroll
    for (int j = 0; j < 4; ++j)
      bv[j] = *(const s16x8*)&Bs[(wc * 64 + j * 16 + lr) * 32 + lk];
    #pragma unroll
    for (int i = 0; i < 4; ++i)
      #pragma unroll
      for (int j = 0; j < 4; ++j)
        acc[i][j] = __builtin_amdgcn_mfma_f32_16x16x32_bf16(av[i], bv[j], acc[i][j], 0, 0, 0);
    __syncthreads();
  }

  if (MODE >= 1) {
    const int nb = *nbp;
    const u16* Bad = ((m0 % S_) >= nb) ? BadV : BadL;
    #pragma unroll
    for (int u = 0; u < 2; ++u) {
      const int row = u * 64 + row_a;
      const int li  = u * 256 + tid;
      gload16(Aad + (size_t)(m0 + row) * 32 + kg, &As[li * 8]);
      gload16(Bad + (size_t)(n0 + row) * 32 + kg, &Bs[li * 8]);
    }
    __syncthreads();
    s16x8 av[4], bv[4];
    #pragma unroll
    for (int i = 0; i < 4; ++i)
      av[i] = *(const s16x8*)&As[(wr * 64 + i * 16 + lr) * 32 + lk];
    #pragma unroll
    for (int j = 0; j < 4; ++j)
      bv[j] = *(const s16x8*)&Bs[(wc * 64 + j * 16 + lr) * 32 + lk];
    #pragma unroll
    for (int i = 0; i < 4; ++i)
      #pragma unroll
      for (int j = 0; j < 4; ++j)
        acc[i][j] = __builtin_amdgcn_mfma_f32_16x16x32_bf16(av[i], bv[j], acc[i][j], 0, 0, 0);
    __syncthreads();
  }

  const int rb = (lane >> 4) * 4;
  #pragma unroll
  for (int j = 0; j < 4; ++j) {
    const int col = n0 + wc * 64 + j * 16 + lr;
    const float bj = bias ? bias[col] : 0.f;
    #pragma unroll
    for (int i = 0; i < 4; ++i) {
      const int row = m0 + wr * 64 + i * 16 + rb;
      #pragma unroll
      for (int r = 0; r < 4; ++r) {
        const float val = acc[i][j][r] + bj;
        const size_t idx = (size_t)(row + r) * N + col;
        if (MODE == 1)      Cb[idx] = f2b(gelu_f(val));
        else if (MODE == 2) Cf[idx] = resid[idx] + val;
        else                Cb[idx] = f2b(val);
      }
    }
  }
}

// ---------------- skinny down-projection: part[ks][M][16] = hid_kslice @ A2t^T ----------------
__global__ __launch_bounds__(256)
void downproj(const u16* __restrict__ hid, const u16* __restrict__ A2tL,
              const u16* __restrict__ A2tV, float* __restrict__ part,
              const int* __restrict__ nbp)
{
  __shared__ u16 As[128 * 32];
  __shared__ u16 Bs[16 * 32];
  const int tid  = threadIdx.x;
  const int lane = tid & 63;
  const int w    = tid >> 6;
  const int lr   = lane & 15;
  const int lk   = (lane >> 4) << 3;
  const int m0   = blockIdx.x * 128;
  const int kb   = blockIdx.y * (FF_ / 8);
  const int nb   = *nbp;
  const u16* A2t = ((m0 % S_) >= nb) ? A2tV : A2tL;
  const int kg    = (tid & 3) * 8;
  const int row_a = tid >> 2;

  const fx4 zero = {0.f, 0.f, 0.f, 0.f};
  fx4 acc[2]; acc[0] = zero; acc[1] = zero;

  for (int k0 = kb; k0 < kb + FF_ / 8; k0 += 32) {
    #pragma unroll
    for (int u = 0; u < 2; ++u)
      gload16(hid + (size_t)(m0 + u * 64 + row_a) * FF_ + k0 + kg,
              &As[(u * 256 + tid) * 8]);
    if (tid < 64)
      gload16(A2t + (size_t)(tid >> 2) * FF_ + k0 + kg, &Bs[tid * 8]);
    __syncthreads();
    s16x8 bv = *(const s16x8*)&Bs[lr * 32 + lk];
    #pragma unroll
    for (int i = 0; i < 2; ++i) {
      s16x8 av = *(const s16x8*)&As[(w * 32 + i * 16 + lr) * 32 + lk];
      acc[i] = __builtin_amdgcn_mfma_f32_16x16x32_bf16(av, bv, acc[i], 0, 0, 0);
    }
    __syncthreads();
  }

  const int rb = (lane >> 4) * 4;
  #pragma unroll
  for (int i = 0; i < 2; ++i)
    #pragma unroll
    for (int r = 0; r < 4; ++r)
      part[(size_t)blockIdx.y * M_ * 16 +
           (size_t)(m0 + w * 32 + i * 16 + rb + r) * 16 + lr] = acc[i][r];
}

// ---------------- reduce partials -> tmp2b bf16 [M,32] ----------------
__global__ __launch_bounds__(256)
void reduce_dp(const float* __restrict__ part, const float* __restrict__ d2,
               u16* __restrict__ tmp2b, const int* __restrict__ nbp)
{
  const int idx = blockIdx.x * 256 + threadIdx.x;   // m*16 + r
  const int m = idx >> 4, r = idx & 15;
  const int nb = *nbp;
  float s = 0.f;
  #pragma unroll
  for (int ks = 0; ks < 8; ++ks) s += part[(size_t)ks * M_ * 16 + idx];
  if ((m % S_) >= nb) s *= d2[r];
  tmp2b[(size_t)m * 32 + r] = f2b(s);
  tmp2b[(size_t)m * 32 + 16 + r] = 0;
}

// ---------------- MFMA flash attention: KBLK=128, double-buffered K/V pipeline ----------------
// 1D grid 1536 = 8 XCD x 192, swizzled so one (b,h)'s 16 q-blocks share an XCD.
// Per tile: issue K(t+1) gload_lds + V(t+1) reg loads BEFORE computing tile t;
// V ds_write mid-tile; single end-of-tile barrier (its vmcnt(0) drain is hidden
// behind the tile's compute).
__global__ __launch_bounds__(256)
void attn_mfma(const u16* __restrict__ qkv, const float* __restrict__ mask,
               u16* __restrict__ o)
{
  __shared__ u16 Kl[2][128 * 64];   // row k, col d, swz col^((k&7)<<3)
  __shared__ u16 Vt[2][64 * 128];   // row d, col k, swz k^(((d&7)^((d>>3)&7))<<3)
  __shared__ u16 QP[4 * 2048];      // prologue: Q 64x64; then per-wave P 16x128

  const int tid  = threadIdx.x;
  const int lane = tid & 63;
  const int wq   = tid >> 6;
  const int lr   = lane & 15;
  const int hi   = lane >> 4;
  // XCD swizzle (bijective: 1536 = 8*192)
  const int lin = blockIdx.x;
  const int vsw = (lin & 7) * 192 + (lin >> 3);
  const int qb  = vsw & 15;
  const int bh  = vsw >> 4;
  const int b    = bh / H_;
  const int h    = bh % H_;
  const size_t tok0 = (size_t)b * S_ + (size_t)qb * 64;
  const size_t colh = (size_t)h * HD_;

  const int va  = tid >> 3;          // V staging: k-rows 4*va..+3
  const int vc8 = (tid & 7) * 8;     // V staging: d cols vc8..+7

  // ---- prologue: issue Q + K(0) gloads, V(0) reg loads ----
  #pragma unroll
  for (int u = 0; u < 2; ++u) {
    const int li = u * 256 + tid;
    const int r  = li >> 3;
    const int cb = ((li & 7) ^ (r & 7)) * 8;
    gload16(qkv + (tok0 + r) * QLD + colh + cb, &QP[li * 8]);
  }
  {
    const size_t ktok = (size_t)b * S_;
    #pragma unroll
    for (int u = 0; u < 4; ++u) {
      const int li = u * 256 + tid;
      const int r  = li >> 3;
      const int cb = ((li & 7) ^ (r & 7)) * 8;
      gload16(qkv + (ktok + r) * QLD + D_ + colh + cb, &Kl[0][li * 8]);
    }
    const u16* vp = qkv + (ktok + 4 * va) * QLD + 2 * D_ + colh + vc8;
    s16x8 w0 = *(const s16x8*)vp;
    s16x8 w1 = *(const s16x8*)(vp + QLD);
    s16x8 w2 = *(const s16x8*)(vp + 2 * QLD);
    s16x8 w3 = *(const s16x8*)(vp + 3 * QLD);
    #pragma unroll
    for (int jj = 0; jj < 8; ++jj) {
      const int d  = vc8 + jj;
      const int sw = ((d & 7) ^ ((d >> 3) & 7)) << 3;
      const int cp = (4 * va) ^ sw;
      *(uint32_t*)&Vt[0][d * 128 + cp] =
          (uint32_t)(u16)w0[jj] | ((uint32_t)(u16)w1[jj] << 16);
      *(uint32_t*)&Vt[0][d * 128 + cp + 2] =
          (uint32_t)(u16)w2[jj] | ((uint32_t)(u16)w3[jj] << 16);
    }
  }
  __syncthreads();   // Q + K0 visible, V0 writes visible

  s16x8 qa[2];
  {
    const int qrow = wq * 16 + lr;
    #pragma unroll
    for (int ks = 0; ks < 2; ++ks)
      qa[ks] = *(const s16x8*)&QP[qrow * 64 + ((ks * 32 + hi * 8) ^ ((qrow & 7) << 3))];
  }
  __syncthreads();   // all qa reads done before any P overwrite of QP

  const fx4 zero = {0.f, 0.f, 0.f, 0.f};
  fx4 oacc[4];
  #pragma unroll
  for (int dj = 0; dj < 4; ++dj) oacc[dj] = zero;
  float mreg[4], lreg[4];
  #pragma unroll
  for (int r = 0; r < 4; ++r) { mreg[r] = -3.0e38f; lreg[r] = 0.f; }

  const int NT = S_ / KBLK;   // 8
  for (int kt = 0; kt < NT; ++kt) {
    const int cur = kt & 1;
    const int nxt = cur ^ 1;

    // ---- issue next-tile staging (K -> LDS direct, V -> regs) ----
    s16x8 w0, w1, w2, w3;
    if (kt + 1 < NT) {
      const size_t ktokn = (size_t)b * S_ + (size_t)(kt + 1) * KBLK;
      #pragma unroll
      for (int u = 0; u < 4; ++u) {
        const int li = u * 256 + tid;
        const int r  = li >> 3;
        const int cb = ((li & 7) ^ (r & 7)) * 8;
        gload16(qkv + (ktokn + r) * QLD + D_ + colh + cb, &Kl[nxt][li * 8]);
      }
      const u16* vp = qkv + (ktokn + 4 * va) * QLD + 2 * D_ + colh + vc8;
      w0 = *(const s16x8*)vp;
      w1 = *(const s16x8*)(vp + QLD);
      w2 = *(const s16x8*)(vp + 2 * QLD);
      w3 = *(const s16x8*)(vp + 3 * QLD);
    }

    // ---- QK^T from Kl[cur], two register-halves of 4 column-groups ----
    float val[8][4];
    #pragma unroll
    for (int jh = 0; jh < 2; ++jh) {
      s16x8 kb2[4][2];
      #pragma unroll
      for (int j = 0; j < 4; ++j) {
        const int n = (jh * 4 + j) * 16 + lr;
        #pragma unroll
        for (int ks = 0; ks < 2; ++ks)
          kb2[j][ks] = *(const s16x8*)&Kl[cur][n * 64 + ((ks * 32 + hi * 8) ^ ((n & 7) << 3))];
      }
      float mvh[4][4];
      {
        const float* mp = mask + (size_t)(qb * 64 + wq * 16 + hi * 4) * S_
                        + (size_t)kt * KBLK + jh * 64 + lr;
        #pragma unroll
        for (int j = 0; j < 4; ++j)
          #pragma unroll
          for (int r = 0; r < 4; ++r)
            mvh[j][r] = mp[(size_t)r * S_ + j * 16];
      }
      fx4 sf[4];
      #pragma unroll
      for (int j = 0; j < 4; ++j) sf[j] = zero;
      __builtin_amdgcn_s_setprio(1);
      #pragma unroll
      for (int ks = 0; ks < 2; ++ks)
        #pragma unroll
        for (int j = 0; j < 4; ++j)
          sf[j] = __builtin_amdgcn_mfma_f32_16x16x32_bf16(qa[ks], kb2[j][ks], sf[j], 0, 0, 0);
      __builtin_amdgcn_s_setprio(0);
      #pragma unroll
      for (int j = 0; j < 4; ++j)
        #pragma unroll
        for (int r = 0; r < 4; ++r)
          val[jh * 4 + j][r] = sf[j][r] * 0.125f + mvh[j][r];
    }

    // ---- online softmax over 128 cols ----
    #pragma unroll
    for (int r = 0; r < 4; ++r) {
      float mx = val[0][r];
      #pragma unroll
      for (int j = 1; j < 8; ++j) mx = fmaxf(mx, val[j][r]);
      mx = fmaxf(mx, __shfl_xor(mx, 1));
      mx = fmaxf(mx, __shfl_xor(mx, 2));
      mx = fmaxf(mx, __shfl_xor(mx, 4));
      mx = fmaxf(mx, __shfl_xor(mx, 8));
      const float mn  = fmaxf(mreg[r], mx);
      const float fac = __expf(mreg[r] - mn);
      mreg[r] = mn;
      float rs = 0.f;
      #pragma unroll
      for (int j = 0; j < 8; ++j) {
        const float p = __expf(val[j][r] - mn);
        val[j][r] = p;
        rs += p;
      }
      rs += __shfl_xor(rs, 1); rs += __shfl_xor(rs, 2);
      rs += __shfl_xor(rs, 4); rs += __shfl_xor(rs, 8);
      lreg[r] = lreg[r] * fac + rs;
      #pragma unroll
      for (int dj = 0; dj < 4; ++dj) oacc[dj][r] *= fac;
    }

    // ---- P -> wave-private overlay LDS (bf16, swz) ----
    #pragma unroll
    for (int j = 0; j < 8; ++j) {
      const int col = j * 16 + lr;
      #pragma unroll
      for (int r = 0; r < 4; ++r) {
        const int row = hi * 4 + r;
        QP[wq * 2048 + row * 128 + (col ^ ((row & 7) << 3))] = f2b(val[j][r]);
      }
    }

    // ---- write next-tile V (regs -> LDS, opposite buffer) ----
    if (kt + 1 < NT) {
      #pragma unroll
      for (int jj = 0; jj < 8; ++jj) {
        const int d  = vc8 + jj;
        const int sw = ((d & 7) ^ ((d >> 3) & 7)) << 3;
        const int cp = (4 * va) ^ sw;
        *(uint32_t*)&Vt[nxt][d * 128 + cp] =
            (uint32_t)(u16)w0[jj] | ((uint32_t)(u16)w1[jj] << 16);
        *(uint32_t*)&Vt[nxt][d * 128 + cp + 2] =
            (uint32_t)(u16)w2[jj] | ((uint32_t)(u16)w3[jj] << 16);
      }
    }

    // ---- PV from Vt[cur]: 4 K-slices of 32 ----
    #pragma unroll
    for (int ks = 0; ks < 4; ++ks) {
      s16x8 pa = *(const s16x8*)&QP[wq * 2048 + lr * 128 +
                                    ((ks * 32 + hi * 8) ^ ((lr & 7) << 3))];
      s16x8 bv2[4];
      #pragma unroll
      for (int dj = 0; dj < 4; ++dj) {
        const int n  = dj * 16 + lr;
        const int sw = ((n & 7) ^ ((n >> 3) & 7)) << 3;
        bv2[dj] = *(const s16x8*)&Vt[cur][n * 128 + ((ks * 32 + hi * 8) ^ sw)];
      }
      __builtin_amdgcn_s_setprio(1);
      #pragma unroll
      for (int dj = 0; dj < 4; ++dj)
        oacc[dj] = __builtin_amdgcn_mfma_f32_16x16x32_bf16(pa, bv2[dj], oacc[dj], 0, 0, 0);
      __builtin_amdgcn_s_setprio(0);
    }

    __syncthreads();   // staged K(t+1)/V(t+1) visible; drain hidden by compute
  }

  // ---- epilogue: O /= l, write ----
  #pragma unroll
  for (int r = 0; r < 4; ++r) {
    const float inv = 1.f / lreg[r];
    const size_t grow = (tok0 + wq * 16 + hi * 4 + r) * D_ + colh;
    #pragma unroll
    for (int dj = 0; dj < 4; ++dj)
      o[grow + dj * 16 + lr] = f2b(oacc[dj][r] * inv);
  }
}

extern "C" void kernel_launch(void* const* d_in, const int* in_sizes, int n_in,
                              void* d_out, int out_size, void* d_ws, size_t ws_size,
                              hipStream_t stream)
{
  const float* x      = (const float*)d_in[0];
  const float* mask   = (const float*)d_in[1];
  const float* n1g    = (const float*)d_in[2];
  const float* n1b    = (const float*)d_in[3];
  const float* q_w    = (const float*)d_in[4];
  const float* q_bv   = (const float*)d_in[5];
  const float* k_w    = (const float*)d_in[6];
  const float* k_bv   = (const float*)d_in[7];
  const float* v_w    = (const float*)d_in[8];
  const float* v_bv   = (const float*)d_in[9];
  const float* o_w    = (const float*)d_in[10];
  const float* o_bv   = (const float*)d_in[11];
  const float* n2g    = (const float*)d_in[12];
  const float* n2b    = (const float*)d_in[13];
  const float* fc1_w  = (const float*)d_in[14];
  const float* fc1_bv = (const float*)d_in[15];
  const float* fc2_w  = (const float*)d_in[16];
  const float* fc2_bv = (const float*)d_in[17];
  const float* lora1A = (const float*)d_in[18];
  const float* lora1B = (const float*)d_in[19];
  const float* lora2A = (const float*)d_in[20];
  const float* lora2B = (const float*)d_in[21];
  const float* vera1A = (const float*)d_in[22];
  const float* vera1B = (const float*)d_in[23];
  const float* vera2A = (const float*)d_in[24];
  const float* vera2B = (const float*)d_in[25];
  const float* e1d    = (const float*)d_in[26];
  const float* e1b    = (const float*)d_in[27];
  const float* e2d    = (const float*)d_in[28];
  const float* e2b    = (const float*)d_in[29];
  const int*   nbp    = (const int*)d_in[30];

  char* wsb = (char*)d_ws;
  u16* h1    = (u16*)wsb; wsb += (size_t)M_ * D_ * 2;       // 12.6 MB
  u16* qkv   = (u16*)wsb; wsb += (size_t)M_ * QLD * 2;      // 37.7 MB
  u16* attno = (u16*)wsb; wsb += (size_t)M_ * D_ * 2;
  u16* oproj = (u16*)wsb; wsb += (size_t)M_ * D_ * 2;
  u16* n2    = (u16*)wsb; wsb += (size_t)M_ * D_ * 2;
  u16* wqkv  = (u16*)wsb; wsb += (size_t)QLD * D_ * 2;
  u16* wo    = (u16*)wsb; wsb += (size_t)D_ * D_ * 2;
  u16* wfc1  = (u16*)wsb; wsb += (size_t)FF_ * D_ * 2;
  u16* wfc2  = (u16*)wsb; wsb += (size_t)D_ * FF_ * 2;
  u16* tmp1b = (u16*)wsb; wsb += (size_t)M_ * 32 * 2;
  u16* tmp2b = (u16*)wsb; wsb += (size_t)M_ * 32 * 2;
  u16* up1L  = (u16*)wsb; wsb += (size_t)FF_ * 32 * 2;
  u16* up1V  = (u16*)wsb; wsb += (size_t)FF_ * 32 * 2;
  u16* up2L  = (u16*)wsb; wsb += (size_t)D_ * 32 * 2;
  u16* up2V  = (u16*)wsb; wsb += (size_t)D_ * 32 * 2;
  u16* a2tL  = (u16*)wsb; wsb += (size_t)16 * FF_ * 2;
  u16* a2tV  = (u16*)wsb; wsb += (size_t)16 * FF_ * 2;
  float* qkvb = (float*)wsb; wsb += (size_t)QLD * 4;
  float* part = (float*)wsb; wsb += (size_t)8 * M_ * 16 * 4; // 4 MB
  u16* hidb = h1;   // [M,FF] bf16 aliases h1+qkv (both dead by fc1)

  const int totq = (4 * D_ * D_ + 2 * FF_ * D_) / 4;
  cvt_all<<<totq / 256, 256, 0, stream>>>(q_w, k_w, v_w, o_w, fc1_w, fc2_w,
                                          wqkv, wo, wfc1, wfc2);
  prep_all<<<FF_ / 256, 256, 0, stream>>>(q_bv, k_bv, v_bv, qkvb,
                                          lora1B, vera1B, e1b, up1L, up1V,
                                          lora2B, vera2B, e2b, up2L, up2V,
                                          lora2A, vera2A, a2tL, a2tV);

  ln_k<false><<<M_, 256, 0, stream>>>(x, nullptr, n1g, n1b, h1, nullptr,
                                      nullptr, nullptr, nullptr, nullptr, nullptr);
  gemm_bt<0><<<dim3(M_/128, QLD/128), 256, 0, stream>>>(
      h1, wqkv, qkvb, qkv, nullptr, nullptr, nullptr, nullptr, nullptr, nullptr,
      M_, QLD, D_);
  attn_mfma<<<(S_/64) * (B_*H_), 256, 0, stream>>>(qkv, mask, attno);
  gemm_bt<0><<<dim3(M_/128, D_/128), 256, 0, stream>>>(
      attno, wo, o_bv, oproj, nullptr, nullptr, nullptr, nullptr, nullptr, nullptr,
      M_, D_, D_);

  ln_k<true><<<M_, 256, 0, stream>>>(x, oproj, n2g, n2b, n2, (float*)d_out,
                                     lora1A, vera1A, e1d, tmp1b, nbp);

  gemm_bt<1><<<dim3(M_/128, FF_/128), 256, 0, stream>>>(
      n2, wfc1, fc1_bv, hidb, nullptr, nullptr, tmp1b, up1L, up1V, nbp,
      M_, FF_, D_);

  downproj<<<dim3(M_/128, 8), 256, 0, stream>>>(hidb, a2tL, a2tV, part, nbp);
  reduce_dp<<<M_*16/256, 256, 0, stream>>>(part, e2d, tmp2b, nbp);

  gemm_bt<2><<<dim3(M_/128, D_/128), 256, 0, stream>>>(
      hidb, wfc2, fc2_bv, nullptr, (float*)d_out, (const float*)d_out,
      tmp2b, up2L, up2V, nbp, M_, D_, FF_);
}

// Round 7
// 380.687 us; speedup vs baseline: 3.9567x; 1.0042x over previous
//
#include <hip/hip_runtime.h>
#include <stdint.h>

#define B_  8
#define S_  1024
#define D_  768
#define H_  12
#define HD_ 64
#define FF_ 3072
#define M_  (B_*S_)   // 8192 tokens
#define R_  16
#define QLD 2304      // packed QKV row stride
#define KBLK 128

typedef unsigned short u16;
typedef short s16x8 __attribute__((ext_vector_type(8)));   // 8 bf16 (4 VGPRs)
typedef float fx4  __attribute__((ext_vector_type(4)));    // 4 fp32 acc

__device__ __forceinline__ float b2f(u16 u) {
  union { unsigned int i; float f; } c; c.i = ((unsigned int)u) << 16; return c.f;
}
__device__ __forceinline__ u16 f2b(float f) {   // RNE f32->bf16
  union { float f; unsigned int i; } c; c.f = f;
  unsigned int x = c.i;
  x += 0x7FFFu + ((x >> 16) & 1u);
  return (u16)(x >> 16);
}
__device__ __forceinline__ float gelu_f(float x) {  // jax.nn.gelu approximate=True (tanh)
  float u = 0.7978845608028654f * (x + 0.044715f * x * x * x);
  float e = __expf(2.f * u);
  float t = 1.f - 2.f / (e + 1.f);
  return 0.5f * x * (1.f + t);
}
__device__ __forceinline__ void gload16(const u16* gsrc, u16* ldst) {
  __builtin_amdgcn_global_load_lds(
      (__attribute__((address_space(1))) void*)(gsrc),
      (__attribute__((address_space(3))) void*)(ldst), 16, 0, 0);
}

// ---------------- all weights f32 -> bf16, one kernel ----------------
__global__ __launch_bounds__(256)
void cvt_all(const float* __restrict__ q_w, const float* __restrict__ k_w,
             const float* __restrict__ v_w, const float* __restrict__ o_w,
             const float* __restrict__ fc1_w, const float* __restrict__ fc2_w,
             u16* __restrict__ wqkv, u16* __restrict__ wo,
             u16* __restrict__ wfc1, u16* __restrict__ wfc2)
{
  const int i = blockIdx.x * 256 + threadIdx.x;   // quad index
  const int q1  = D_ * D_ / 4;
  const int fd4 = FF_ * D_ / 4;
  const float* s; u16* d; int j;
  if      (i <     q1)       { s = q_w;   d = wqkv;            j = i; }
  else if (i < 2 * q1)       { s = k_w;   d = wqkv + D_*D_;    j = i - q1; }
  else if (i < 3 * q1)       { s = v_w;   d = wqkv + 2*D_*D_;  j = i - 2*q1; }
  else if (i < 4 * q1)       { s = o_w;   d = wo;              j = i - 3*q1; }
  else if (i < 4 * q1 + fd4) { s = fc1_w; d = wfc1;            j = i - 4*q1; }
  else                       { s = fc2_w; d = wfc2;            j = i - 4*q1 - fd4; }
  const float4 f = ((const float4*)s)[j];
  ushort4 o4; o4.x = f2b(f.x); o4.y = f2b(f.y); o4.z = f2b(f.z); o4.w = f2b(f.w);
  ((ushort4*)d)[j] = o4;
}

// ---------------- all small preps, one kernel ----------------
__global__ __launch_bounds__(256)
void prep_all(const float* __restrict__ q_bv, const float* __restrict__ k_bv,
              const float* __restrict__ v_bv, float* __restrict__ qkvb,
              const float* __restrict__ lora1B, const float* __restrict__ vera1B,
              const float* __restrict__ e1b, u16* __restrict__ up1L, u16* __restrict__ up1V,
              const float* __restrict__ lora2B, const float* __restrict__ vera2B,
              const float* __restrict__ e2b, u16* __restrict__ up2L, u16* __restrict__ up2V,
              const float* __restrict__ lora2A, const float* __restrict__ vera2A,
              u16* __restrict__ a2tL, u16* __restrict__ a2tV)
{
  const int f = blockIdx.x * 256 + threadIdx.x;   // 0..FF_-1
  if (f < QLD)
    qkvb[f] = (f < D_) ? q_bv[f] : (f < 2 * D_) ? k_bv[f - D_] : v_bv[f - 2 * D_];
  {
    const float ev = e1b[f];
    #pragma unroll
    for (int r = 0; r < 16; ++r) {
      up1L[(size_t)f * 32 + r] = f2b(lora1B[(size_t)r * FF_ + f]);
      up1V[(size_t)f * 32 + r] = f2b(vera1B[(size_t)r * FF_ + f] * ev);
      up1L[(size_t)f * 32 + 16 + r] = 0;
      up1V[(size_t)f * 32 + 16 + r] = 0;
    }
  }
  {
    const float4* apl = (const float4*)(lora2A + (size_t)f * 16);
    const float4* apv = (const float4*)(vera2A + (size_t)f * 16);
    #pragma unroll
    for (int q4 = 0; q4 < 4; ++q4) {
      const float4 l4 = apl[q4], v4 = apv[q4];
      a2tL[(size_t)(q4*4+0) * FF_ + f] = f2b(l4.x);
      a2tL[(size_t)(q4*4+1) * FF_ + f] = f2b(l4.y);
      a2tL[(size_t)(q4*4+2) * FF_ + f] = f2b(l4.z);
      a2tL[(size_t)(q4*4+3) * FF_ + f] = f2b(l4.w);
      a2tV[(size_t)(q4*4+0) * FF_ + f] = f2b(v4.x);
      a2tV[(size_t)(q4*4+1) * FF_ + f] = f2b(v4.y);
      a2tV[(size_t)(q4*4+2) * FF_ + f] = f2b(v4.z);
      a2tV[(size_t)(q4*4+3) * FF_ + f] = f2b(v4.w);
    }
  }
  if (f < D_) {
    const float ev = e2b[f];
    #pragma unroll
    for (int r = 0; r < 16; ++r) {
      up2L[(size_t)f * 32 + r] = f2b(lora2B[(size_t)r * D_ + f]);
      up2V[(size_t)f * 32 + r] = f2b(vera2B[(size_t)r * D_ + f] * ev);
      up2L[(size_t)f * 32 + 16 + r] = 0;
      up2V[(size_t)f * 32 + 16 + r] = 0;
    }
  }
}

// ---------------- LayerNorm (+residual add, + fused rank-16 down-projection) ----------------
template<bool ADD>
__global__ __launch_bounds__(256)
void ln_k(const float* __restrict__ x, const u16* __restrict__ add,
          const float* __restrict__ g, const float* __restrict__ beta,
          u16* __restrict__ outb, float* __restrict__ xsum,
          const float* __restrict__ Alora, const float* __restrict__ Avera,
          const float* __restrict__ dvec, u16* __restrict__ tmp1b,
          const int* __restrict__ nbp)
{
  const int row = blockIdx.x;
  const size_t base = (size_t)row * D_;
  float v0[3]; float s = 0.f, sq = 0.f;
  #pragma unroll
  for (int i = 0; i < 3; ++i) {
    const int d = threadIdx.x + i * 256;
    float val = x[base + d];
    if (ADD) { val += b2f(add[base + d]); xsum[base + d] = val; }
    v0[i] = val; s += val; sq += val * val;
  }
  #pragma unroll
  for (int mm = 32; mm >= 1; mm >>= 1) { s += __shfl_xor(s, mm); sq += __shfl_xor(sq, mm); }
  __shared__ float ss[4], s2[4];
  if ((threadIdx.x & 63) == 0) { ss[threadIdx.x >> 6] = s; s2[threadIdx.x >> 6] = sq; }
  __syncthreads();
  s  = ss[0] + ss[1] + ss[2] + ss[3];
  sq = s2[0] + s2[1] + s2[2] + s2[3];
  const float mean = s * (1.f / D_);
  const float var  = sq * (1.f / D_) - mean * mean;
  const float rs   = rsqrtf(var + 1e-6f);
  float nv[3];
  #pragma unroll
  for (int i = 0; i < 3; ++i) {
    const int d = threadIdx.x + i * 256;
    nv[i] = (v0[i] - mean) * rs * g[d] + beta[d];
    outb[base + d] = f2b(nv[i]);
  }

  if (ADD) {
    const int nb = *nbp;
    const bool ex = (row % S_) >= nb;
    const float* Am = ex ? Avera : Alora;
    float p[16];
    #pragma unroll
    for (int r = 0; r < 16; ++r) p[r] = 0.f;
    #pragma unroll
    for (int i = 0; i < 3; ++i) {
      const int d = threadIdx.x + i * 256;
      const float4* ap = (const float4*)(Am + (size_t)d * R_);
      const float4 a0 = ap[0], a1 = ap[1], a2 = ap[2], a3 = ap[3];
      const float vv = nv[i];
      p[0]  += vv * a0.x; p[1]  += vv * a0.y; p[2]  += vv * a0.z; p[3]  += vv * a0.w;
      p[4]  += vv * a1.x; p[5]  += vv * a1.y; p[6]  += vv * a1.z; p[7]  += vv * a1.w;
      p[8]  += vv * a2.x; p[9]  += vv * a2.y; p[10] += vv * a2.z; p[11] += vv * a2.w;
      p[12] += vv * a3.x; p[13] += vv * a3.y; p[14] += vv * a3.z; p[15] += vv * a3.w;
    }
    #pragma unroll
    for (int st = 1; st < 16; st <<= 1)
      #pragma unroll
      for (int r = 0; r < 16; ++r) p[r] += __shfl_xor(p[r], st);
    __shared__ float sred[16][16];
    const int grp = threadIdx.x >> 4;
    if ((threadIdx.x & 15) == 0) {
      #pragma unroll
      for (int r = 0; r < 16; ++r) sred[grp][r] = p[r];
    }
    __syncthreads();
    if (threadIdx.x < 16) {
      float v = 0.f;
      #pragma unroll
      for (int gg = 0; gg < 16; ++gg) v += sred[gg][threadIdx.x];
      if (ex) v *= dvec[threadIdx.x];
      tmp1b[(size_t)row * 32 + threadIdx.x] = f2b(v);
      tmp1b[(size_t)row * 32 + 16 + threadIdx.x] = 0;
    }
  }
}

// ---------------- bf16 MFMA GEMM: C = A[M,K] * W[N,K]^T + bias (+adapter kstep, epilogues) ----------------
// 1D grid with XCD-chunked swizzle (nwg divisible by 8; n-fastest inside chunk).
template<int MODE>
__global__ __launch_bounds__(256)
void gemm_bt(const u16* __restrict__ A, const u16* __restrict__ W,
             const float* __restrict__ bias, u16* __restrict__ Cb,
             float* __restrict__ Cf, const float* __restrict__ resid,
             const u16* __restrict__ Aad, const u16* __restrict__ BadL,
             const u16* __restrict__ BadV, const int* __restrict__ nbp,
             int M, int N, int K)
{
  __shared__ u16 As[128 * 32];
  __shared__ u16 Bs[128 * 32];
  const int tid   = threadIdx.x;
  const int lane  = tid & 63;
  const int wid   = tid >> 6;
  const int wr    = wid >> 1;
  const int wc    = wid & 1;
  const int lr    = lane & 15;
  const int lk    = (lane >> 4) << 3;
  // XCD-chunked swizzle
  const int gn    = N >> 7;
  const int nwg   = (M >> 7) * gn;
  const int chunk = nwg >> 3;
  const int lin   = blockIdx.x;
  const int swz   = (lin & 7) * chunk + (lin >> 3);
  const int m0    = (swz / gn) * 128;
  const int n0    = (swz % gn) * 128;
  const int kg    = (tid & 3) * 8;
  const int row_a = tid >> 2;

  fx4 acc[4][4];
  const fx4 zero = {0.f, 0.f, 0.f, 0.f};
  #pragma unroll
  for (int i = 0; i < 4; ++i)
    #pragma unroll
    for (int j = 0; j < 4; ++j) acc[i][j] = zero;

  for (int k0 = 0; k0 < K; k0 += 32) {
    #pragma unroll
    for (int u = 0; u < 2; ++u) {
      const int row = u * 64 + row_a;
      const int li  = u * 256 + tid;
      gload16(A + (size_t)(m0 + row) * K + k0 + kg, &As[li * 8]);
      gload16(W + (size_t)(n0 + row) * K + k0 + kg, &Bs[li * 8]);
    }
    __syncthreads();
    s16x8 av[4], bv[4];
    #pragma unroll
    for (int i = 0; i < 4; ++i)
      av[i] = *(const s16x8*)&As[(wr * 64 + i * 16 + lr) * 32 + lk];
    #pragma unroll
    for (int j = 0; j < 4; ++j)
      bv[j] = *(const s16x8*)&Bs[(wc * 64 + j * 16 + lr) * 32 + lk];
    #pragma unroll
    for (int i = 0; i < 4; ++i)
      #pragma unroll
      for (int j = 0; j < 4; ++j)
        acc[i][j] = __builtin_amdgcn_mfma_f32_16x16x32_bf16(av[i], bv[j], acc[i][j], 0, 0, 0);
    __syncthreads();
  }

  if (MODE >= 1) {
    const int nbb = *nbp;
    const u16* Bad = ((m0 % S_) >= nbb) ? BadV : BadL;
    #pragma unroll
    for (int u = 0; u < 2; ++u) {
      const int row = u * 64 + row_a;
      const int li  = u * 256 + tid;
      gload16(Aad + (size_t)(m0 + row) * 32 + kg, &As[li * 8]);
      gload16(Bad + (size_t)(n0 + row) * 32 + kg, &Bs[li * 8]);
    }
    __syncthreads();
    s16x8 av[4], bv[4];
    #pragma unroll
    for (int i = 0; i < 4; ++i)
      av[i] = *(const s16x8*)&As[(wr * 64 + i * 16 + lr) * 32 + lk];
    #pragma unroll
    for (int j = 0; j < 4; ++j)
      bv[j] = *(const s16x8*)&Bs[(wc * 64 + j * 16 + lr) * 32 + lk];
    #pragma unroll
    for (int i = 0; i < 4; ++i)
      #pragma unroll
      for (int j = 0; j < 4; ++j)
        acc[i][j] = __builtin_amdgcn_mfma_f32_16x16x32_bf16(av[i], bv[j], acc[i][j], 0, 0, 0);
    __syncthreads();
  }

  const int rb = (lane >> 4) * 4;
  #pragma unroll
  for (int j = 0; j < 4; ++j) {
    const int col = n0 + wc * 64 + j * 16 + lr;
    const float bj = bias ? bias[col] : 0.f;
    #pragma unroll
    for (int i = 0; i < 4; ++i) {
      const int row = m0 + wr * 64 + i * 16 + rb;
      #pragma unroll
      for (int r = 0; r < 4; ++r) {
        const float val = acc[i][j][r] + bj;
        const size_t idx = (size_t)(row + r) * N + col;
        if (MODE == 1)      Cb[idx] = f2b(gelu_f(val));
        else if (MODE == 2) Cf[idx] = resid[idx] + val;
        else                Cb[idx] = f2b(val);
      }
    }
  }
}

// ---------------- skinny down-projection: part[ks][M][16] = hid_kslice @ A2t^T ----------------
__global__ __launch_bounds__(256)
void downproj(const u16* __restrict__ hid, const u16* __restrict__ A2tL,
              const u16* __restrict__ A2tV, float* __restrict__ part,
              const int* __restrict__ nbp)
{
  __shared__ u16 As[128 * 32];
  __shared__ u16 Bs[16 * 32];
  const int tid  = threadIdx.x;
  const int lane = tid & 63;
  const int w    = tid >> 6;
  const int lr   = lane & 15;
  const int lk   = (lane >> 4) << 3;
  const int m0   = blockIdx.x * 128;
  const int kb   = blockIdx.y * (FF_ / 8);
  const int nb   = *nbp;
  const u16* A2t = ((m0 % S_) >= nb) ? A2tV : A2tL;
  const int kg    = (tid & 3) * 8;
  const int row_a = tid >> 2;

  const fx4 zero = {0.f, 0.f, 0.f, 0.f};
  fx4 acc[2]; acc[0] = zero; acc[1] = zero;

  for (int k0 = kb; k0 < kb + FF_ / 8; k0 += 32) {
    #pragma unroll
    for (int u = 0; u < 2; ++u)
      gload16(hid + (size_t)(m0 + u * 64 + row_a) * FF_ + k0 + kg,
              &As[(u * 256 + tid) * 8]);
    if (tid < 64)
      gload16(A2t + (size_t)(tid >> 2) * FF_ + k0 + kg, &Bs[tid * 8]);
    __syncthreads();
    s16x8 bv = *(const s16x8*)&Bs[lr * 32 + lk];
    #pragma unroll
    for (int i = 0; i < 2; ++i) {
      s16x8 av = *(const s16x8*)&As[(w * 32 + i * 16 + lr) * 32 + lk];
      acc[i] = __builtin_amdgcn_mfma_f32_16x16x32_bf16(av, bv, acc[i], 0, 0, 0);
    }
    __syncthreads();
  }

  const int rb = (lane >> 4) * 4;
  #pragma unroll
  for (int i = 0; i < 2; ++i)
    #pragma unroll
    for (int r = 0; r < 4; ++r)
      part[(size_t)blockIdx.y * M_ * 16 +
           (size_t)(m0 + w * 32 + i * 16 + rb + r) * 16 + lr] = acc[i][r];
}

// ---------------- reduce partials -> tmp2b bf16 [M,32] ----------------
__global__ __launch_bounds__(256)
void reduce_dp(const float* __restrict__ part, const float* __restrict__ d2,
               u16* __restrict__ tmp2b, const int* __restrict__ nbp)
{
  const int idx = blockIdx.x * 256 + threadIdx.x;   // m*16 + r
  const int m = idx >> 4, r = idx & 15;
  const int nb = *nbp;
  float s = 0.f;
  #pragma unroll
  for (int ks = 0; ks < 8; ++ks) s += part[(size_t)ks * M_ * 16 + idx];
  if ((m % S_) >= nb) s *= d2[r];
  tmp2b[(size_t)m * 32 + r] = f2b(s);
  tmp2b[(size_t)m * 32 + 16 + r] = 0;
}

// ---------------- MFMA flash attention: swapped QK^T (q lane-local), dbuf K/V ----------------
// S[k][q] via mfma(K_frag, Q_frag): each lane owns full row q = wq*16 + (lane&15).
// Softmax: 2-shfl reduce; P packed via v_perm (trunc), 8x ds_write_b64 to swizzled
// wave-private buffer; PV A-frags via 4x ds_read_b128.
__global__ __launch_bounds__(256)
void attn_mfma(const u16* __restrict__ qkv, const float* __restrict__ mask,
               u16* __restrict__ o)
{
  __shared__ u16 Kl[2][128 * 64];   // row k, col d, swz col^((k&7)<<3)
  __shared__ u16 Vt[2][64 * 128];   // row d, col k, swz k^(((d&7)^((d>>3)&7))<<3)
  __shared__ uint32_t Pl[4][1024];  // per-wave P rows [16][64 u32]; prologue: Q 64x64 bf16 overlay

  const int tid  = threadIdx.x;
  const int lane = tid & 63;
  const int wq   = tid >> 6;
  const int lr   = lane & 15;
  const int hi   = lane >> 4;
  // XCD swizzle (bijective: 1536 = 8*192)
  const int lin = blockIdx.x;
  const int vsw = (lin & 7) * 192 + (lin >> 3);
  const int qb  = vsw & 15;
  const int bh  = vsw >> 4;
  const int b    = bh / H_;
  const int h    = bh % H_;
  const size_t tok0 = (size_t)b * S_ + (size_t)qb * 64;
  const size_t colh = (size_t)h * HD_;

  const int va  = tid >> 3;          // V staging: k-rows 4*va..+3
  const int vc8 = (tid & 7) * 8;     // V staging: d cols vc8..+7
  u16* qstage = (u16*)&Pl[0][0];

  // ---- prologue: issue Q + K(0) gloads, V(0) reg loads ----
  #pragma unroll
  for (int u = 0; u < 2; ++u) {
    const int li = u * 256 + tid;
    const int r  = li >> 3;
    const int cb = ((li & 7) ^ (r & 7)) * 8;
    gload16(qkv + (tok0 + r) * QLD + colh + cb, &qstage[li * 8]);
  }
  {
    const size_t ktok = (size_t)b * S_;
    #pragma unroll
    for (int u = 0; u < 4; ++u) {
      const int li = u * 256 + tid;
      const int r  = li >> 3;
      const int cb = ((li & 7) ^ (r & 7)) * 8;
      gload16(qkv + (ktok + r) * QLD + D_ + colh + cb, &Kl[0][li * 8]);
    }
    const u16* vp = qkv + (ktok + 4 * va) * QLD + 2 * D_ + colh + vc8;
    s16x8 w0 = *(const s16x8*)vp;
    s16x8 w1 = *(const s16x8*)(vp + QLD);
    s16x8 w2 = *(const s16x8*)(vp + 2 * QLD);
    s16x8 w3 = *(const s16x8*)(vp + 3 * QLD);
    #pragma unroll
    for (int jj = 0; jj < 8; ++jj) {
      const int d  = vc8 + jj;
      const int sw = ((d & 7) ^ ((d >> 3) & 7)) << 3;
      const int cp = (4 * va) ^ sw;
      *(uint32_t*)&Vt[0][d * 128 + cp] =
          (uint32_t)(u16)w0[jj] | ((uint32_t)(u16)w1[jj] << 16);
      *(uint32_t*)&Vt[0][d * 128 + cp + 2] =
          (uint32_t)(u16)w2[jj] | ((uint32_t)(u16)w3[jj] << 16);
    }
  }
  __syncthreads();   // Q + K0 + V0 visible

  s16x8 qa[2];
  {
    const int qrow = wq * 16 + lr;
    #pragma unroll
    for (int ks = 0; ks < 2; ++ks)
      qa[ks] = *(const s16x8*)&qstage[qrow * 64 + ((ks * 32 + hi * 8) ^ ((qrow & 7) << 3))];
  }
  __syncthreads();   // all qa reads done before any P overwrite of Pl

  const fx4 zero = {0.f, 0.f, 0.f, 0.f};
  fx4 oacc[4];
  #pragma unroll
  for (int dj = 0; dj < 4; ++dj) oacc[dj] = zero;
  float mreg = -3.0e38f, lreg = 0.f;   // per-lane: q-row = wq*16 + lr

  const int NT = S_ / KBLK;   // 8
  for (int kt = 0; kt < NT; ++kt) {
    const int cur = kt & 1;
    const int nxt = cur ^ 1;

    // ---- issue next-tile staging (K -> LDS direct, V -> regs) ----
    s16x8 w0, w1, w2, w3;
    if (kt + 1 < NT) {
      const size_t ktokn = (size_t)b * S_ + (size_t)(kt + 1) * KBLK;
      #pragma unroll
      for (int u = 0; u < 4; ++u) {
        const int li = u * 256 + tid;
        const int r  = li >> 3;
        const int cb = ((li & 7) ^ (r & 7)) * 8;
        gload16(qkv + (ktokn + r) * QLD + D_ + colh + cb, &Kl[nxt][li * 8]);
      }
      const u16* vp = qkv + (ktokn + 4 * va) * QLD + 2 * D_ + colh + vc8;
      w0 = *(const s16x8*)vp;
      w1 = *(const s16x8*)(vp + QLD);
      w2 = *(const s16x8*)(vp + 2 * QLD);
      w3 = *(const s16x8*)(vp + 3 * QLD);
    }

    // ---- QK^T SWAPPED: sf[kg] holds S[k = kg*16+4hi+r][q = wq*16+lr] ----
    float val[8][4];
    #pragma unroll
    for (int jh = 0; jh < 2; ++jh) {
      s16x8 kb2[4][2];
      #pragma unroll
      for (int j = 0; j < 4; ++j) {
        const int n = (jh * 4 + j) * 16 + lr;
        #pragma unroll
        for (int ks = 0; ks < 2; ++ks)
          kb2[j][ks] = *(const s16x8*)&Kl[cur][n * 64 + ((ks * 32 + hi * 8) ^ ((n & 7) << 3))];
      }
      // mask: per-lane float4 (q-row fixed, k contiguous)
      fx4 m4[4];
      {
        const float* mp = mask + (size_t)(qb * 64 + wq * 16 + lr) * S_
                        + (size_t)kt * KBLK + jh * 64 + 4 * hi;
        #pragma unroll
        for (int j = 0; j < 4; ++j)
          m4[j] = *(const fx4*)(mp + j * 16);
      }
      fx4 sf[4];
      #pragma unroll
      for (int j = 0; j < 4; ++j) sf[j] = zero;
      __builtin_amdgcn_s_setprio(1);
      #pragma unroll
      for (int ks = 0; ks < 2; ++ks)
        #pragma unroll
        for (int j = 0; j < 4; ++j)
          sf[j] = __builtin_amdgcn_mfma_f32_16x16x32_bf16(kb2[j][ks], qa[ks], sf[j], 0, 0, 0);
      __builtin_amdgcn_s_setprio(0);
      #pragma unroll
      for (int j = 0; j < 4; ++j)
        #pragma unroll
        for (int r = 0; r < 4; ++r)
          val[jh * 4 + j][r] = sf[j][r] * 0.125f + m4[j][r];
    }

    // ---- online softmax: whole row per lane, 2-shfl reduces ----
    {
      float mk[8];
      #pragma unroll
      for (int kg = 0; kg < 8; ++kg)
        mk[kg] = fmaxf(fmaxf(val[kg][0], val[kg][1]), fmaxf(val[kg][2], val[kg][3]));
      float mx = fmaxf(fmaxf(fmaxf(mk[0], mk[1]), fmaxf(mk[2], mk[3])),
                       fmaxf(fmaxf(mk[4], mk[5]), fmaxf(mk[6], mk[7])));
      mx = fmaxf(mx, __shfl_xor(mx, 16));
      mx = fmaxf(mx, __shfl_xor(mx, 32));
      const float mn  = fmaxf(mreg, mx);
      const float fac = __expf(mreg - mn);
      mreg = mn;
      float sk[8];
      #pragma unroll
      for (int kg = 0; kg < 8; ++kg) {
        #pragma unroll
        for (int r = 0; r < 4; ++r) val[kg][r] = __expf(val[kg][r] - mn);
        sk[kg] = (val[kg][0] + val[kg][1]) + (val[kg][2] + val[kg][3]);
      }
      float rs = ((sk[0] + sk[1]) + (sk[2] + sk[3])) + ((sk[4] + sk[5]) + (sk[6] + sk[7]));
      rs += __shfl_xor(rs, 16);
      rs += __shfl_xor(rs, 32);
      lreg = lreg * fac + rs;
      // redistribute fac to oacc row layout (rows q' = 4hi + r, any lane with lr=q')
      float facr[4];
      #pragma unroll
      for (int r = 0; r < 4; ++r) facr[r] = __shfl(fac, hi * 4 + r);
      #pragma unroll
      for (int dj = 0; dj < 4; ++dj)
        #pragma unroll
        for (int r = 0; r < 4; ++r) oacc[dj][r] *= facr[r];
    }

    // ---- P pack (v_perm trunc) -> wave-private swizzled LDS, 8x b64 ----
    {
      uint32_t* prow = &Pl[wq][lr * 64];
      #pragma unroll
      for (int kg = 0; kg < 8; ++kg) {
        const uint32_t p0 = __builtin_amdgcn_perm(
            __float_as_uint(val[kg][1]), __float_as_uint(val[kg][0]), 0x07060302u);
        const uint32_t p1 = __builtin_amdgcn_perm(
            __float_as_uint(val[kg][3]), __float_as_uint(val[kg][2]), 0x07060302u);
        const int i0 = (8 * kg + 2 * hi) ^ ((lr & 7) << 3);
        uint2 pk; pk.x = p0; pk.y = p1;
        *(uint2*)&prow[i0] = pk;
      }
    }

    // ---- write next-tile V (regs -> LDS, opposite buffer) ----
    if (kt + 1 < NT) {
      #pragma unroll
      for (int jj = 0; jj < 8; ++jj) {
        const int d  = vc8 + jj;
        const int sw = ((d & 7) ^ ((d >> 3) & 7)) << 3;
        const int cp = (4 * va) ^ sw;
        *(uint32_t*)&Vt[nxt][d * 128 + cp] =
            (uint32_t)(u16)w0[jj] | ((uint32_t)(u16)w1[jj] << 16);
        *(uint32_t*)&Vt[nxt][d * 128 + cp + 2] =
            (uint32_t)(u16)w2[jj] | ((uint32_t)(u16)w3[jj] << 16);
      }
    }

    // ---- PV from Vt[cur]: 4 K-slices of 32; A-frag = P[q=lr][ks*32+8hi..+7] ----
    #pragma unroll
    for (int ks = 0; ks < 4; ++ks) {
      const int pbase = (16 * ks + 4 * hi) ^ ((lr & 7) << 3);
      s16x8 pa = *(const s16x8*)&Pl[wq][lr * 64 + pbase];
      s16x8 bv2[4];
      #pragma unroll
      for (int dj = 0; dj < 4; ++dj) {
        const int n  = dj * 16 + lr;
        const int sw = ((n & 7) ^ ((n >> 3) & 7)) << 3;
        bv2[dj] = *(const s16x8*)&Vt[cur][n * 128 + ((ks * 32 + hi * 8) ^ sw)];
      }
      __builtin_amdgcn_s_setprio(1);
      #pragma unroll
      for (int dj = 0; dj < 4; ++dj)
        oacc[dj] = __builtin_amdgcn_mfma_f32_16x16x32_bf16(pa, bv2[dj], oacc[dj], 0, 0, 0);
      __builtin_amdgcn_s_setprio(0);
    }

    __syncthreads();   // staged K(t+1)/V(t+1) visible; drain hidden by compute
  }

  // ---- epilogue: O /= l (per-row inv redistributed), write ----
  {
    const float linv = 1.f / lreg;
    float invr[4];
    #pragma unroll
    for (int r = 0; r < 4; ++r) invr[r] = __shfl(linv, hi * 4 + r);
    #pragma unroll
    for (int r = 0; r < 4; ++r) {
      const size_t grow = (tok0 + wq * 16 + hi * 4 + r) * D_ + colh;
      #pragma unroll
      for (int dj = 0; dj < 4; ++dj)
        o[grow + dj * 16 + lr] = f2b(oacc[dj][r] * invr[r]);
    }
  }
}

extern "C" void kernel_launch(void* const* d_in, const int* in_sizes, int n_in,
                              void* d_out, int out_size, void* d_ws, size_t ws_size,
                              hipStream_t stream)
{
  const float* x      = (const float*)d_in[0];
  const float* mask   = (const float*)d_in[1];
  const float* n1g    = (const float*)d_in[2];
  const float* n1b    = (const float*)d_in[3];
  const float* q_w    = (const float*)d_in[4];
  const float* q_bv   = (const float*)d_in[5];
  const float* k_w    = (const float*)d_in[6];
  const float* k_bv   = (const float*)d_in[7];
  const float* v_w    = (const float*)d_in[8];
  const float* v_bv   = (const float*)d_in[9];
  const float* o_w    = (const float*)d_in[10];
  const float* o_bv   = (const float*)d_in[11];
  const float* n2g    = (const float*)d_in[12];
  const float* n2b    = (const float*)d_in[13];
  const float* fc1_w  = (const float*)d_in[14];
  const float* fc1_bv = (const float*)d_in[15];
  const float* fc2_w  = (const float*)d_in[16];
  const float* fc2_bv = (const float*)d_in[17];
  const float* lora1A = (const float*)d_in[18];
  const float* lora1B = (const float*)d_in[19];
  const float* lora2A = (const float*)d_in[20];
  const float* lora2B = (const float*)d_in[21];
  const float* vera1A = (const float*)d_in[22];
  const float* vera1B = (const float*)d_in[23];
  const float* vera2A = (const float*)d_in[24];
  const float* vera2B = (const float*)d_in[25];
  const float* e1d    = (const float*)d_in[26];
  const float* e1b    = (const float*)d_in[27];
  const float* e2d    = (const float*)d_in[28];
  const float* e2b    = (const float*)d_in[29];
  const int*   nbp    = (const int*)d_in[30];

  char* wsb = (char*)d_ws;
  u16* h1    = (u16*)wsb; wsb += (size_t)M_ * D_ * 2;       // 12.6 MB
  u16* qkv   = (u16*)wsb; wsb += (size_t)M_ * QLD * 2;      // 37.7 MB
  u16* attno = (u16*)wsb; wsb += (size_t)M_ * D_ * 2;
  u16* oproj = (u16*)wsb; wsb += (size_t)M_ * D_ * 2;
  u16* n2    = (u16*)wsb; wsb += (size_t)M_ * D_ * 2;
  u16* wqkv  = (u16*)wsb; wsb += (size_t)QLD * D_ * 2;
  u16* wo    = (u16*)wsb; wsb += (size_t)D_ * D_ * 2;
  u16* wfc1  = (u16*)wsb; wsb += (size_t)FF_ * D_ * 2;
  u16* wfc2  = (u16*)wsb; wsb += (size_t)D_ * FF_ * 2;
  u16* tmp1b = (u16*)wsb; wsb += (size_t)M_ * 32 * 2;
  u16* tmp2b = (u16*)wsb; wsb += (size_t)M_ * 32 * 2;
  u16* up1L  = (u16*)wsb; wsb += (size_t)FF_ * 32 * 2;
  u16* up1V  = (u16*)wsb; wsb += (size_t)FF_ * 32 * 2;
  u16* up2L  = (u16*)wsb; wsb += (size_t)D_ * 32 * 2;
  u16* up2V  = (u16*)wsb; wsb += (size_t)D_ * 32 * 2;
  u16* a2tL  = (u16*)wsb; wsb += (size_t)16 * FF_ * 2;
  u16* a2tV  = (u16*)wsb; wsb += (size_t)16 * FF_ * 2;
  float* qkvb = (float*)wsb; wsb += (size_t)QLD * 4;
  float* part = (float*)wsb; wsb += (size_t)8 * M_ * 16 * 4; // 4 MB
  u16* hidb = h1;   // [M,FF] bf16 aliases h1+qkv (both dead by fc1)

  const int totq = (4 * D_ * D_ + 2 * FF_ * D_) / 4;
  cvt_all<<<totq / 256, 256, 0, stream>>>(q_w, k_w, v_w, o_w, fc1_w, fc2_w,
                                          wqkv, wo, wfc1, wfc2);
  prep_all<<<FF_ / 256, 256, 0, stream>>>(q_bv, k_bv, v_bv, qkvb,
                                          lora1B, vera1B, e1b, up1L, up1V,
                                          lora2B, vera2B, e2b, up2L, up2V,
                                          lora2A, vera2A, a2tL, a2tV);

  ln_k<false><<<M_, 256, 0, stream>>>(x, nullptr, n1g, n1b, h1, nullptr,
                                      nullptr, nullptr, nullptr, nullptr, nullptr);
  gemm_bt<0><<<(M_/128) * (QLD/128), 256, 0, stream>>>(
      h1, wqkv, qkvb, qkv, nullptr, nullptr, nullptr, nullptr, nullptr, nullptr,
      M_, QLD, D_);
  attn_mfma<<<(S_/64) * (B_*H_), 256, 0, stream>>>(qkv, mask, attno);
  gemm_bt<0><<<(M_/128) * (D_/128), 256, 0, stream>>>(
      attno, wo, o_bv, oproj, nullptr, nullptr, nullptr, nullptr, nullptr, nullptr,
      M_, D_, D_);

  ln_k<true><<<M_, 256, 0, stream>>>(x, oproj, n2g, n2b, n2, (float*)d_out,
                                     lora1A, vera1A, e1d, tmp1b, nbp);

  gemm_bt<1><<<(M_/128) * (FF_/128), 256, 0, stream>>>(
      n2, wfc1, fc1_bv, hidb, nullptr, nullptr, tmp1b, up1L, up1V, nbp,
      M_, FF_, D_);

  downproj<<<dim3(M_/128, 8), 256, 0, stream>>>(hidb, a2tL, a2tV, part, nbp);
  reduce_dp<<<M_*16/256, 256, 0, stream>>>(part, e2d, tmp2b, nbp);

  gemm_bt<2><<<(M_/128) * (D_/128), 256, 0, stream>>>(
      hidb, wfc2, fc2_bv, nullptr, (float*)d_out, (const float*)d_out,
      tmp2b, up2L, up2V, nbp, M_, D_, FF_);
}

// Round 8
// 369.446 us; speedup vs baseline: 4.0771x; 1.0304x over previous
//
#include <hip/hip_runtime.h>
#include <stdint.h>

#define B_  8
#define S_  1024
#define D_  768
#define H_  12
#define HD_ 64
#define FF_ 3072
#define M_  (B_*S_)   // 8192 tokens
#define R_  16
#define QLD 2304      // packed QKV row stride
#define KBLK 128

typedef unsigned short u16;
typedef short s16x8 __attribute__((ext_vector_type(8)));   // 8 bf16 (4 VGPRs)
typedef float fx4  __attribute__((ext_vector_type(4)));    // 4 fp32 acc

__device__ __forceinline__ float b2f(u16 u) {
  union { unsigned int i; float f; } c; c.i = ((unsigned int)u) << 16; return c.f;
}
__device__ __forceinline__ u16 f2b(float f) {   // RNE f32->bf16
  union { float f; unsigned int i; } c; c.f = f;
  unsigned int x = c.i;
  x += 0x7FFFu + ((x >> 16) & 1u);
  return (u16)(x >> 16);
}
__device__ __forceinline__ float gelu_f(float x) {  // jax.nn.gelu approximate=True (tanh)
  float u = 0.7978845608028654f * (x + 0.044715f * x * x * x);
  float e = __expf(2.f * u);
  float t = 1.f - 2.f / (e + 1.f);
  return 0.5f * x * (1.f + t);
}
__device__ __forceinline__ void gload16(const u16* gsrc, u16* ldst) {
  __builtin_amdgcn_global_load_lds(
      (__attribute__((address_space(1))) void*)(gsrc),
      (__attribute__((address_space(3))) void*)(ldst), 16, 0, 0);
}

// ---------------- all weights f32 -> bf16, one kernel ----------------
__global__ __launch_bounds__(256)
void cvt_all(const float* __restrict__ q_w, const float* __restrict__ k_w,
             const float* __restrict__ v_w, const float* __restrict__ o_w,
             const float* __restrict__ fc1_w, const float* __restrict__ fc2_w,
             u16* __restrict__ wqkv, u16* __restrict__ wo,
             u16* __restrict__ wfc1, u16* __restrict__ wfc2)
{
  const int i = blockIdx.x * 256 + threadIdx.x;   // quad index
  const int q1  = D_ * D_ / 4;
  const int fd4 = FF_ * D_ / 4;
  const float* s; u16* d; int j;
  if      (i <     q1)       { s = q_w;   d = wqkv;            j = i; }
  else if (i < 2 * q1)       { s = k_w;   d = wqkv + D_*D_;    j = i - q1; }
  else if (i < 3 * q1)       { s = v_w;   d = wqkv + 2*D_*D_;  j = i - 2*q1; }
  else if (i < 4 * q1)       { s = o_w;   d = wo;              j = i - 3*q1; }
  else if (i < 4 * q1 + fd4) { s = fc1_w; d = wfc1;            j = i - 4*q1; }
  else                       { s = fc2_w; d = wfc2;            j = i - 4*q1 - fd4; }
  const float4 f = ((const float4*)s)[j];
  ushort4 o4; o4.x = f2b(f.x); o4.y = f2b(f.y); o4.z = f2b(f.z); o4.w = f2b(f.w);
  ((ushort4*)d)[j] = o4;
}

// ---------------- all small preps, one kernel ----------------
__global__ __launch_bounds__(256)
void prep_all(const float* __restrict__ q_bv, const float* __restrict__ k_bv,
              const float* __restrict__ v_bv, float* __restrict__ qkvb,
              const float* __restrict__ lora1B, const float* __restrict__ vera1B,
              const float* __restrict__ e1b, u16* __restrict__ up1L, u16* __restrict__ up1V,
              const float* __restrict__ lora2B, const float* __restrict__ vera2B,
              const float* __restrict__ e2b, u16* __restrict__ up2L, u16* __restrict__ up2V,
              const float* __restrict__ lora2A, const float* __restrict__ vera2A,
              u16* __restrict__ a2tL, u16* __restrict__ a2tV)
{
  const int f = blockIdx.x * 256 + threadIdx.x;   // 0..FF_-1
  if (f < QLD)
    qkvb[f] = (f < D_) ? q_bv[f] : (f < 2 * D_) ? k_bv[f - D_] : v_bv[f - 2 * D_];
  {
    const float ev = e1b[f];
    #pragma unroll
    for (int r = 0; r < 16; ++r) {
      up1L[(size_t)f * 32 + r] = f2b(lora1B[(size_t)r * FF_ + f]);
      up1V[(size_t)f * 32 + r] = f2b(vera1B[(size_t)r * FF_ + f] * ev);
      up1L[(size_t)f * 32 + 16 + r] = 0;
      up1V[(size_t)f * 32 + 16 + r] = 0;
    }
  }
  {
    const float4* apl = (const float4*)(lora2A + (size_t)f * 16);
    const float4* apv = (const float4*)(vera2A + (size_t)f * 16);
    #pragma unroll
    for (int q4 = 0; q4 < 4; ++q4) {
      const float4 l4 = apl[q4], v4 = apv[q4];
      a2tL[(size_t)(q4*4+0) * FF_ + f] = f2b(l4.x);
      a2tL[(size_t)(q4*4+1) * FF_ + f] = f2b(l4.y);
      a2tL[(size_t)(q4*4+2) * FF_ + f] = f2b(l4.z);
      a2tL[(size_t)(q4*4+3) * FF_ + f] = f2b(l4.w);
      a2tV[(size_t)(q4*4+0) * FF_ + f] = f2b(v4.x);
      a2tV[(size_t)(q4*4+1) * FF_ + f] = f2b(v4.y);
      a2tV[(size_t)(q4*4+2) * FF_ + f] = f2b(v4.z);
      a2tV[(size_t)(q4*4+3) * FF_ + f] = f2b(v4.w);
    }
  }
  if (f < D_) {
    const float ev = e2b[f];
    #pragma unroll
    for (int r = 0; r < 16; ++r) {
      up2L[(size_t)f * 32 + r] = f2b(lora2B[(size_t)r * D_ + f]);
      up2V[(size_t)f * 32 + r] = f2b(vera2B[(size_t)r * D_ + f] * ev);
      up2L[(size_t)f * 32 + 16 + r] = 0;
      up2V[(size_t)f * 32 + 16 + r] = 0;
    }
  }
}

// ---------------- LayerNorm (+residual add, + fused rank-16 down-projection) ----------------
template<bool ADD>
__global__ __launch_bounds__(256)
void ln_k(const float* __restrict__ x, const u16* __restrict__ add,
          const float* __restrict__ g, const float* __restrict__ beta,
          u16* __restrict__ outb, float* __restrict__ xsum,
          const float* __restrict__ Alora, const float* __restrict__ Avera,
          const float* __restrict__ dvec, u16* __restrict__ tmp1b,
          const int* __restrict__ nbp)
{
  const int row = blockIdx.x;
  const size_t base = (size_t)row * D_;
  float v0[3]; float s = 0.f, sq = 0.f;
  #pragma unroll
  for (int i = 0; i < 3; ++i) {
    const int d = threadIdx.x + i * 256;
    float val = x[base + d];
    if (ADD) { val += b2f(add[base + d]); xsum[base + d] = val; }
    v0[i] = val; s += val; sq += val * val;
  }
  #pragma unroll
  for (int mm = 32; mm >= 1; mm >>= 1) { s += __shfl_xor(s, mm); sq += __shfl_xor(sq, mm); }
  __shared__ float ss[4], s2[4];
  if ((threadIdx.x & 63) == 0) { ss[threadIdx.x >> 6] = s; s2[threadIdx.x >> 6] = sq; }
  __syncthreads();
  s  = ss[0] + ss[1] + ss[2] + ss[3];
  sq = s2[0] + s2[1] + s2[2] + s2[3];
  const float mean = s * (1.f / D_);
  const float var  = sq * (1.f / D_) - mean * mean;
  const float rs   = rsqrtf(var + 1e-6f);
  float nv[3];
  #pragma unroll
  for (int i = 0; i < 3; ++i) {
    const int d = threadIdx.x + i * 256;
    nv[i] = (v0[i] - mean) * rs * g[d] + beta[d];
    outb[base + d] = f2b(nv[i]);
  }

  if (ADD) {
    const int nb = *nbp;
    const bool ex = (row % S_) >= nb;
    const float* Am = ex ? Avera : Alora;
    float p[16];
    #pragma unroll
    for (int r = 0; r < 16; ++r) p[r] = 0.f;
    #pragma unroll
    for (int i = 0; i < 3; ++i) {
      const int d = threadIdx.x + i * 256;
      const float4* ap = (const float4*)(Am + (size_t)d * R_);
      const float4 a0 = ap[0], a1 = ap[1], a2 = ap[2], a3 = ap[3];
      const float vv = nv[i];
      p[0]  += vv * a0.x; p[1]  += vv * a0.y; p[2]  += vv * a0.z; p[3]  += vv * a0.w;
      p[4]  += vv * a1.x; p[5]  += vv * a1.y; p[6]  += vv * a1.z; p[7]  += vv * a1.w;
      p[8]  += vv * a2.x; p[9]  += vv * a2.y; p[10] += vv * a2.z; p[11] += vv * a2.w;
      p[12] += vv * a3.x; p[13] += vv * a3.y; p[14] += vv * a3.z; p[15] += vv * a3.w;
    }
    #pragma unroll
    for (int st = 1; st < 16; st <<= 1)
      #pragma unroll
      for (int r = 0; r < 16; ++r) p[r] += __shfl_xor(p[r], st);
    __shared__ float sred[16][16];
    const int grp = threadIdx.x >> 4;
    if ((threadIdx.x & 15) == 0) {
      #pragma unroll
      for (int r = 0; r < 16; ++r) sred[grp][r] = p[r];
    }
    __syncthreads();
    if (threadIdx.x < 16) {
      float v = 0.f;
      #pragma unroll
      for (int gg = 0; gg < 16; ++gg) v += sred[gg][threadIdx.x];
      if (ex) v *= dvec[threadIdx.x];
      tmp1b[(size_t)row * 32 + threadIdx.x] = f2b(v);
      tmp1b[(size_t)row * 32 + 16 + threadIdx.x] = 0;
    }
  }
}

// ---------------- bf16 MFMA GEMM, 2-phase double-buffered pipeline ----------------
// C = A[M,K] * W[N,K]^T + bias; MODE>=1 adds the adapter k-step as pipeline step nst.
// Per step: STAGE(t+1, buf^1) issued FIRST, then ds_read+MFMA from buf[cur], then ONE
// barrier (vmcnt drain overlapped by the compute phase).
template<int MODE>
__global__ __launch_bounds__(256)
void gemm_bt(const u16* __restrict__ A, const u16* __restrict__ W,
             const float* __restrict__ bias, u16* __restrict__ Cb,
             float* __restrict__ Cf, const float* __restrict__ resid,
             const u16* __restrict__ Aad, const u16* __restrict__ BadL,
             const u16* __restrict__ BadV, const int* __restrict__ nbp,
             int M, int N, int K)
{
  __shared__ u16 As[2][128 * 32];
  __shared__ u16 Bs[2][128 * 32];
  const int tid   = threadIdx.x;
  const int lane  = tid & 63;
  const int wid   = tid >> 6;
  const int wr    = wid >> 1;
  const int wc    = wid & 1;
  const int lr    = lane & 15;
  const int lk    = (lane >> 4) << 3;
  // XCD-chunked swizzle (nwg divisible by 8)
  const int gn    = N >> 7;
  const int nwg   = (M >> 7) * gn;
  const int chunk = nwg >> 3;
  const int lin   = blockIdx.x;
  const int swz   = (lin & 7) * chunk + (lin >> 3);
  const int m0    = (swz / gn) * 128;
  const int n0    = (swz % gn) * 128;
  const int kg    = (tid & 3) * 8;
  const int row_a = tid >> 2;

  const int nst = K >> 5;                      // main k-steps
  const int tot = (MODE >= 1) ? nst + 1 : nst; // + adapter step
  const u16* Bad = nullptr;
  if (MODE >= 1) Bad = ((m0 % S_) >= *nbp) ? BadV : BadL;

  const u16* arow = A + (size_t)(m0 + row_a) * K + kg;
  const u16* wrow = W + (size_t)(n0 + row_a) * K + kg;
  const size_t half_a = (size_t)64 * K;

  fx4 acc[4][4];
  const fx4 zero = {0.f, 0.f, 0.f, 0.f};
  #pragma unroll
  for (int i = 0; i < 4; ++i)
    #pragma unroll
    for (int j = 0; j < 4; ++j) acc[i][j] = zero;

  // prologue: stage step 0 into buf 0
  gload16(arow,          &As[0][tid * 8]);
  gload16(arow + half_a, &As[0][(256 + tid) * 8]);
  gload16(wrow,          &Bs[0][tid * 8]);
  gload16(wrow + half_a, &Bs[0][(256 + tid) * 8]);
  __syncthreads();

  for (int t = 0; t < tot; ++t) {
    const int cur = t & 1;
    // issue next-step staging before consuming current
    if (t + 1 < tot) {
      const int nxt = cur ^ 1;
      if (MODE >= 1 && t + 1 == nst) {
        gload16(Aad + (size_t)(m0 + row_a) * 32 + kg,      &As[nxt][tid * 8]);
        gload16(Aad + (size_t)(m0 + 64 + row_a) * 32 + kg, &As[nxt][(256 + tid) * 8]);
        gload16(Bad + (size_t)(n0 + row_a) * 32 + kg,      &Bs[nxt][tid * 8]);
        gload16(Bad + (size_t)(n0 + 64 + row_a) * 32 + kg, &Bs[nxt][(256 + tid) * 8]);
      } else {
        const size_t ko = (size_t)(t + 1) * 32;
        gload16(arow + ko,          &As[nxt][tid * 8]);
        gload16(arow + ko + half_a, &As[nxt][(256 + tid) * 8]);
        gload16(wrow + ko,          &Bs[nxt][tid * 8]);
        gload16(wrow + ko + half_a, &Bs[nxt][(256 + tid) * 8]);
      }
    }
    // consume buf[cur]
    s16x8 av[4], bv[4];
    #pragma unroll
    for (int i = 0; i < 4; ++i)
      av[i] = *(const s16x8*)&As[cur][(wr * 64 + i * 16 + lr) * 32 + lk];
    #pragma unroll
    for (int j = 0; j < 4; ++j)
      bv[j] = *(const s16x8*)&Bs[cur][(wc * 64 + j * 16 + lr) * 32 + lk];
    __builtin_amdgcn_s_setprio(1);
    #pragma unroll
    for (int i = 0; i < 4; ++i)
      #pragma unroll
      for (int j = 0; j < 4; ++j)
        acc[i][j] = __builtin_amdgcn_mfma_f32_16x16x32_bf16(av[i], bv[j], acc[i][j], 0, 0, 0);
    __builtin_amdgcn_s_setprio(0);
    __syncthreads();   // next-step loads drained here, after compute
  }

  const int rb = (lane >> 4) * 4;
  #pragma unroll
  for (int j = 0; j < 4; ++j) {
    const int col = n0 + wc * 64 + j * 16 + lr;
    const float bj = bias ? bias[col] : 0.f;
    #pragma unroll
    for (int i = 0; i < 4; ++i) {
      const int row = m0 + wr * 64 + i * 16 + rb;
      #pragma unroll
      for (int r = 0; r < 4; ++r) {
        const float val = acc[i][j][r] + bj;
        const size_t idx = (size_t)(row + r) * N + col;
        if (MODE == 1)      Cb[idx] = f2b(gelu_f(val));
        else if (MODE == 2) Cf[idx] = resid[idx] + val;
        else                Cb[idx] = f2b(val);
      }
    }
  }
}

// ---------------- skinny down-projection (2-phase dbuf): part[ks][M][16] ----------------
__global__ __launch_bounds__(256)
void downproj(const u16* __restrict__ hid, const u16* __restrict__ A2tL,
              const u16* __restrict__ A2tV, float* __restrict__ part,
              const int* __restrict__ nbp)
{
  __shared__ u16 As[2][128 * 32];
  __shared__ u16 Bs[2][16 * 32];
  const int tid  = threadIdx.x;
  const int lane = tid & 63;
  const int w    = tid >> 6;
  const int lr   = lane & 15;
  const int lk   = (lane >> 4) << 3;
  const int m0   = blockIdx.x * 128;
  const int kb   = blockIdx.y * (FF_ / 8);
  const int nb   = *nbp;
  const u16* A2t = ((m0 % S_) >= nb) ? A2tV : A2tL;
  const int kg    = (tid & 3) * 8;
  const int row_a = tid >> 2;

  const u16* hrow = hid + (size_t)(m0 + row_a) * FF_ + kb + kg;
  const size_t half_h = (size_t)64 * FF_;
  const u16* brow = A2t + (size_t)(tid >> 2) * FF_ + kb + kg;

  const fx4 zero = {0.f, 0.f, 0.f, 0.f};
  fx4 acc[2]; acc[0] = zero; acc[1] = zero;

  const int nst = (FF_ / 8) >> 5;   // 12
  // prologue
  gload16(hrow,          &As[0][tid * 8]);
  gload16(hrow + half_h, &As[0][(256 + tid) * 8]);
  if (tid < 64) gload16(brow, &Bs[0][tid * 8]);
  __syncthreads();

  for (int t = 0; t < nst; ++t) {
    const int cur = t & 1;
    if (t + 1 < nst) {
      const int nxt = cur ^ 1;
      const size_t ko = (size_t)(t + 1) * 32;
      gload16(hrow + ko,          &As[nxt][tid * 8]);
      gload16(hrow + ko + half_h, &As[nxt][(256 + tid) * 8]);
      if (tid < 64) gload16(brow + ko, &Bs[nxt][tid * 8]);
    }
    s16x8 bv = *(const s16x8*)&Bs[cur][lr * 32 + lk];
    #pragma unroll
    for (int i = 0; i < 2; ++i) {
      s16x8 av = *(const s16x8*)&As[cur][(w * 32 + i * 16 + lr) * 32 + lk];
      acc[i] = __builtin_amdgcn_mfma_f32_16x16x32_bf16(av, bv, acc[i], 0, 0, 0);
    }
    __syncthreads();
  }

  const int rb = (lane >> 4) * 4;
  #pragma unroll
  for (int i = 0; i < 2; ++i)
    #pragma unroll
    for (int r = 0; r < 4; ++r)
      part[(size_t)blockIdx.y * M_ * 16 +
           (size_t)(m0 + w * 32 + i * 16 + rb + r) * 16 + lr] = acc[i][r];
}

// ---------------- reduce partials -> tmp2b bf16 [M,32] ----------------
__global__ __launch_bounds__(256)
void reduce_dp(const float* __restrict__ part, const float* __restrict__ d2,
               u16* __restrict__ tmp2b, const int* __restrict__ nbp)
{
  const int idx = blockIdx.x * 256 + threadIdx.x;   // m*16 + r
  const int m = idx >> 4, r = idx & 15;
  const int nb = *nbp;
  float s = 0.f;
  #pragma unroll
  for (int ks = 0; ks < 8; ++ks) s += part[(size_t)ks * M_ * 16 + idx];
  if ((m % S_) >= nb) s *= d2[r];
  tmp2b[(size_t)m * 32 + r] = f2b(s);
  tmp2b[(size_t)m * 32 + 16 + r] = 0;
}

// ---------------- MFMA flash attention: swapped QK^T (q lane-local), dbuf K/V ----------------
__global__ __launch_bounds__(256)
void attn_mfma(const u16* __restrict__ qkv, const float* __restrict__ mask,
               u16* __restrict__ o)
{
  __shared__ u16 Kl[2][128 * 64];   // row k, col d, swz col^((k&7)<<3)
  __shared__ u16 Vt[2][64 * 128];   // row d, col k, swz k^(((d&7)^((d>>3)&7))<<3)
  __shared__ uint32_t Pl[4][1024];  // per-wave P rows [16][64 u32]; prologue: Q overlay

  const int tid  = threadIdx.x;
  const int lane = tid & 63;
  const int wq   = tid >> 6;
  const int lr   = lane & 15;
  const int hi   = lane >> 4;
  const int lin = blockIdx.x;
  const int vsw = (lin & 7) * 192 + (lin >> 3);
  const int qb  = vsw & 15;
  const int bh  = vsw >> 4;
  const int b    = bh / H_;
  const int h    = bh % H_;
  const size_t tok0 = (size_t)b * S_ + (size_t)qb * 64;
  const size_t colh = (size_t)h * HD_;

  const int va  = tid >> 3;
  const int vc8 = (tid & 7) * 8;
  u16* qstage = (u16*)&Pl[0][0];

  #pragma unroll
  for (int u = 0; u < 2; ++u) {
    const int li = u * 256 + tid;
    const int r  = li >> 3;
    const int cb = ((li & 7) ^ (r & 7)) * 8;
    gload16(qkv + (tok0 + r) * QLD + colh + cb, &qstage[li * 8]);
  }
  {
    const size_t ktok = (size_t)b * S_;
    #pragma unroll
    for (int u = 0; u < 4; ++u) {
      const int li = u * 256 + tid;
      const int r  = li >> 3;
      const int cb = ((li & 7) ^ (r & 7)) * 8;
      gload16(qkv + (ktok + r) * QLD + D_ + colh + cb, &Kl[0][li * 8]);
    }
    const u16* vp = qkv + (ktok + 4 * va) * QLD + 2 * D_ + colh + vc8;
    s16x8 w0 = *(const s16x8*)vp;
    s16x8 w1 = *(const s16x8*)(vp + QLD);
    s16x8 w2 = *(const s16x8*)(vp + 2 * QLD);
    s16x8 w3 = *(const s16x8*)(vp + 3 * QLD);
    #pragma unroll
    for (int jj = 0; jj < 8; ++jj) {
      const int d  = vc8 + jj;
      const int sw = ((d & 7) ^ ((d >> 3) & 7)) << 3;
      const int cp = (4 * va) ^ sw;
      *(uint32_t*)&Vt[0][d * 128 + cp] =
          (uint32_t)(u16)w0[jj] | ((uint32_t)(u16)w1[jj] << 16);
      *(uint32_t*)&Vt[0][d * 128 + cp + 2] =
          (uint32_t)(u16)w2[jj] | ((uint32_t)(u16)w3[jj] << 16);
    }
  }
  __syncthreads();

  s16x8 qa[2];
  {
    const int qrow = wq * 16 + lr;
    #pragma unroll
    for (int ks = 0; ks < 2; ++ks)
      qa[ks] = *(const s16x8*)&qstage[qrow * 64 + ((ks * 32 + hi * 8) ^ ((qrow & 7) << 3))];
  }
  __syncthreads();

  const fx4 zero = {0.f, 0.f, 0.f, 0.f};
  fx4 oacc[4];
  #pragma unroll
  for (int dj = 0; dj < 4; ++dj) oacc[dj] = zero;
  float mreg = -3.0e38f, lreg = 0.f;

  const int NT = S_ / KBLK;   // 8
  for (int kt = 0; kt < NT; ++kt) {
    const int cur = kt & 1;
    const int nxt = cur ^ 1;

    s16x8 w0, w1, w2, w3;
    if (kt + 1 < NT) {
      const size_t ktokn = (size_t)b * S_ + (size_t)(kt + 1) * KBLK;
      #pragma unroll
      for (int u = 0; u < 4; ++u) {
        const int li = u * 256 + tid;
        const int r  = li >> 3;
        const int cb = ((li & 7) ^ (r & 7)) * 8;
        gload16(qkv + (ktokn + r) * QLD + D_ + colh + cb, &Kl[nxt][li * 8]);
      }
      const u16* vp = qkv + (ktokn + 4 * va) * QLD + 2 * D_ + colh + vc8;
      w0 = *(const s16x8*)vp;
      w1 = *(const s16x8*)(vp + QLD);
      w2 = *(const s16x8*)(vp + 2 * QLD);
      w3 = *(const s16x8*)(vp + 3 * QLD);
    }

    float val[8][4];
    #pragma unroll
    for (int jh = 0; jh < 2; ++jh) {
      s16x8 kb2[4][2];
      #pragma unroll
      for (int j = 0; j < 4; ++j) {
        const int n = (jh * 4 + j) * 16 + lr;
        #pragma unroll
        for (int ks = 0; ks < 2; ++ks)
          kb2[j][ks] = *(const s16x8*)&Kl[cur][n * 64 + ((ks * 32 + hi * 8) ^ ((n & 7) << 3))];
      }
      fx4 m4[4];
      {
        const float* mp = mask + (size_t)(qb * 64 + wq * 16 + lr) * S_
                        + (size_t)kt * KBLK + jh * 64 + 4 * hi;
        #pragma unroll
        for (int j = 0; j < 4; ++j)
          m4[j] = *(const fx4*)(mp + j * 16);
      }
      fx4 sf[4];
      #pragma unroll
      for (int j = 0; j < 4; ++j) sf[j] = zero;
      __builtin_amdgcn_s_setprio(1);
      #pragma unroll
      for (int ks = 0; ks < 2; ++ks)
        #pragma unroll
        for (int j = 0; j < 4; ++j)
          sf[j] = __builtin_amdgcn_mfma_f32_16x16x32_bf16(kb2[j][ks], qa[ks], sf[j], 0, 0, 0);
      __builtin_amdgcn_s_setprio(0);
      #pragma unroll
      for (int j = 0; j < 4; ++j)
        #pragma unroll
        for (int r = 0; r < 4; ++r)
          val[jh * 4 + j][r] = sf[j][r] * 0.125f + m4[j][r];
    }

    {
      float mk[8];
      #pragma unroll
      for (int kg = 0; kg < 8; ++kg)
        mk[kg] = fmaxf(fmaxf(val[kg][0], val[kg][1]), fmaxf(val[kg][2], val[kg][3]));
      float mx = fmaxf(fmaxf(fmaxf(mk[0], mk[1]), fmaxf(mk[2], mk[3])),
                       fmaxf(fmaxf(mk[4], mk[5]), fmaxf(mk[6], mk[7])));
      mx = fmaxf(mx, __shfl_xor(mx, 16));
      mx = fmaxf(mx, __shfl_xor(mx, 32));
      const float mn  = fmaxf(mreg, mx);
      const float fac = __expf(mreg - mn);
      mreg = mn;
      float sk[8];
      #pragma unroll
      for (int kg = 0; kg < 8; ++kg) {
        #pragma unroll
        for (int r = 0; r < 4; ++r) val[kg][r] = __expf(val[kg][r] - mn);
        sk[kg] = (val[kg][0] + val[kg][1]) + (val[kg][2] + val[kg][3]);
      }
      float rs = ((sk[0] + sk[1]) + (sk[2] + sk[3])) + ((sk[4] + sk[5]) + (sk[6] + sk[7]));
      rs += __shfl_xor(rs, 16);
      rs += __shfl_xor(rs, 32);
      lreg = lreg * fac + rs;
      float facr[4];
      #pragma unroll
      for (int r = 0; r < 4; ++r) facr[r] = __shfl(fac, hi * 4 + r);
      #pragma unroll
      for (int dj = 0; dj < 4; ++dj)
        #pragma unroll
        for (int r = 0; r < 4; ++r) oacc[dj][r] *= facr[r];
    }

    {
      uint32_t* prow = &Pl[wq][lr * 64];
      #pragma unroll
      for (int kg = 0; kg < 8; ++kg) {
        const uint32_t p0 = __builtin_amdgcn_perm(
            __float_as_uint(val[kg][1]), __float_as_uint(val[kg][0]), 0x07060302u);
        const uint32_t p1 = __builtin_amdgcn_perm(
            __float_as_uint(val[kg][3]), __float_as_uint(val[kg][2]), 0x07060302u);
        const int i0 = (8 * kg + 2 * hi) ^ ((lr & 7) << 3);
        uint2 pk; pk.x = p0; pk.y = p1;
        *(uint2*)&prow[i0] = pk;
      }
    }

    if (kt + 1 < NT) {
      #pragma unroll
      for (int jj = 0; jj < 8; ++jj) {
        const int d  = vc8 + jj;
        const int sw = ((d & 7) ^ ((d >> 3) & 7)) << 3;
        const int cp = (4 * va) ^ sw;
        *(uint32_t*)&Vt[nxt][d * 128 + cp] =
            (uint32_t)(u16)w0[jj] | ((uint32_t)(u16)w1[jj] << 16);
        *(uint32_t*)&Vt[nxt][d * 128 + cp + 2] =
            (uint32_t)(u16)w2[jj] | ((uint32_t)(u16)w3[jj] << 16);
      }
    }

    #pragma unroll
    for (int ks = 0; ks < 4; ++ks) {
      const int pbase = (16 * ks + 4 * hi) ^ ((lr & 7) << 3);
      s16x8 pa = *(const s16x8*)&Pl[wq][lr * 64 + pbase];
      s16x8 bv2[4];
      #pragma unroll
      for (int dj = 0; dj < 4; ++dj) {
        const int n  = dj * 16 + lr;
        const int sw = ((n & 7) ^ ((n >> 3) & 7)) << 3;
        bv2[dj] = *(const s16x8*)&Vt[cur][n * 128 + ((ks * 32 + hi * 8) ^ sw)];
      }
      __builtin_amdgcn_s_setprio(1);
      #pragma unroll
      for (int dj = 0; dj < 4; ++dj)
        oacc[dj] = __builtin_amdgcn_mfma_f32_16x16x32_bf16(pa, bv2[dj], oacc[dj], 0, 0, 0);
      __builtin_amdgcn_s_setprio(0);
    }

    __syncthreads();
  }

  {
    const float linv = 1.f / lreg;
    float invr[4];
    #pragma unroll
    for (int r = 0; r < 4; ++r) invr[r] = __shfl(linv, hi * 4 + r);
    #pragma unroll
    for (int r = 0; r < 4; ++r) {
      const size_t grow = (tok0 + wq * 16 + hi * 4 + r) * D_ + colh;
      #pragma unroll
      for (int dj = 0; dj < 4; ++dj)
        o[grow + dj * 16 + lr] = f2b(oacc[dj][r] * invr[r]);
    }
  }
}

extern "C" void kernel_launch(void* const* d_in, const int* in_sizes, int n_in,
                              void* d_out, int out_size, void* d_ws, size_t ws_size,
                              hipStream_t stream)
{
  const float* x      = (const float*)d_in[0];
  const float* mask   = (const float*)d_in[1];
  const float* n1g    = (const float*)d_in[2];
  const float* n1b    = (const float*)d_in[3];
  const float* q_w    = (const float*)d_in[4];
  const float* q_bv   = (const float*)d_in[5];
  const float* k_w    = (const float*)d_in[6];
  const float* k_bv   = (const float*)d_in[7];
  const float* v_w    = (const float*)d_in[8];
  const float* v_bv   = (const float*)d_in[9];
  const float* o_w    = (const float*)d_in[10];
  const float* o_bv   = (const float*)d_in[11];
  const float* n2g    = (const float*)d_in[12];
  const float* n2b    = (const float*)d_in[13];
  const float* fc1_w  = (const float*)d_in[14];
  const float* fc1_bv = (const float*)d_in[15];
  const float* fc2_w  = (const float*)d_in[16];
  const float* fc2_bv = (const float*)d_in[17];
  const float* lora1A = (const float*)d_in[18];
  const float* lora1B = (const float*)d_in[19];
  const float* lora2A = (const float*)d_in[20];
  const float* lora2B = (const float*)d_in[21];
  const float* vera1A = (const float*)d_in[22];
  const float* vera1B = (const float*)d_in[23];
  const float* vera2A = (const float*)d_in[24];
  const float* vera2B = (const float*)d_in[25];
  const float* e1d    = (const float*)d_in[26];
  const float* e1b    = (const float*)d_in[27];
  const float* e2d    = (const float*)d_in[28];
  const float* e2b    = (const float*)d_in[29];
  const int*   nbp    = (const int*)d_in[30];

  char* wsb = (char*)d_ws;
  u16* h1    = (u16*)wsb; wsb += (size_t)M_ * D_ * 2;       // 12.6 MB
  u16* qkv   = (u16*)wsb; wsb += (size_t)M_ * QLD * 2;      // 37.7 MB
  u16* attno = (u16*)wsb; wsb += (size_t)M_ * D_ * 2;
  u16* oproj = (u16*)wsb; wsb += (size_t)M_ * D_ * 2;
  u16* n2    = (u16*)wsb; wsb += (size_t)M_ * D_ * 2;
  u16* wqkv  = (u16*)wsb; wsb += (size_t)QLD * D_ * 2;
  u16* wo    = (u16*)wsb; wsb += (size_t)D_ * D_ * 2;
  u16* wfc1  = (u16*)wsb; wsb += (size_t)FF_ * D_ * 2;
  u16* wfc2  = (u16*)wsb; wsb += (size_t)D_ * FF_ * 2;
  u16* tmp1b = (u16*)wsb; wsb += (size_t)M_ * 32 * 2;
  u16* tmp2b = (u16*)wsb; wsb += (size_t)M_ * 32 * 2;
  u16* up1L  = (u16*)wsb; wsb += (size_t)FF_ * 32 * 2;
  u16* up1V  = (u16*)wsb; wsb += (size_t)FF_ * 32 * 2;
  u16* up2L  = (u16*)wsb; wsb += (size_t)D_ * 32 * 2;
  u16* up2V  = (u16*)wsb; wsb += (size_t)D_ * 32 * 2;
  u16* a2tL  = (u16*)wsb; wsb += (size_t)16 * FF_ * 2;
  u16* a2tV  = (u16*)wsb; wsb += (size_t)16 * FF_ * 2;
  float* qkvb = (float*)wsb; wsb += (size_t)QLD * 4;
  float* part = (float*)wsb; wsb += (size_t)8 * M_ * 16 * 4; // 4 MB
  u16* hidb = h1;   // [M,FF] bf16 aliases h1+qkv (both dead by fc1)

  const int totq = (4 * D_ * D_ + 2 * FF_ * D_) / 4;
  cvt_all<<<totq / 256, 256, 0, stream>>>(q_w, k_w, v_w, o_w, fc1_w, fc2_w,
                                          wqkv, wo, wfc1, wfc2);
  prep_all<<<FF_ / 256, 256, 0, stream>>>(q_bv, k_bv, v_bv, qkvb,
                                          lora1B, vera1B, e1b, up1L, up1V,
                                          lora2B, vera2B, e2b, up2L, up2V,
                                          lora2A, vera2A, a2tL, a2tV);

  ln_k<false><<<M_, 256, 0, stream>>>(x, nullptr, n1g, n1b, h1, nullptr,
                                      nullptr, nullptr, nullptr, nullptr, nullptr);
  gemm_bt<0><<<(M_/128) * (QLD/128), 256, 0, stream>>>(
      h1, wqkv, qkvb, qkv, nullptr, nullptr, nullptr, nullptr, nullptr, nullptr,
      M_, QLD, D_);
  attn_mfma<<<(S_/64) * (B_*H_), 256, 0, stream>>>(qkv, mask, attno);
  gemm_bt<0><<<(M_/128) * (D_/128), 256, 0, stream>>>(
      attno, wo, o_bv, oproj, nullptr, nullptr, nullptr, nullptr, nullptr, nullptr,
      M_, D_, D_);

  ln_k<true><<<M_, 256, 0, stream>>>(x, oproj, n2g, n2b, n2, (float*)d_out,
                                     lora1A, vera1A, e1d, tmp1b, nbp);

  gemm_bt<1><<<(M_/128) * (FF_/128), 256, 0, stream>>>(
      n2, wfc1, fc1_bv, hidb, nullptr, nullptr, tmp1b, up1L, up1V, nbp,
      M_, FF_, D_);

  downproj<<<dim3(M_/128, 8), 256, 0, stream>>>(hidb, a2tL, a2tV, part, nbp);
  reduce_dp<<<M_*16/256, 256, 0, stream>>>(part, e2d, tmp2b, nbp);

  gemm_bt<2><<<(M_/128) * (D_/128), 256, 0, stream>>>(
      hidb, wfc2, fc2_bv, nullptr, (float*)d_out, (const float*)d_out,
      tmp2b, up2L, up2V, nbp, M_, D_, FF_);
}